// Round 2
// baseline (23700.020 us; speedup 1.0000x reference)
//
#include <hip/hip_runtime.h>
#include <hip/hip_cooperative_groups.h>

namespace cg = cooperative_groups;

typedef __attribute__((ext_vector_type(8))) short bf16x8;
typedef __attribute__((ext_vector_type(8))) unsigned short u16x8;
typedef __attribute__((ext_vector_type(4))) unsigned short u16x4;
typedef __attribute__((ext_vector_type(4))) float f32x4;

#define NB 32
#define NT 512
#define ND 256
#define NE 1024
#define NH 1024

__device__ __forceinline__ float bf2f(unsigned short u){
  union { unsigned int i; float f; } w; w.i = ((unsigned int)u) << 16; return w.f;
}
__device__ __forceinline__ unsigned short f2bf(float f){
  union { float f; unsigned int i; } w; w.f = f;
  unsigned int r = (w.i >> 16) & 1u;
  return (unsigned short)((w.i + 0x7fffu + r) >> 16);
}

// ---------------- conversion / prep ----------------
__global__ void f2b_kernel(const float* __restrict__ src, unsigned short* __restrict__ dst, long n){
  long i = (long)blockIdx.x*blockDim.x + threadIdx.x;
  long stride = (long)gridDim.x*blockDim.x;
  for (; i < n; i += stride) dst[i] = f2bf(src[i]);
}

// obs chunk: local row lr=(b*Tc+tl) -> global row b*512 + t0 + tl
__global__ void f2b_obs_chunk(const float* __restrict__ obs, unsigned short* __restrict__ dst,
                              int lgTc, int t0){
  const int Tc = 1 << lgTc;
  const long n = (long)NB * Tc * ND;
  long i = (long)blockIdx.x*blockDim.x + threadIdx.x;
  long stride = (long)gridDim.x*blockDim.x;
  for (; i < n; i += stride){
    long lr = i >> 8;           // ND=256
    int col = (int)(i & 255);
    long gr = (lr >> lgTc)*NT + t0 + (lr & (Tc-1));
    dst[i] = f2bf(obs[gr*ND + col]);
  }
}

__global__ void prep_kernel(const float* __restrict__ Wa, const float* __restrict__ Wc,
                            const float* __restrict__ ba, const float* __restrict__ bc,
                            const float* __restrict__ b_ih, const float* __restrict__ b_hh,
                            unsigned short* __restrict__ Whead, float* __restrict__ bias_heads,
                            float* __restrict__ bias_xg){
  int i = blockIdx.x*blockDim.x + threadIdx.x;
  int stride = gridDim.x*blockDim.x;
  for (int v = i; v < 65*1024; v += stride){
    int n = v >> 10, k = v & 1023;
    float w = (n < 64) ? Wa[v] : Wc[k];
    Whead[v] = f2bf(w);
  }
  for (int v = i; v < 4096; v += stride) bias_xg[v] = b_ih[v] + b_hh[v];
  for (int v = i; v < 65; v += stride) bias_heads[v] = (v < 64) ? ba[v] : bc[0];
}

__global__ void init_hc(const float* __restrict__ hxs, const float* __restrict__ cxs,
                        float* __restrict__ h_bufs, float* __restrict__ c_buf){
  int i = blockIdx.x*blockDim.x + threadIdx.x;
  if (i < NB*NH){ h_bufs[i] = hxs[i]; c_buf[i] = cxs[i]; }
}

__global__ void sentinel_kernel(float* __restrict__ out){ out[0] = 1.0e6f; }

// ---------------- bf16 MFMA GEMM: C[M,N] = act(A[M,K] @ Bw[N,K]^T + bias) ----------------
template<int SILU, int HEADS>
__global__ __launch_bounds__(256)
void gemm_bt(const unsigned short* __restrict__ A, const unsigned short* __restrict__ Bw,
             const float* __restrict__ bias, unsigned short* __restrict__ C,
             float* __restrict__ oLogits, float* __restrict__ oValues,
             int K, int N, int Nreal)
{
  __shared__ __align__(16) unsigned short As[128*40];
  __shared__ __align__(16) unsigned short Bs[128*40];
  const int tid = threadIdx.x;
  const int lane = tid & 63;
  const int wave = tid >> 6;
  const int wm = wave >> 1, wn = wave & 1;
  const int m0 = blockIdx.x * 128, n0 = blockIdx.y * 128;
  f32x4 acc[4][4];
#pragma unroll
  for (int i=0;i<4;i++)
#pragma unroll
    for (int j=0;j<4;j++){ f32x4 z = {0.f,0.f,0.f,0.f}; acc[i][j] = z; }
  const int rowL = tid >> 1;
  const int kL = (tid & 1) * 16;
  const int fr = lane & 15;
  const int kf = (lane >> 4) * 8;

  for (int k0 = 0; k0 < K; k0 += 32) {
    u16x8 va0 = *(const u16x8*)&A[(size_t)(m0+rowL)*K + k0 + kL];
    u16x8 va1 = *(const u16x8*)&A[(size_t)(m0+rowL)*K + k0 + kL + 8];
    u16x8 vb0, vb1;
    int nrow = n0 + rowL;
    if (nrow < Nreal) {
      vb0 = *(const u16x8*)&Bw[(size_t)nrow*K + k0 + kL];
      vb1 = *(const u16x8*)&Bw[(size_t)nrow*K + k0 + kL + 8];
    } else {
#pragma unroll
      for (int q=0;q<8;q++){ vb0[q]=0; vb1[q]=0; }
    }
    __syncthreads();
    *(u16x8*)&As[rowL*40 + kL]     = va0;
    *(u16x8*)&As[rowL*40 + kL + 8] = va1;
    *(u16x8*)&Bs[rowL*40 + kL]     = vb0;
    *(u16x8*)&Bs[rowL*40 + kL + 8] = vb1;
    __syncthreads();
    bf16x8 af[4], bfr[4];
#pragma unroll
    for (int f=0; f<4; f++){
      af[f]  = *(const bf16x8*)&As[(wm*64 + f*16 + fr)*40 + kf];
      bfr[f] = *(const bf16x8*)&Bs[(wn*64 + f*16 + fr)*40 + kf];
    }
#pragma unroll
    for (int i=0;i<4;i++)
#pragma unroll
      for (int j=0;j<4;j++)
        acc[i][j] = __builtin_amdgcn_mfma_f32_16x16x32_bf16(af[i], bfr[j], acc[i][j], 0, 0, 0);
  }

  const int mb = (lane >> 4) * 4;
  const int nb = lane & 15;
#pragma unroll
  for (int i=0;i<4;i++)
#pragma unroll
    for (int j=0;j<4;j++)
#pragma unroll
      for (int r=0;r<4;r++){
        int m = m0 + wm*64 + i*16 + mb + r;
        int n = n0 + wn*64 + j*16 + nb;
        if (HEADS && n >= Nreal) continue;
        float v = acc[i][j][r] + bias[n];
        if (SILU) v = v / (1.f + expf(-v));
        if (!HEADS) {
          C[(size_t)m*N + n] = f2bf(v);
        } else {
          if (n < 64) oLogits[(size_t)m*64 + n] = v;
          else if (n == 64) oValues[m] = v;
        }
      }
}

// ---------------- LSTM: cooperative chunk kernel ----------------
// 256 WGs x 256 thr. WG wg owns hidden units wg*4..+3 (16 gate rows), fp32 W slice in LDS.
__global__ __launch_bounds__(256)
void lstm_chunk(const unsigned short* __restrict__ xg, const float* __restrict__ Whh,
                float* __restrict__ h_bufs, float* __restrict__ c_buf,
                float* __restrict__ hist, float* __restrict__ dh, float* __restrict__ dc,
                int t0, int t1, int Tc)
{
  cg::grid_group grid = cg::this_grid();
  __shared__ __align__(16) float Wl[16*1024];   // 64 KB, XOR-swizzled
  const int wg = blockIdx.x;
  const int n0w = wg * 4;
  const int tid = threadIdx.x;

  for (int i = tid; i < 16*1024; i += 256) {
    int r = i >> 10, k = i & 1023;
    Wl[i ^ (((i >> 5) & 7) << 2)] = Whh[(size_t)((r>>2)*NH + n0w + (r&3))*NH + k];
  }
  const int kc = tid & 31, bg = tid >> 5;
  int bE=0, jE=0, nE=0, blE=0;
  float c_reg = 0.f, h_keep = 0.f;
  if (kc < 16) { blE = kc >> 2; jE = kc & 3; bE = bg*4 + blE; nE = n0w + jE; c_reg = c_buf[bE*NH + nE]; }
  __syncthreads();

  for (int t = t0; t < t1; t++) {
    const float* hb = h_bufs + (t & 1) * (NB*NH);
    float acc[16][4];
#pragma unroll
    for (int r=0;r<16;r++)
#pragma unroll
      for (int bb=0;bb<4;bb++) acc[r][bb] = 0.f;

#pragma unroll
    for (int kk=0; kk<8; kk++){
      const int k4 = kc*32 + kk*4;
      f32x4 hq[4];
#pragma unroll
      for (int bb=0;bb<4;bb++)
        hq[bb] = *(const f32x4*)&hb[(bg*4+bb)*NH + k4];
#pragma unroll
      for (int r=0;r<16;r++){
        int idx = r*1024 + k4;
        f32x4 wq = *(const f32x4*)&Wl[idx ^ ((kc & 7) << 2)];
#pragma unroll
        for (int bb=0;bb<4;bb++)
          acc[r][bb] = fmaf(wq[0],hq[bb][0], fmaf(wq[1],hq[bb][1],
                       fmaf(wq[2],hq[bb][2], fmaf(wq[3],hq[bb][3], acc[r][bb]))));
      }
    }
#pragma unroll
    for (int r=0;r<16;r++)
#pragma unroll
      for (int bb=0;bb<4;bb++){
        float v = acc[r][bb];
        v += __shfl_xor(v, 1);
        v += __shfl_xor(v, 2);
        v += __shfl_xor(v, 4);
        v += __shfl_xor(v, 8);
        v += __shfl_xor(v, 16);
        acc[r][bb] = v;
      }
    if (kc < 16) {
      int tl = t - t0;
      size_t xbase = ((size_t)bE*Tc + tl)*4096;
      float gi = acc[ 0+jE][blE] + bf2f(xg[xbase + 0*NH + nE]);
      float gf = acc[ 4+jE][blE] + bf2f(xg[xbase + 1*NH + nE]);
      float gg = acc[ 8+jE][blE] + bf2f(xg[xbase + 2*NH + nE]);
      float go = acc[12+jE][blE] + bf2f(xg[xbase + 3*NH + nE]);
      float iv = 1.f/(1.f+expf(-gi));
      float fv = 1.f/(1.f+expf(-gf));
      float gv = tanhf(gg);
      float ov = 1.f/(1.f+expf(-go));
      float c = fv*c_reg + iv*gv;
      float h = ov*tanhf(c);
      c_reg = c; h_keep = h;
      h_bufs[((t+1)&1)*(NB*NH) + bE*NH + nE] = h;
      hist[((size_t)bE*Tc + tl)*NH + nE] = h;
    }
    grid.sync();
  }
  if (kc < 16) {
    c_buf[bE*NH + nE] = c_reg;
    if (t1 == NT){ dh[bE*NH + nE] = h_keep; dc[bE*NH + nE] = c_reg; }
  }
}

// ---------------- LSTM: per-step fallback (regular launches) ----------------
__global__ __launch_bounds__(256)
void lstm_step(const unsigned short* __restrict__ xg, const float* __restrict__ Whh,
               float* __restrict__ h_bufs, float* __restrict__ c_buf,
               float* __restrict__ hist, float* __restrict__ dh, float* __restrict__ dc,
               int t, int t0, int Tc)
{
  const int wg = blockIdx.x;
  const int n0w = wg * 4;
  const int tid = threadIdx.x;
  const int kc = tid & 31, bg = tid >> 5;
  const float* hb = h_bufs + (t & 1) * (NB*NH);
  float acc[16][4];
#pragma unroll
  for (int r=0;r<16;r++)
#pragma unroll
    for (int bb=0;bb<4;bb++) acc[r][bb] = 0.f;

#pragma unroll
  for (int kk=0; kk<8; kk++){
    const int k4 = kc*32 + kk*4;
    f32x4 hq[4];
#pragma unroll
    for (int bb=0;bb<4;bb++)
      hq[bb] = *(const f32x4*)&hb[(bg*4+bb)*NH + k4];
#pragma unroll
    for (int r=0;r<16;r++){
      f32x4 wq = *(const f32x4*)&Whh[(size_t)((r>>2)*NH + n0w + (r&3))*NH + k4];
#pragma unroll
      for (int bb=0;bb<4;bb++)
        acc[r][bb] = fmaf(wq[0],hq[bb][0], fmaf(wq[1],hq[bb][1],
                     fmaf(wq[2],hq[bb][2], fmaf(wq[3],hq[bb][3], acc[r][bb]))));
    }
  }
#pragma unroll
  for (int r=0;r<16;r++)
#pragma unroll
    for (int bb=0;bb<4;bb++){
      float v = acc[r][bb];
      v += __shfl_xor(v, 1);
      v += __shfl_xor(v, 2);
      v += __shfl_xor(v, 4);
      v += __shfl_xor(v, 8);
      v += __shfl_xor(v, 16);
      acc[r][bb] = v;
    }
  if (kc < 16) {
    int blE = kc >> 2, jE = kc & 3;
    int bE = bg*4 + blE, nE = n0w + jE;
    int tl = t - t0;
    size_t xbase = ((size_t)bE*Tc + tl)*4096;
    float gi = acc[ 0+jE][blE] + bf2f(xg[xbase + 0*NH + nE]);
    float gf = acc[ 4+jE][blE] + bf2f(xg[xbase + 1*NH + nE]);
    float gg = acc[ 8+jE][blE] + bf2f(xg[xbase + 2*NH + nE]);
    float go = acc[12+jE][blE] + bf2f(xg[xbase + 3*NH + nE]);
    float iv = 1.f/(1.f+expf(-gi));
    float fv = 1.f/(1.f+expf(-gf));
    float gv = tanhf(gg);
    float ov = 1.f/(1.f+expf(-go));
    float c_prev = c_buf[bE*NH + nE];
    float c = fv*c_prev + iv*gv;
    float h = ov*tanhf(c);
    c_buf[bE*NH + nE] = c;
    h_bufs[((t+1)&1)*(NB*NH) + bE*NH + nE] = h;
    hist[((size_t)bE*Tc + tl)*NH + nE] = h;
    if (t == NT-1){ dh[bE*NH + nE] = h; dc[bE*NH + nE] = c; }
  }
}

// ---------------- LayerNorm (chunked rows) -> bf16 out_ln (global rows) ----------------
__global__ __launch_bounds__(256)
void ln_chunk(const float* __restrict__ X, const float* __restrict__ gam, const float* __restrict__ bet,
              unsigned short* __restrict__ Y, int lgTc, int t0)
{
  const int row = blockIdx.x;               // local (b*Tc + tl)
  const int Tc = 1 << lgTc;
  const int bl = row >> lgTc, tl = row & (Tc-1);
  const long grow = (long)bl*NT + t0 + tl;
  const int tid = threadIdx.x;
  const float* x = X + (size_t)row*NH;
  f32x4 v = *(const f32x4*)&x[tid*4];
  float s = v[0]+v[1]+v[2]+v[3];
  s += __shfl_xor(s,1); s += __shfl_xor(s,2); s += __shfl_xor(s,4);
  s += __shfl_xor(s,8); s += __shfl_xor(s,16); s += __shfl_xor(s,32);
  __shared__ float red[8];
  if ((tid & 63) == 0) red[tid >> 6] = s;
  __syncthreads();
  float mean = (red[0]+red[1]+red[2]+red[3]) * (1.0f/NH);
  float d0 = v[0]-mean, d1 = v[1]-mean, d2 = v[2]-mean, d3 = v[3]-mean;
  float q = d0*d0 + d1*d1 + d2*d2 + d3*d3;
  q += __shfl_xor(q,1); q += __shfl_xor(q,2); q += __shfl_xor(q,4);
  q += __shfl_xor(q,8); q += __shfl_xor(q,16); q += __shfl_xor(q,32);
  if ((tid & 63) == 0) red[4 + (tid >> 6)] = q;
  __syncthreads();
  float var = (red[4]+red[5]+red[6]+red[7]) * (1.0f/NH);
  float rs = 1.f / sqrtf(var + 1e-5f);
  f32x4 gm = *(const f32x4*)&gam[tid*4];
  f32x4 bt = *(const f32x4*)&bet[tid*4];
  u16x4 ov;
  ov[0] = f2bf(d0*rs*gm[0] + bt[0]);
  ov[1] = f2bf(d1*rs*gm[1] + bt[1]);
  ov[2] = f2bf(d2*rs*gm[2] + bt[2]);
  ov[3] = f2bf(d3*rs*gm[3] + bt[3]);
  *(u16x4*)&Y[(size_t)grow*NH + tid*4] = ov;
}

// ---------------- ar / tar losses ----------------
__global__ __launch_bounds__(256)
void loss_partial(const unsigned short* __restrict__ Yu, float* __restrict__ partials)
{
  float ar = 0.f, tar = 0.f;
  long stride = (long)gridDim.x*256;
  for (long vv = (long)blockIdx.x*256 + threadIdx.x; vv < 2097152; vv += stride){
    long i = vv*8;
    int t = (int)((i >> 10) & 511);
    u16x8 y = *(const u16x8*)&Yu[i];
    float x[8];
#pragma unroll
    for (int q=0;q<8;q++){ x[q] = bf2f(y[q]); ar += x[q]*x[q]; }
    if (t > 0){
      u16x8 yp = *(const u16x8*)&Yu[i - 1024];
#pragma unroll
      for (int q=0;q<8;q++){ float d = x[q] - bf2f(yp[q]); tar += d*d; }
    }
  }
  ar += __shfl_xor(ar,1); ar += __shfl_xor(ar,2); ar += __shfl_xor(ar,4);
  ar += __shfl_xor(ar,8); ar += __shfl_xor(ar,16); ar += __shfl_xor(ar,32);
  tar += __shfl_xor(tar,1); tar += __shfl_xor(tar,2); tar += __shfl_xor(tar,4);
  tar += __shfl_xor(tar,8); tar += __shfl_xor(tar,16); tar += __shfl_xor(tar,32);
  __shared__ float red[16];
  int w = threadIdx.x >> 6;
  if ((threadIdx.x & 63) == 0){ red[w] = ar; red[8+w] = tar; }
  __syncthreads();
  if (threadIdx.x == 0){
    partials[blockIdx.x*2]   = red[0]+red[1]+red[2]+red[3];
    partials[blockIdx.x*2+1] = red[8]+red[9]+red[10]+red[11];
  }
}

__global__ __launch_bounds__(256)
void loss_final(const float* __restrict__ partials, float* __restrict__ oAr, float* __restrict__ oTar){
  double sa = 0.0, st = 0.0;
  for (int i = threadIdx.x; i < 1024; i += 256){ sa += (double)partials[2*i]; st += (double)partials[2*i+1]; }
  for (int m=1;m<64;m<<=1){ sa += __shfl_xor(sa, m); st += __shfl_xor(st, m); }
  __shared__ double rd[8];
  int w = threadIdx.x >> 6;
  if ((threadIdx.x & 63) == 0){ rd[w] = sa; rd[4+w] = st; }
  __syncthreads();
  if (threadIdx.x == 0){
    double a  = rd[0]+rd[1]+rd[2]+rd[3];
    double tt = rd[4]+rd[5]+rd[6]+rd[7];
    oAr[0]  = (float)(a  / 16777216.0 * 0.01);
    oTar[0] = (float)(tt / 16744448.0 * 0.01);
  }
}

// ---------------- launch ----------------
extern "C" void kernel_launch(void* const* d_in, const int* in_sizes, int n_in,
                              void* d_out, int out_size, void* d_ws, size_t ws_size,
                              hipStream_t stream)
{
  const float* obs  = (const float*)d_in[0];
  const float* hxs  = (const float*)d_in[1];
  const float* cxs  = (const float*)d_in[2];
  const float* W1   = (const float*)d_in[3];
  const float* b1   = (const float*)d_in[4];
  const float* W2   = (const float*)d_in[5];
  const float* b2   = (const float*)d_in[6];
  const float* W_ih = (const float*)d_in[7];
  const float* W_hh = (const float*)d_in[8];
  const float* b_ih = (const float*)d_in[9];
  const float* b_hh = (const float*)d_in[10];
  const float* ln_g = (const float*)d_in[11];
  const float* ln_b = (const float*)d_in[12];
  const float* Wa   = (const float*)d_in[13];
  const float* ba   = (const float*)d_in[14];
  const float* Wc   = (const float*)d_in[15];
  const float* bc   = (const float*)d_in[16];

  char* ws = (char*)d_ws;
  size_t off = 0;
  auto alloc = [&](size_t bytes)->char*{
    char* p = ws + off;
    off = (off + bytes + 255) & ~(size_t)255;
    return p;
  };
  // ---- fixed buffers ----
  unsigned short* W1_b    = (unsigned short*)alloc((size_t)NE*ND*2);
  unsigned short* W2_b    = (unsigned short*)alloc((size_t)NE*NE*2);
  unsigned short* Wih_b   = (unsigned short*)alloc((size_t)4*NH*NE*2);
  unsigned short* Whead_b = (unsigned short*)alloc((size_t)65*NH*2);
  float* bias_heads       = (float*)alloc(65*4);
  float* bias_xg          = (float*)alloc(4096*4);
  unsigned short* outln_b = (unsigned short*)alloc((size_t)NB*NT*NH*2);   // 32 MB
  float* h_bufs           = (float*)alloc((size_t)2*NB*NH*4);
  float* c_buf            = (float*)alloc((size_t)NB*NH*4);
  float* partials         = (float*)alloc((size_t)1024*2*4);
  const size_t fixedEnd = off;

  // ---- pick chunk size (largest that fits) ----
  int lg = -1;
  for (int L = 9; L >= 4; --L){
    size_t Mc = (size_t)NB << L;
    size_t per = Mc*ND*2 + 2*(Mc*NE*2) + Mc*4096*2 + Mc*NH*4 + 6*256;
    if (fixedEnd + per <= ws_size){ lg = L; break; }
  }
  if (lg < 0){ sentinel_kernel<<<1,1,0,stream>>>((float*)d_out); return; }
  const int Tc = 1 << lg;
  const int Mc = NB << lg;
  const int nChunks = NT >> lg;

  unsigned short* obs_c  = (unsigned short*)alloc((size_t)Mc*ND*2);
  unsigned short* enc1_c = (unsigned short*)alloc((size_t)Mc*NE*2);
  unsigned short* enc2_c = (unsigned short*)alloc((size_t)Mc*NE*2);
  unsigned short* xg_c   = (unsigned short*)alloc((size_t)Mc*4096*2);
  float* hist_c          = (float*)alloc((size_t)Mc*NH*4);

  float* o = (float*)d_out;
  float* oLogits = o;
  float* oValues = o + (size_t)NB*NT*64;
  float* oH  = oValues + NB*NT;
  float* oC  = oH + NB*NH;
  float* oAr = oC + NB*NH;
  float* oTar= oAr + 1;

  // ---- one-time weight prep ----
  f2b_kernel<<<256 ,256,0,stream>>>(W1,   W1_b,  (long)NE*ND);
  f2b_kernel<<<512 ,256,0,stream>>>(W2,   W2_b,  (long)NE*NE);
  f2b_kernel<<<1024,256,0,stream>>>(W_ih, Wih_b, (long)4*NH*NE);
  prep_kernel<<<260,256,0,stream>>>(Wa, Wc, ba, bc, b_ih, b_hh, Whead_b, bias_heads, bias_xg);
  init_hc<<<128,256,0,stream>>>(hxs, cxs, h_bufs, c_buf);

  // ---- chunked pipeline ----
  for (int c = 0; c < nChunks; ++c){
    int t0 = c << lg, t1 = t0 + Tc;
    f2b_obs_chunk<<<512,256,0,stream>>>(obs, obs_c, lg, t0);
    gemm_bt<1,0><<<dim3(Mc/128,8) ,256,0,stream>>>(obs_c,  W1_b,  b1,      enc1_c, nullptr, nullptr, ND, NE, NE);
    gemm_bt<1,0><<<dim3(Mc/128,8) ,256,0,stream>>>(enc1_c, W2_b,  b2,      enc2_c, nullptr, nullptr, NE, NE, NE);
    gemm_bt<0,0><<<dim3(Mc/128,32),256,0,stream>>>(enc2_c, Wih_b, bias_xg, xg_c,   nullptr, nullptr, NE, 4096, 4096);

    int a_t0 = t0, a_t1 = t1, a_Tc = Tc;
    void* args[] = { (void*)&xg_c, (void*)&W_hh, (void*)&h_bufs, (void*)&c_buf,
                     (void*)&hist_c, (void*)&oH, (void*)&oC,
                     (void*)&a_t0, (void*)&a_t1, (void*)&a_Tc };
    hipError_t ce = hipLaunchCooperativeKernel((const void*)lstm_chunk, dim3(256), dim3(256), args, 0u, stream);
    if (ce != hipSuccess){
      for (int t = t0; t < t1; ++t)
        lstm_step<<<256,256,0,stream>>>(xg_c, W_hh, h_bufs, c_buf, hist_c, oH, oC, t, t0, Tc);
    }
    ln_chunk<<<Mc,256,0,stream>>>(hist_c, ln_g, ln_b, outln_b, lg, t0);
  }

  // ---- heads + losses ----
  gemm_bt<0,1><<<dim3(128,1),256,0,stream>>>(outln_b, Whead_b, bias_heads, nullptr, oLogits, oValues, NH, 128, 65);
  loss_partial<<<1024,256,0,stream>>>(outln_b, partials);
  loss_final<<<1,256,0,stream>>>(partials, oAr, oTar);
}

// Round 3
// 8912.105 us; speedup vs baseline: 2.6593x; 2.6593x over previous
//
#include <hip/hip_runtime.h>

typedef __attribute__((ext_vector_type(8))) short bf16x8;
typedef __attribute__((ext_vector_type(8))) unsigned short u16x8;
typedef __attribute__((ext_vector_type(4))) unsigned short u16x4;
typedef __attribute__((ext_vector_type(4))) float f32x4;
typedef __attribute__((ext_vector_type(4))) int i32x4;

#define NB 32
#define NT 512
#define ND 256
#define NE 1024
#define NH 1024

__device__ __forceinline__ float bf2f(unsigned short u){
  union { unsigned int i; float f; } w; w.i = ((unsigned int)u) << 16; return w.f;
}
__device__ __forceinline__ unsigned short f2bf(float f){
  union { float f; unsigned int i; } w; w.f = f;
  unsigned int r = (w.i >> 16) & 1u;
  return (unsigned short)((w.i + 0x7fffu + r) >> 16);
}

// ---- cache-bypass (coherent-point) memory ops: sc0 sc1 => bypass L1/L2, hit L3/HBM ----
__device__ __forceinline__ f32x4 bypass_load_f32x4(const float* p){
  f32x4 r;
  asm volatile("global_load_dwordx4 %0, %1, off sc0 sc1" : "=v"(r) : "v"(p) : "memory");
  return r;  // caller must s_waitcnt before use
}
__device__ __forceinline__ i32x4 bypass_load_i32x4_wait(const int* p){
  i32x4 r;
  asm volatile("global_load_dwordx4 %0, %1, off sc0 sc1\n\ts_waitcnt vmcnt(0)"
               : "=v"(r) : "v"(p) : "memory");
  return r;
}
__device__ __forceinline__ void bypass_store_f32(float* p, float v){
  asm volatile("global_store_dword %0, %1, off sc0 sc1" :: "v"(p), "v"(v) : "memory");
}
__device__ __forceinline__ void bypass_store_i32(int* p, int v){
  asm volatile("global_store_dword %0, %1, off sc0 sc1" :: "v"(p), "v"(v) : "memory");
}

// ---------------- conversion / prep ----------------
__global__ void f2b_kernel(const float* __restrict__ src, unsigned short* __restrict__ dst, long n){
  long i = (long)blockIdx.x*blockDim.x + threadIdx.x;
  long stride = (long)gridDim.x*blockDim.x;
  for (; i < n; i += stride) dst[i] = f2bf(src[i]);
}

__global__ void f2b_obs_chunk(const float* __restrict__ obs, unsigned short* __restrict__ dst,
                              int lgTc, int t0){
  const int Tc = 1 << lgTc;
  const long n = (long)NB * Tc * ND;
  long i = (long)blockIdx.x*blockDim.x + threadIdx.x;
  long stride = (long)gridDim.x*blockDim.x;
  for (; i < n; i += stride){
    long lr = i >> 8;
    int col = (int)(i & 255);
    long gr = (lr >> lgTc)*NT + t0 + (lr & (Tc-1));
    dst[i] = f2bf(obs[gr*ND + col]);
  }
}

__global__ void prep_kernel(const float* __restrict__ Wa, const float* __restrict__ Wc,
                            const float* __restrict__ ba, const float* __restrict__ bc,
                            const float* __restrict__ b_ih, const float* __restrict__ b_hh,
                            unsigned short* __restrict__ Whead, float* __restrict__ bias_heads,
                            float* __restrict__ bias_xg){
  int i = blockIdx.x*blockDim.x + threadIdx.x;
  int stride = gridDim.x*blockDim.x;
  for (int v = i; v < 65*1024; v += stride){
    int n = v >> 10, k = v & 1023;
    float w = (n < 64) ? Wa[v] : Wc[k];
    Whead[v] = f2bf(w);
  }
  for (int v = i; v < 4096; v += stride) bias_xg[v] = b_ih[v] + b_hh[v];
  for (int v = i; v < 65; v += stride) bias_heads[v] = (v < 64) ? ba[v] : bc[0];
}

__global__ void init_hc(const float* __restrict__ hxs, const float* __restrict__ cxs,
                        float* __restrict__ h_bufs, float* __restrict__ c_buf,
                        int* __restrict__ flags){
  int i = blockIdx.x*blockDim.x + threadIdx.x;
  if (i < NB*NH){ h_bufs[i] = hxs[i]; c_buf[i] = cxs[i]; }
  if (i < 256) flags[i] = 0;
}

__global__ void sentinel_kernel(float* __restrict__ out){ out[0] = 1.0e6f; }

// ---------------- bf16 MFMA GEMM: C[M,N] = act(A[M,K] @ Bw[N,K]^T + bias) ----------------
template<int SILU, int HEADS>
__global__ __launch_bounds__(256)
void gemm_bt(const unsigned short* __restrict__ A, const unsigned short* __restrict__ Bw,
             const float* __restrict__ bias, unsigned short* __restrict__ C,
             float* __restrict__ oLogits, float* __restrict__ oValues,
             int K, int N, int Nreal)
{
  __shared__ __align__(16) unsigned short As[128*40];
  __shared__ __align__(16) unsigned short Bs[128*40];
  const int tid = threadIdx.x;
  const int lane = tid & 63;
  const int wave = tid >> 6;
  const int wm = wave >> 1, wn = wave & 1;
  const int m0 = blockIdx.x * 128, n0 = blockIdx.y * 128;
  f32x4 acc[4][4];
#pragma unroll
  for (int i=0;i<4;i++)
#pragma unroll
    for (int j=0;j<4;j++){ f32x4 z = {0.f,0.f,0.f,0.f}; acc[i][j] = z; }
  const int rowL = tid >> 1;
  const int kL = (tid & 1) * 16;
  const int fr = lane & 15;
  const int kf = (lane >> 4) * 8;

  for (int k0 = 0; k0 < K; k0 += 32) {
    u16x8 va0 = *(const u16x8*)&A[(size_t)(m0+rowL)*K + k0 + kL];
    u16x8 va1 = *(const u16x8*)&A[(size_t)(m0+rowL)*K + k0 + kL + 8];
    u16x8 vb0, vb1;
    int nrow = n0 + rowL;
    if (nrow < Nreal) {
      vb0 = *(const u16x8*)&Bw[(size_t)nrow*K + k0 + kL];
      vb1 = *(const u16x8*)&Bw[(size_t)nrow*K + k0 + kL + 8];
    } else {
#pragma unroll
      for (int q=0;q<8;q++){ vb0[q]=0; vb1[q]=0; }
    }
    __syncthreads();
    *(u16x8*)&As[rowL*40 + kL]     = va0;
    *(u16x8*)&As[rowL*40 + kL + 8] = va1;
    *(u16x8*)&Bs[rowL*40 + kL]     = vb0;
    *(u16x8*)&Bs[rowL*40 + kL + 8] = vb1;
    __syncthreads();
    bf16x8 af[4], bfr[4];
#pragma unroll
    for (int f=0; f<4; f++){
      af[f]  = *(const bf16x8*)&As[(wm*64 + f*16 + fr)*40 + kf];
      bfr[f] = *(const bf16x8*)&Bs[(wn*64 + f*16 + fr)*40 + kf];
    }
#pragma unroll
    for (int i=0;i<4;i++)
#pragma unroll
      for (int j=0;j<4;j++)
        acc[i][j] = __builtin_amdgcn_mfma_f32_16x16x32_bf16(af[i], bfr[j], acc[i][j], 0, 0, 0);
  }

  const int mb = (lane >> 4) * 4;
  const int nb = lane & 15;
#pragma unroll
  for (int i=0;i<4;i++)
#pragma unroll
    for (int j=0;j<4;j++)
#pragma unroll
      for (int r=0;r<4;r++){
        int m = m0 + wm*64 + i*16 + mb + r;
        int n = n0 + wn*64 + j*16 + nb;
        if (HEADS && n >= Nreal) continue;
        float v = acc[i][j][r] + bias[n];
        if (SILU) v = v / (1.f + expf(-v));
        if (!HEADS) {
          C[(size_t)m*N + n] = f2bf(v);
        } else {
          if (n < 64) oLogits[(size_t)m*64 + n] = v;
          else if (n == 64) oValues[m] = v;
        }
      }
}

// ---------------- LSTM: persistent kernel, custom bypass barrier ----------------
// 256 WGs x 512 thr. WG wg owns hidden units wg*4..+3 (16 gate rows), fp32 W slice in LDS (64KB).
// Wave wv (0..7) owns batches wv*4..+3. Lane owns k in {lane*4 + 256*j : j=0..3}.
// h exchanged via sc0sc1 (L2-bypass) loads/stores; barrier = per-WG flag + wave-0 poll.
#define ISSUE_HQ(J, DST) \
  { _Pragma("unroll") for (int bb=0;bb<4;bb++) \
      DST[bb] = bypass_load_f32x4(hb + (size_t)(wv*4+bb)*NH + (J)*256 + kbase); }

#define COMPUTE_J(J, CUR) \
  { _Pragma("unroll") for (int r=0;r<16;r++){ \
      f32x4 wq = *(const f32x4*)&Wl[r*1024 + (J)*256 + kbase]; \
      _Pragma("unroll") for (int bb=0;bb<4;bb++) \
        acc[r][bb] = fmaf(wq[0],CUR[bb][0], fmaf(wq[1],CUR[bb][1], \
                     fmaf(wq[2],CUR[bb][2], fmaf(wq[3],CUR[bb][3], acc[r][bb])))); } }

__global__ __launch_bounds__(512)
void lstm_chunk(const unsigned short* __restrict__ xg, const float* __restrict__ Whh,
                float* __restrict__ h_bufs, float* __restrict__ c_buf,
                float* __restrict__ hist, float* __restrict__ dh, float* __restrict__ dc,
                int* __restrict__ flags,
                int t0, int t1, int Tc)
{
  __shared__ __align__(16) float Wl[16*1024];   // 64 KB, row-major [16][1024]
  const int wg = blockIdx.x;
  const int n0w = wg * 4;
  const int tid = threadIdx.x;
  const int lane = tid & 63;
  const int wv = tid >> 6;
  const int kbase = lane * 4;

  for (int i = tid; i < 16*1024; i += 512) {
    int r = i >> 10, k = i & 1023;
    Wl[i] = Whh[(size_t)((r>>2)*NH + n0w + (r&3))*NH + k];
  }

  // epilogue ownership: lanes 0..15 of each wave
  int bE=0, jE=0, nE=0, blE=0;
  float c_reg = 0.f, h_keep = 0.f;
  if (lane < 16) {
    blE = lane >> 2; jE = lane & 3;
    bE = wv*4 + blE; nE = n0w + jE;
    c_reg = c_buf[bE*NH + nE];
  }
  __syncthreads();

  for (int t = t0; t < t1; t++) {
    const float* hb = h_bufs + (size_t)(t & 1) * (NB*NH);
    float acc[16][4];
#pragma unroll
    for (int r=0;r<16;r++)
#pragma unroll
      for (int bb=0;bb<4;bb++) acc[r][bb] = 0.f;

    f32x4 hqA[4], hqB[4];
    ISSUE_HQ(0, hqA)
    ISSUE_HQ(1, hqB)
    asm volatile("s_waitcnt vmcnt(4)" ::: "memory"); __builtin_amdgcn_sched_barrier(0);
    COMPUTE_J(0, hqA)
    ISSUE_HQ(2, hqA)
    asm volatile("s_waitcnt vmcnt(4)" ::: "memory"); __builtin_amdgcn_sched_barrier(0);
    COMPUTE_J(1, hqB)
    ISSUE_HQ(3, hqB)
    asm volatile("s_waitcnt vmcnt(4)" ::: "memory"); __builtin_amdgcn_sched_barrier(0);
    COMPUTE_J(2, hqA)
    asm volatile("s_waitcnt vmcnt(0)" ::: "memory"); __builtin_amdgcn_sched_barrier(0);
    COMPUTE_J(3, hqB)

    // k-reduction across the 64 lanes of each wave
#pragma unroll
    for (int r=0;r<16;r++)
#pragma unroll
      for (int bb=0;bb<4;bb++){
        float v = acc[r][bb];
        v += __shfl_xor(v, 1);
        v += __shfl_xor(v, 2);
        v += __shfl_xor(v, 4);
        v += __shfl_xor(v, 8);
        v += __shfl_xor(v, 16);
        v += __shfl_xor(v, 32);
        acc[r][bb] = v;
      }

    if (lane < 16) {
      int tl = t - t0;
      size_t xbase = ((size_t)bE*Tc + tl)*4096;
      float gi = acc[ 0+jE][blE] + bf2f(xg[xbase + 0*NH + nE]);
      float gf = acc[ 4+jE][blE] + bf2f(xg[xbase + 1*NH + nE]);
      float gg = acc[ 8+jE][blE] + bf2f(xg[xbase + 2*NH + nE]);
      float go = acc[12+jE][blE] + bf2f(xg[xbase + 3*NH + nE]);
      float iv = 1.f/(1.f+expf(-gi));
      float fv = 1.f/(1.f+expf(-gf));
      float gv = tanhf(gg);
      float ov = 1.f/(1.f+expf(-go));
      float c = fv*c_reg + iv*gv;
      float h = ov*tanhf(c);
      c_reg = c; h_keep = h;
      bypass_store_f32(h_bufs + (size_t)((t+1)&1)*(NB*NH) + bE*NH + nE, h);
      hist[((size_t)bE*Tc + tl)*NH + nE] = h;      // normal store: consumed after kernel boundary
    }
    // drain own stores, then WG-wide arrival
    asm volatile("s_waitcnt vmcnt(0)" ::: "memory");
    __syncthreads();
    if (tid < 64){
      if (tid == 0) bypass_store_i32(&flags[wg], t+1);
      const int target = t+1;
      while (true){
        i32x4 f = bypass_load_i32x4_wait(&flags[tid*4]);
        int m0_ = min(min(f[0],f[1]), min(f[2],f[3]));
#pragma unroll
        for (int off=32; off; off>>=1) m0_ = min(m0_, __shfl_xor(m0_, off));
        if (m0_ >= target) break;
        __builtin_amdgcn_s_sleep(1);
      }
    }
    __syncthreads();
  }
  if (lane < 16) {
    c_buf[bE*NH + nE] = c_reg;
    if (t1 == NT){ dh[bE*NH + nE] = h_keep; dc[bE*NH + nE] = c_reg; }
  }
}

// ---------------- LSTM: per-step fallback (regular launches, 256 thr) ----------------
__global__ __launch_bounds__(256)
void lstm_step(const unsigned short* __restrict__ xg, const float* __restrict__ Whh,
               float* __restrict__ h_bufs, float* __restrict__ c_buf,
               float* __restrict__ hist, float* __restrict__ dh, float* __restrict__ dc,
               int t, int t0, int Tc)
{
  const int wg = blockIdx.x;
  const int n0w = wg * 4;
  const int tid = threadIdx.x;
  const int kc = tid & 31, bg = tid >> 5;
  const float* hb = h_bufs + (t & 1) * (NB*NH);
  float acc[16][4];
#pragma unroll
  for (int r=0;r<16;r++)
#pragma unroll
    for (int bb=0;bb<4;bb++) acc[r][bb] = 0.f;

#pragma unroll
  for (int kk=0; kk<8; kk++){
    const int k4 = kc*32 + kk*4;
    f32x4 hq[4];
#pragma unroll
    for (int bb=0;bb<4;bb++)
      hq[bb] = *(const f32x4*)&hb[(bg*4+bb)*NH + k4];
#pragma unroll
    for (int r=0;r<16;r++){
      f32x4 wq = *(const f32x4*)&Whh[(size_t)((r>>2)*NH + n0w + (r&3))*NH + k4];
#pragma unroll
      for (int bb=0;bb<4;bb++)
        acc[r][bb] = fmaf(wq[0],hq[bb][0], fmaf(wq[1],hq[bb][1],
                     fmaf(wq[2],hq[bb][2], fmaf(wq[3],hq[bb][3], acc[r][bb]))));
    }
  }
#pragma unroll
  for (int r=0;r<16;r++)
#pragma unroll
    for (int bb=0;bb<4;bb++){
      float v = acc[r][bb];
      v += __shfl_xor(v, 1);
      v += __shfl_xor(v, 2);
      v += __shfl_xor(v, 4);
      v += __shfl_xor(v, 8);
      v += __shfl_xor(v, 16);
      acc[r][bb] = v;
    }
  if (kc < 16) {
    int blE = kc >> 2, jE = kc & 3;
    int bE = bg*4 + blE, nE = n0w + jE;
    int tl = t - t0;
    size_t xbase = ((size_t)bE*Tc + tl)*4096;
    float gi = acc[ 0+jE][blE] + bf2f(xg[xbase + 0*NH + nE]);
    float gf = acc[ 4+jE][blE] + bf2f(xg[xbase + 1*NH + nE]);
    float gg = acc[ 8+jE][blE] + bf2f(xg[xbase + 2*NH + nE]);
    float go = acc[12+jE][blE] + bf2f(xg[xbase + 3*NH + nE]);
    float iv = 1.f/(1.f+expf(-gi));
    float fv = 1.f/(1.f+expf(-gf));
    float gv = tanhf(gg);
    float ov = 1.f/(1.f+expf(-go));
    float c_prev = c_buf[bE*NH + nE];
    float c = fv*c_prev + iv*gv;
    float h = ov*tanhf(c);
    c_buf[bE*NH + nE] = c;
    h_bufs[((t+1)&1)*(NB*NH) + bE*NH + nE] = h;
    hist[((size_t)bE*Tc + tl)*NH + nE] = h;
    if (t == NT-1){ dh[bE*NH + nE] = h; dc[bE*NH + nE] = c; }
  }
}

// ---------------- LayerNorm (chunked rows) -> bf16 out_ln (global rows) ----------------
__global__ __launch_bounds__(256)
void ln_chunk(const float* __restrict__ X, const float* __restrict__ gam, const float* __restrict__ bet,
              unsigned short* __restrict__ Y, int lgTc, int t0)
{
  const int row = blockIdx.x;
  const int Tc = 1 << lgTc;
  const int bl = row >> lgTc, tl = row & (Tc-1);
  const long grow = (long)bl*NT + t0 + tl;
  const int tid = threadIdx.x;
  const float* x = X + (size_t)row*NH;
  f32x4 v = *(const f32x4*)&x[tid*4];
  float s = v[0]+v[1]+v[2]+v[3];
  s += __shfl_xor(s,1); s += __shfl_xor(s,2); s += __shfl_xor(s,4);
  s += __shfl_xor(s,8); s += __shfl_xor(s,16); s += __shfl_xor(s,32);
  __shared__ float red[8];
  if ((tid & 63) == 0) red[tid >> 6] = s;
  __syncthreads();
  float mean = (red[0]+red[1]+red[2]+red[3]) * (1.0f/NH);
  float d0 = v[0]-mean, d1 = v[1]-mean, d2 = v[2]-mean, d3 = v[3]-mean;
  float q = d0*d0 + d1*d1 + d2*d2 + d3*d3;
  q += __shfl_xor(q,1); q += __shfl_xor(q,2); q += __shfl_xor(q,4);
  q += __shfl_xor(q,8); q += __shfl_xor(q,16); q += __shfl_xor(q,32);
  if ((tid & 63) == 0) red[4 + (tid >> 6)] = q;
  __syncthreads();
  float var = (red[4]+red[5]+red[6]+red[7]) * (1.0f/NH);
  float rs = 1.f / sqrtf(var + 1e-5f);
  f32x4 gm = *(const f32x4*)&gam[tid*4];
  f32x4 bt = *(const f32x4*)&bet[tid*4];
  u16x4 ov;
  ov[0] = f2bf(d0*rs*gm[0] + bt[0]);
  ov[1] = f2bf(d1*rs*gm[1] + bt[1]);
  ov[2] = f2bf(d2*rs*gm[2] + bt[2]);
  ov[3] = f2bf(d3*rs*gm[3] + bt[3]);
  *(u16x4*)&Y[(size_t)grow*NH + tid*4] = ov;
}

// ---------------- ar / tar losses ----------------
__global__ __launch_bounds__(256)
void loss_partial(const unsigned short* __restrict__ Yu, float* __restrict__ partials)
{
  float ar = 0.f, tar = 0.f;
  long stride = (long)gridDim.x*256;
  for (long vv = (long)blockIdx.x*256 + threadIdx.x; vv < 2097152; vv += stride){
    long i = vv*8;
    int t = (int)((i >> 10) & 511);
    u16x8 y = *(const u16x8*)&Yu[i];
    float x[8];
#pragma unroll
    for (int q=0;q<8;q++){ x[q] = bf2f(y[q]); ar += x[q]*x[q]; }
    if (t > 0){
      u16x8 yp = *(const u16x8*)&Yu[i - 1024];
#pragma unroll
      for (int q=0;q<8;q++){ float d = x[q] - bf2f(yp[q]); tar += d*d; }
    }
  }
  ar += __shfl_xor(ar,1); ar += __shfl_xor(ar,2); ar += __shfl_xor(ar,4);
  ar += __shfl_xor(ar,8); ar += __shfl_xor(ar,16); ar += __shfl_xor(ar,32);
  tar += __shfl_xor(tar,1); tar += __shfl_xor(tar,2); tar += __shfl_xor(tar,4);
  tar += __shfl_xor(tar,8); tar += __shfl_xor(tar,16); tar += __shfl_xor(tar,32);
  __shared__ float red[16];
  int w = threadIdx.x >> 6;
  if ((threadIdx.x & 63) == 0){ red[w] = ar; red[8+w] = tar; }
  __syncthreads();
  if (threadIdx.x == 0){
    partials[blockIdx.x*2]   = red[0]+red[1]+red[2]+red[3];
    partials[blockIdx.x*2+1] = red[8]+red[9]+red[10]+red[11];
  }
}

__global__ __launch_bounds__(256)
void loss_final(const float* __restrict__ partials, float* __restrict__ oAr, float* __restrict__ oTar){
  double sa = 0.0, st = 0.0;
  for (int i = threadIdx.x; i < 1024; i += 256){ sa += (double)partials[2*i]; st += (double)partials[2*i+1]; }
  for (int m=1;m<64;m<<=1){ sa += __shfl_xor(sa, m); st += __shfl_xor(st, m); }
  __shared__ double rd[8];
  int w = threadIdx.x >> 6;
  if ((threadIdx.x & 63) == 0){ rd[w] = sa; rd[4+w] = st; }
  __syncthreads();
  if (threadIdx.x == 0){
    double a  = rd[0]+rd[1]+rd[2]+rd[3];
    double tt = rd[4]+rd[5]+rd[6]+rd[7];
    oAr[0]  = (float)(a  / 16777216.0 * 0.01);
    oTar[0] = (float)(tt / 16744448.0 * 0.01);
  }
}

// ---------------- launch ----------------
extern "C" void kernel_launch(void* const* d_in, const int* in_sizes, int n_in,
                              void* d_out, int out_size, void* d_ws, size_t ws_size,
                              hipStream_t stream)
{
  const float* obs  = (const float*)d_in[0];
  const float* hxs  = (const float*)d_in[1];
  const float* cxs  = (const float*)d_in[2];
  const float* W1   = (const float*)d_in[3];
  const float* b1   = (const float*)d_in[4];
  const float* W2   = (const float*)d_in[5];
  const float* b2   = (const float*)d_in[6];
  const float* W_ih = (const float*)d_in[7];
  const float* W_hh = (const float*)d_in[8];
  const float* b_ih = (const float*)d_in[9];
  const float* b_hh = (const float*)d_in[10];
  const float* ln_g = (const float*)d_in[11];
  const float* ln_b = (const float*)d_in[12];
  const float* Wa   = (const float*)d_in[13];
  const float* ba   = (const float*)d_in[14];
  const float* Wc   = (const float*)d_in[15];
  const float* bc   = (const float*)d_in[16];

  char* ws = (char*)d_ws;
  size_t off = 0;
  auto alloc = [&](size_t bytes)->char*{
    char* p = ws + off;
    off = (off + bytes + 255) & ~(size_t)255;
    return p;
  };
  // ---- fixed buffers ----
  unsigned short* W1_b    = (unsigned short*)alloc((size_t)NE*ND*2);
  unsigned short* W2_b    = (unsigned short*)alloc((size_t)NE*NE*2);
  unsigned short* Wih_b   = (unsigned short*)alloc((size_t)4*NH*NE*2);
  unsigned short* Whead_b = (unsigned short*)alloc((size_t)65*NH*2);
  float* bias_heads       = (float*)alloc(65*4);
  float* bias_xg          = (float*)alloc(4096*4);
  unsigned short* outln_b = (unsigned short*)alloc((size_t)NB*NT*NH*2);   // 32 MB
  float* h_bufs           = (float*)alloc((size_t)2*NB*NH*4);
  float* c_buf            = (float*)alloc((size_t)NB*NH*4);
  int*   flags            = (int*)alloc(256*4);
  float* partials         = (float*)alloc((size_t)1024*2*4);
  const size_t fixedEnd = off;

  // ---- pick chunk size (largest that fits) ----
  int lg = -1;
  for (int L = 9; L >= 4; --L){
    size_t Mc = (size_t)NB << L;
    size_t per = Mc*ND*2 + 2*(Mc*NE*2) + Mc*4096*2 + Mc*NH*4 + 6*256;
    if (fixedEnd + per <= ws_size){ lg = L; break; }
  }
  if (lg < 0){ sentinel_kernel<<<1,1,0,stream>>>((float*)d_out); return; }
  const int Tc = 1 << lg;
  const int Mc = NB << lg;
  const int nChunks = NT >> lg;

  unsigned short* obs_c  = (unsigned short*)alloc((size_t)Mc*ND*2);
  unsigned short* enc1_c = (unsigned short*)alloc((size_t)Mc*NE*2);
  unsigned short* enc2_c = (unsigned short*)alloc((size_t)Mc*NE*2);
  unsigned short* xg_c   = (unsigned short*)alloc((size_t)Mc*4096*2);
  float* hist_c          = (float*)alloc((size_t)Mc*NH*4);

  float* o = (float*)d_out;
  float* oLogits = o;
  float* oValues = o + (size_t)NB*NT*64;
  float* oH  = oValues + NB*NT;
  float* oC  = oH + NB*NH;
  float* oAr = oC + NB*NH;
  float* oTar= oAr + 1;

  // ---- one-time weight prep ----
  f2b_kernel<<<256 ,256,0,stream>>>(W1,   W1_b,  (long)NE*ND);
  f2b_kernel<<<512 ,256,0,stream>>>(W2,   W2_b,  (long)NE*NE);
  f2b_kernel<<<1024,256,0,stream>>>(W_ih, Wih_b, (long)4*NH*NE);
  prep_kernel<<<260,256,0,stream>>>(Wa, Wc, ba, bc, b_ih, b_hh, Whead_b, bias_heads, bias_xg);
  init_hc<<<128,256,0,stream>>>(hxs, cxs, h_bufs, c_buf, flags);

  // ---- chunked pipeline ----
  for (int c = 0; c < nChunks; ++c){
    int t0 = c << lg, t1 = t0 + Tc;
    f2b_obs_chunk<<<512,256,0,stream>>>(obs, obs_c, lg, t0);
    gemm_bt<1,0><<<dim3(Mc/128,8) ,256,0,stream>>>(obs_c,  W1_b,  b1,      enc1_c, nullptr, nullptr, ND, NE, NE);
    gemm_bt<1,0><<<dim3(Mc/128,8) ,256,0,stream>>>(enc1_c, W2_b,  b2,      enc2_c, nullptr, nullptr, NE, NE, NE);
    gemm_bt<0,0><<<dim3(Mc/128,32),256,0,stream>>>(enc2_c, Wih_b, bias_xg, xg_c,   nullptr, nullptr, NE, 4096, 4096);

    int a_t0 = t0, a_t1 = t1, a_Tc = Tc;
    void* args[] = { (void*)&xg_c, (void*)&W_hh, (void*)&h_bufs, (void*)&c_buf,
                     (void*)&hist_c, (void*)&oH, (void*)&oC, (void*)&flags,
                     (void*)&a_t0, (void*)&a_t1, (void*)&a_Tc };
    hipError_t ce = hipLaunchCooperativeKernel((const void*)lstm_chunk, dim3(256), dim3(512), args, 0u, stream);
    if (ce != hipSuccess){
      for (int t = t0; t < t1; ++t)
        lstm_step<<<256,256,0,stream>>>(xg_c, W_hh, h_bufs, c_buf, hist_c, oH, oC, t, t0, Tc);
    }
    ln_chunk<<<Mc,256,0,stream>>>(hist_c, ln_g, ln_b, outln_b, lg, t0);
  }

  // ---- heads + losses ----
  gemm_bt<0,1><<<dim3(128,1),256,0,stream>>>(outln_b, Whead_b, bias_heads, nullptr, oLogits, oValues, NH, 128, 65);
  loss_partial<<<1024,256,0,stream>>>(outln_b, partials);
  loss_final<<<1,256,0,stream>>>(partials, oAr, oTar);
}

// Round 4
// 8518.123 us; speedup vs baseline: 2.7823x; 1.0463x over previous
//
#include <hip/hip_runtime.h>

typedef __attribute__((ext_vector_type(8))) short bf16x8;
typedef __attribute__((ext_vector_type(8))) unsigned short u16x8;
typedef __attribute__((ext_vector_type(4))) unsigned short u16x4;
typedef __attribute__((ext_vector_type(4))) float f32x4;

#define NB 32
#define NT 512
#define ND 256
#define NE 1024
#define NH 1024

__device__ __forceinline__ float bf2f(unsigned short u){
  union { unsigned int i; float f; } w; w.i = ((unsigned int)u) << 16; return w.f;
}
__device__ __forceinline__ unsigned short f2bf(float f){
  union { float f; unsigned int i; } w; w.f = f;
  unsigned int r = (w.i >> 16) & 1u;
  return (unsigned short)((w.i + 0x7fffu + r) >> 16);
}

// ---- cache-bypass (coherence-point) memory ops ----
__device__ __forceinline__ f32x4 bypass_load_f32x4(const float* p){
  f32x4 r;
  asm volatile("global_load_dwordx4 %0, %1, off sc0 sc1" : "=v"(r) : "v"(p) : "memory");
  return r;  // caller must s_waitcnt before use
}
__device__ __forceinline__ int bypass_load_i32(const int* p){
  int r;
  asm volatile("global_load_dword %0, %1, off sc0 sc1\n\ts_waitcnt vmcnt(0)"
               : "=v"(r) : "v"(p) : "memory");
  return r;
}
__device__ __forceinline__ void bypass_store_f32x4(float* p, f32x4 v){
  asm volatile("global_store_dwordx4 %0, %1, off sc0 sc1" :: "v"(p), "v"(v) : "memory");
}

// ---- global_load_lds width=16 (m97 pattern) ----
__device__ __forceinline__ void gload_lds16(const void* g, void* l){
  __builtin_amdgcn_global_load_lds(
      (const __attribute__((address_space(1))) void*)g,
      (__attribute__((address_space(3))) void*)l, 16, 0, 0);
}

// ---------------- conversion / prep ----------------
__global__ void f2b_kernel(const float* __restrict__ src, unsigned short* __restrict__ dst, long n){
  long i = (long)blockIdx.x*blockDim.x + threadIdx.x;
  long stride = (long)gridDim.x*blockDim.x;
  for (; i < n; i += stride) dst[i] = f2bf(src[i]);
}

__global__ void f2b_obs_chunk(const float* __restrict__ obs, unsigned short* __restrict__ dst,
                              int lgTc, int t0){
  const int Tc = 1 << lgTc;
  const long n = (long)NB * Tc * ND;
  long i = (long)blockIdx.x*blockDim.x + threadIdx.x;
  long stride = (long)gridDim.x*blockDim.x;
  for (; i < n; i += stride){
    long lr = i >> 8;
    int col = (int)(i & 255);
    long gr = (lr >> lgTc)*NT + t0 + (lr & (Tc-1));
    dst[i] = f2bf(obs[gr*ND + col]);
  }
}

__global__ void prep_kernel(const float* __restrict__ Wa, const float* __restrict__ Wc,
                            const float* __restrict__ ba, const float* __restrict__ bc,
                            const float* __restrict__ b_ih, const float* __restrict__ b_hh,
                            unsigned short* __restrict__ Whead, float* __restrict__ bias_heads,
                            float* __restrict__ bias_xg){
  int i = blockIdx.x*blockDim.x + threadIdx.x;
  int stride = gridDim.x*blockDim.x;
  for (int v = i; v < 128*1024; v += stride){
    int n = v >> 10, k = v & 1023;
    float w = (n < 64) ? Wa[v] : (n == 64 ? Wc[k] : 0.f);
    Whead[v] = f2bf(w);
  }
  for (int v = i; v < 4096; v += stride) bias_xg[v] = b_ih[v] + b_hh[v];
  for (int v = i; v < 65; v += stride) bias_heads[v] = (v < 64) ? ba[v] : bc[0];
}

__global__ void init_hc(const float* __restrict__ hxs, const float* __restrict__ cxs,
                        float* __restrict__ h_bufs, float* __restrict__ c_buf,
                        int* __restrict__ cnt){
  int i = blockIdx.x*blockDim.x + threadIdx.x;
  if (i < NB*NH){ h_bufs[i] = hxs[i]; c_buf[i] = cxs[i]; }
  if (i == 0) cnt[0] = 0;
}

__global__ void sentinel_kernel(float* __restrict__ out){ out[0] = 1.0e6f; }

// ---------------- bf16 MFMA GEMM: C[M,N] = act(A[M,K] @ Bw[N,K]^T + bias) ----------------
// 128x128 tile, 4 waves (2x2), BK=32, LDS linear [128][32], global_load_lds width=16.
template<int SILU, int HEADS>
__global__ __launch_bounds__(256)
void gemm_bt(const unsigned short* __restrict__ A, const unsigned short* __restrict__ Bw,
             const float* __restrict__ bias, unsigned short* __restrict__ C,
             float* __restrict__ oLogits, float* __restrict__ oValues,
             int K, int N, int Nreal)
{
  __shared__ __align__(16) unsigned short As[128*32];
  __shared__ __align__(16) unsigned short Bs[128*32];
  const int tid = threadIdx.x;
  const int lane = tid & 63;
  const int w = tid >> 6;
  const int wm = w >> 1, wn = w & 1;
  const int m0 = blockIdx.x * 128, n0 = blockIdx.y * 128;
  f32x4 acc[4][4];
#pragma unroll
  for (int i=0;i<4;i++)
#pragma unroll
    for (int j=0;j<4;j++){ f32x4 z = {0.f,0.f,0.f,0.f}; acc[i][j] = z; }
  const int fr = lane & 15;
  const int kf = (lane >> 4) * 8;

  // staging geometry: chunk c (16B) -> row c>>2, sub (c&3)*8 elems; lds base wave-uniform
  const int r0 = tid >> 2, s0 = tid & 3;
  char* ldsA0 = (char*)As + w*1024;
  char* ldsA1 = (char*)As + 4096 + w*1024;
  char* ldsB0 = (char*)Bs + w*1024;
  char* ldsB1 = (char*)Bs + 4096 + w*1024;
  const unsigned short* gA0 = A  + (size_t)(m0+r0)*K    + s0*8;
  const unsigned short* gA1 = A  + (size_t)(m0+r0+64)*K + s0*8;
  const unsigned short* gB0 = Bw + (size_t)(n0+r0)*K    + s0*8;
  const unsigned short* gB1 = Bw + (size_t)(n0+r0+64)*K + s0*8;

  for (int k0 = 0; k0 < K; k0 += 32) {
    __syncthreads();                 // previous frag reads done before overwrite
    gload_lds16(gA0 + k0, ldsA0);
    gload_lds16(gA1 + k0, ldsA1);
    gload_lds16(gB0 + k0, ldsB0);
    gload_lds16(gB1 + k0, ldsB1);
    asm volatile("s_waitcnt vmcnt(0)" ::: "memory");
    __syncthreads();
    bf16x8 af[4], bfr[4];
#pragma unroll
    for (int f=0; f<4; f++){
      af[f]  = *(const bf16x8*)&As[(wm*64 + f*16 + fr)*32 + kf];
      bfr[f] = *(const bf16x8*)&Bs[(wn*64 + f*16 + fr)*32 + kf];
    }
#pragma unroll
    for (int i=0;i<4;i++)
#pragma unroll
      for (int j=0;j<4;j++)
        acc[i][j] = __builtin_amdgcn_mfma_f32_16x16x32_bf16(af[i], bfr[j], acc[i][j], 0, 0, 0);
  }

  const int mb = (lane >> 4) * 4;
  const int nb = lane & 15;
#pragma unroll
  for (int i=0;i<4;i++)
#pragma unroll
    for (int j=0;j<4;j++)
#pragma unroll
      for (int r=0;r<4;r++){
        int m = m0 + wm*64 + i*16 + mb + r;
        int n = n0 + wn*64 + j*16 + nb;
        if (HEADS && n >= Nreal) continue;
        float v = acc[i][j][r] + bias[n];
        if (SILU) v = v / (1.f + expf(-v));
        if (!HEADS) {
          C[(size_t)m*N + n] = f2bf(v);
        } else {
          if (n < 64) oLogits[(size_t)m*64 + n] = v;
          else if (n == 64) oValues[m] = v;
        }
      }
}

// ---------------- LSTM: persistent kernel, atomic-counter barrier ----------------
// 256 WGs x 512 thr. WG owns hidden units wg*4..+3 (16 gate rows, r = type*4+unit),
// fp32 W slice [16][1024] in LDS. Wave wv owns batches wv*4..+3.
// Lane: kc=lane&15 (k 16-way split), bsub=lane>>4 (batch within wave).
// h exchanged via sc0sc1 16B stores/loads; barrier = monotonic atomic counter.
#define SEL4(A0,A1,A2,A3) ((kc&2)?((kc&1)?(A3):(A2)):((kc&1)?(A1):(A0)))

__global__ __launch_bounds__(512)
void lstm_chunk(const unsigned short* __restrict__ xg, const float* __restrict__ Whh,
                float* __restrict__ h_bufs, float* __restrict__ c_buf,
                unsigned short* __restrict__ hist, float* __restrict__ dh, float* __restrict__ dc,
                int* __restrict__ cnt, int t0, int t1, int Tc)
{
  __shared__ __align__(16) float Wl[16*1024];   // 64 KB, [r][k]
  const int wg = blockIdx.x;
  const int n0w = wg * 4;
  const int tid = threadIdx.x;
  const int lane = tid & 63;
  const int wv = tid >> 6;
  const int kc = lane & 15;
  const int bsub = lane >> 4;
  const int b = wv*4 + bsub;

  for (int i = tid*4; i < 16*1024; i += 2048){
    int r = i >> 10, k = i & 1023;
    int grow = (r>>2)*NH + n0w + (r&3);
    *(f32x4*)&Wl[i] = *(const f32x4*)&Whh[(size_t)grow*NH + k];
  }
  float c_reg = 0.f, h_keep = 0.f;
  if (kc < 4) c_reg = c_buf[b*NH + n0w + kc];
  __syncthreads();

  for (int t = t0; t < t1; t++){
    const float* hb = h_bufs + (size_t)(t&1)*(NB*NH);
    float* hb_next  = h_bufs + (size_t)((t+1)&1)*(NB*NH);
    const int tl = t - t0;

    // xg prefetch (independent of h; ordered before poll by asm memory clobbers)
    float xgi=0.f, xgf=0.f, xgg=0.f, xgo=0.f;
    if (kc < 4){
      size_t xbase = ((size_t)b*Tc + tl)*4096 + n0w + kc;
      xgi = bf2f(xg[xbase]);
      xgf = bf2f(xg[xbase + 1024]);
      xgg = bf2f(xg[xbase + 2048]);
      xgo = bf2f(xg[xbase + 3072]);
    }

    // wait until all WGs completed step t-1 (counter is monotonic, 256 per step)
    {
      const int target = 256*t;
      while (bypass_load_i32(cnt) < target) __builtin_amdgcn_s_sleep(2);
    }

    // issue all 16 h loads (this lane's k-slice for its batch)
    f32x4 hq[16];
    const float* hrow = hb + (size_t)b*NH + kc*4;
#pragma unroll
    for (int kk=0; kk<16; kk++) hq[kk] = bypass_load_f32x4(hrow + kk*64);

    float acc[16];
#pragma unroll
    for (int r=0;r<16;r++) acc[r] = 0.f;

#pragma unroll
    for (int g=0; g<4; g++){
      if (g==0){ asm volatile("s_waitcnt vmcnt(12)" ::: "memory"); }
      else if (g==1){ asm volatile("s_waitcnt vmcnt(8)" ::: "memory"); }
      else if (g==2){ asm volatile("s_waitcnt vmcnt(4)" ::: "memory"); }
      else { asm volatile("s_waitcnt vmcnt(0)" ::: "memory"); }
      __builtin_amdgcn_sched_barrier(0);
#pragma unroll
      for (int kq=0; kq<4; kq++){
        const int kk = g*4 + kq;
#pragma unroll
        for (int r=0;r<16;r++){
          f32x4 wq = *(const f32x4*)&Wl[r*1024 + kk*64 + kc*4];
          acc[r] = fmaf(wq[0],hq[kk][0], fmaf(wq[1],hq[kk][1],
                   fmaf(wq[2],hq[kk][2], fmaf(wq[3],hq[kk][3], acc[r]))));
        }
      }
    }

    // reduce over the 16 kc lanes (4-stage butterfly; all lanes end with sums)
#pragma unroll
    for (int r=0;r<16;r++){
      float v = acc[r];
      v += __shfl_xor(v, 1);
      v += __shfl_xor(v, 2);
      v += __shfl_xor(v, 4);
      v += __shfl_xor(v, 8);
      acc[r] = v;
    }

    // epilogue: lane kc<4 owns hidden unit kc for batch b
    float gi = SEL4(acc[0], acc[1], acc[2], acc[3])   + xgi;
    float gf = SEL4(acc[4], acc[5], acc[6], acc[7])   + xgf;
    float gg = SEL4(acc[8], acc[9], acc[10], acc[11]) + xgg;
    float go = SEL4(acc[12],acc[13],acc[14],acc[15])  + xgo;
    float iv = 1.f/(1.f+expf(-gi));
    float fv = 1.f/(1.f+expf(-gf));
    float gv = tanhf(gg);
    float ov = 1.f/(1.f+expf(-go));
    float c_new = fv*c_reg + iv*gv;
    float h_new = ov*tanhf(c_new);
    if (kc < 4){ c_reg = c_new; h_keep = h_new; }

    // gather 4 units of this batch into lane kc==0, store 16B
    const int base = lane & 48;
    float h0 = __shfl(h_new, base + 0);
    float h1 = __shfl(h_new, base + 1);
    float h2 = __shfl(h_new, base + 2);
    float h3 = __shfl(h_new, base + 3);
    if (kc == 0){
      f32x4 hv = { h0, h1, h2, h3 };
      bypass_store_f32x4(hb_next + (size_t)b*NH + n0w, hv);
      u16x4 hp;
      hp[0] = f2bf(h0); hp[1] = f2bf(h1); hp[2] = f2bf(h2); hp[3] = f2bf(h3);
      *(u16x4*)&hist[((size_t)b*Tc + tl)*NH + n0w] = hp;   // normal store; read after kernel boundary
    }

    // arrival
    asm volatile("s_waitcnt vmcnt(0)" ::: "memory");
    __syncthreads();
    if (tid == 0) atomicAdd(cnt, 1);
  }
  if (kc < 4){
    c_buf[b*NH + n0w + kc] = c_reg;
    if (t1 == NT){ dh[b*NH + n0w + kc] = h_keep; dc[b*NH + n0w + kc] = c_reg; }
  }
}

// ---------------- LSTM: per-step fallback (regular launches, 256 thr) ----------------
__global__ __launch_bounds__(256)
void lstm_step(const unsigned short* __restrict__ xg, const float* __restrict__ Whh,
               float* __restrict__ h_bufs, float* __restrict__ c_buf,
               unsigned short* __restrict__ hist, float* __restrict__ dh, float* __restrict__ dc,
               int* __restrict__ cnt, int t, int t0, int Tc)
{
  const int wg = blockIdx.x;
  const int n0w = wg * 4;
  const int tid = threadIdx.x;
  const int kc = tid & 31, bg = tid >> 5;
  const float* hb = h_bufs + (t & 1) * (NB*NH);
  float acc[16][4];
#pragma unroll
  for (int r=0;r<16;r++)
#pragma unroll
    for (int bb=0;bb<4;bb++) acc[r][bb] = 0.f;

#pragma unroll
  for (int kk=0; kk<8; kk++){
    const int k4 = kc*32 + kk*4;
    f32x4 hq[4];
#pragma unroll
    for (int bb=0;bb<4;bb++)
      hq[bb] = *(const f32x4*)&hb[(bg*4+bb)*NH + k4];
#pragma unroll
    for (int r=0;r<16;r++){
      f32x4 wq = *(const f32x4*)&Whh[(size_t)((r>>2)*NH + n0w + (r&3))*NH + k4];
#pragma unroll
      for (int bb=0;bb<4;bb++)
        acc[r][bb] = fmaf(wq[0],hq[bb][0], fmaf(wq[1],hq[bb][1],
                     fmaf(wq[2],hq[bb][2], fmaf(wq[3],hq[bb][3], acc[r][bb]))));
    }
  }
#pragma unroll
  for (int r=0;r<16;r++)
#pragma unroll
    for (int bb=0;bb<4;bb++){
      float v = acc[r][bb];
      v += __shfl_xor(v, 1);
      v += __shfl_xor(v, 2);
      v += __shfl_xor(v, 4);
      v += __shfl_xor(v, 8);
      v += __shfl_xor(v, 16);
      acc[r][bb] = v;
    }
  if (kc < 16) {
    int blE = kc >> 2, jE = kc & 3;
    int bE = bg*4 + blE, nE = n0w + jE;
    int tl = t - t0;
    size_t xbase = ((size_t)bE*Tc + tl)*4096;
    float gi = acc[ 0+jE][blE] + bf2f(xg[xbase + 0*NH + nE]);
    float gf = acc[ 4+jE][blE] + bf2f(xg[xbase + 1*NH + nE]);
    float gg = acc[ 8+jE][blE] + bf2f(xg[xbase + 2*NH + nE]);
    float go = acc[12+jE][blE] + bf2f(xg[xbase + 3*NH + nE]);
    float iv = 1.f/(1.f+expf(-gi));
    float fv = 1.f/(1.f+expf(-gf));
    float gv = tanhf(gg);
    float ov = 1.f/(1.f+expf(-go));
    float c_prev = c_buf[bE*NH + nE];
    float c = fv*c_prev + iv*gv;
    float h = ov*tanhf(c);
    c_buf[bE*NH + nE] = c;
    h_bufs[((t+1)&1)*(NB*NH) + bE*NH + nE] = h;
    hist[((size_t)bE*Tc + tl)*NH + nE] = f2bf(h);
    if (t == NT-1){ dh[bE*NH + nE] = h; dc[bE*NH + nE] = c; }
  }
  if (tid == 0 && blockIdx.x == 0) atomicAdd(cnt, 256);  // keep counter protocol consistent
}

// ---------------- LayerNorm (bf16 in, chunked rows) -> bf16 out_ln (global rows) ----------------
__global__ __launch_bounds__(256)
void ln_chunk(const unsigned short* __restrict__ X, const float* __restrict__ gam, const float* __restrict__ bet,
              unsigned short* __restrict__ Y, int lgTc, int t0)
{
  const int row = blockIdx.x;
  const int Tc = 1 << lgTc;
  const int bl = row >> lgTc, tl = row & (Tc-1);
  const long grow = (long)bl*NT + t0 + tl;
  const int tid = threadIdx.x;
  u16x4 xv = *(const u16x4*)&X[(size_t)row*NH + tid*4];
  float v0 = bf2f(xv[0]), v1 = bf2f(xv[1]), v2 = bf2f(xv[2]), v3 = bf2f(xv[3]);
  float s = v0+v1+v2+v3;
  s += __shfl_xor(s,1); s += __shfl_xor(s,2); s += __shfl_xor(s,4);
  s += __shfl_xor(s,8); s += __shfl_xor(s,16); s += __shfl_xor(s,32);
  __shared__ float red[8];
  if ((tid & 63) == 0) red[tid >> 6] = s;
  __syncthreads();
  float mean = (red[0]+red[1]+red[2]+red[3]) * (1.0f/NH);
  float d0 = v0-mean, d1 = v1-mean, d2 = v2-mean, d3 = v3-mean;
  float q = d0*d0 + d1*d1 + d2*d2 + d3*d3;
  q += __shfl_xor(q,1); q += __shfl_xor(q,2); q += __shfl_xor(q,4);
  q += __shfl_xor(q,8); q += __shfl_xor(q,16); q += __shfl_xor(q,32);
  if ((tid & 63) == 0) red[4 + (tid >> 6)] = q;
  __syncthreads();
  float var = (red[4]+red[5]+red[6]+red[7]) * (1.0f/NH);
  float rs = 1.f / sqrtf(var + 1e-5f);
  f32x4 gm = *(const f32x4*)&gam[tid*4];
  f32x4 bt = *(const f32x4*)&bet[tid*4];
  u16x4 ov;
  ov[0] = f2bf(d0*rs*gm[0] + bt[0]);
  ov[1] = f2bf(d1*rs*gm[1] + bt[1]);
  ov[2] = f2bf(d2*rs*gm[2] + bt[2]);
  ov[3] = f2bf(d3*rs*gm[3] + bt[3]);
  *(u16x4*)&Y[(size_t)grow*NH + tid*4] = ov;
}

// ---------------- ar / tar losses ----------------
__global__ __launch_bounds__(256)
void loss_partial(const unsigned short* __restrict__ Yu, float* __restrict__ partials)
{
  float ar = 0.f, tar = 0.f;
  long stride = (long)gridDim.x*256;
  for (long vv = (long)blockIdx.x*256 + threadIdx.x; vv < 2097152; vv += stride){
    long i = vv*8;
    int t = (int)((i >> 10) & 511);
    u16x8 y = *(const u16x8*)&Yu[i];
    float x[8];
#pragma unroll
    for (int q=0;q<8;q++){ x[q] = bf2f(y[q]); ar += x[q]*x[q]; }
    if (t > 0){
      u16x8 yp = *(const u16x8*)&Yu[i - 1024];
#pragma unroll
      for (int q=0;q<8;q++){ float d = x[q] - bf2f(yp[q]); tar += d*d; }
    }
  }
  ar += __shfl_xor(ar,1); ar += __shfl_xor(ar,2); ar += __shfl_xor(ar,4);
  ar += __shfl_xor(ar,8); ar += __shfl_xor(ar,16); ar += __shfl_xor(ar,32);
  tar += __shfl_xor(tar,1); tar += __shfl_xor(tar,2); tar += __shfl_xor(tar,4);
  tar += __shfl_xor(tar,8); tar += __shfl_xor(tar,16); tar += __shfl_xor(tar,32);
  __shared__ float red[16];
  int w = threadIdx.x >> 6;
  if ((threadIdx.x & 63) == 0){ red[w] = ar; red[8+w] = tar; }
  __syncthreads();
  if (threadIdx.x == 0){
    partials[blockIdx.x*2]   = red[0]+red[1]+red[2]+red[3];
    partials[blockIdx.x*2+1] = red[8]+red[9]+red[10]+red[11];
  }
}

__global__ __launch_bounds__(256)
void loss_final(const float* __restrict__ partials, float* __restrict__ oAr, float* __restrict__ oTar){
  double sa = 0.0, st = 0.0;
  for (int i = threadIdx.x; i < 1024; i += 256){ sa += (double)partials[2*i]; st += (double)partials[2*i+1]; }
  for (int m=1;m<64;m<<=1){ sa += __shfl_xor(sa, m); st += __shfl_xor(st, m); }
  __shared__ double rd[8];
  int w = threadIdx.x >> 6;
  if ((threadIdx.x & 63) == 0){ rd[w] = sa; rd[4+w] = st; }
  __syncthreads();
  if (threadIdx.x == 0){
    double a  = rd[0]+rd[1]+rd[2]+rd[3];
    double tt = rd[4]+rd[5]+rd[6]+rd[7];
    oAr[0]  = (float)(a  / 16777216.0 * 0.01);
    oTar[0] = (float)(tt / 16744448.0 * 0.01);
  }
}

// ---------------- launch ----------------
extern "C" void kernel_launch(void* const* d_in, const int* in_sizes, int n_in,
                              void* d_out, int out_size, void* d_ws, size_t ws_size,
                              hipStream_t stream)
{
  const float* obs  = (const float*)d_in[0];
  const float* hxs  = (const float*)d_in[1];
  const float* cxs  = (const float*)d_in[2];
  const float* W1   = (const float*)d_in[3];
  const float* b1   = (const float*)d_in[4];
  const float* W2   = (const float*)d_in[5];
  const float* b2   = (const float*)d_in[6];
  const float* W_ih = (const float*)d_in[7];
  const float* W_hh = (const float*)d_in[8];
  const float* b_ih = (const float*)d_in[9];
  const float* b_hh = (const float*)d_in[10];
  const float* ln_g = (const float*)d_in[11];
  const float* ln_b = (const float*)d_in[12];
  const float* Wa   = (const float*)d_in[13];
  const float* ba   = (const float*)d_in[14];
  const float* Wc   = (const float*)d_in[15];
  const float* bc   = (const float*)d_in[16];

  char* ws = (char*)d_ws;
  size_t off = 0;
  auto alloc = [&](size_t bytes)->char*{
    char* p = ws + off;
    off = (off + bytes + 255) & ~(size_t)255;
    return p;
  };
  // ---- fixed buffers ----
  unsigned short* W1_b    = (unsigned short*)alloc((size_t)NE*ND*2);
  unsigned short* W2_b    = (unsigned short*)alloc((size_t)NE*NE*2);
  unsigned short* Wih_b   = (unsigned short*)alloc((size_t)4*NH*NE*2);
  unsigned short* Whead_b = (unsigned short*)alloc((size_t)128*NH*2);
  float* bias_heads       = (float*)alloc(65*4);
  float* bias_xg          = (float*)alloc(4096*4);
  unsigned short* outln_b = (unsigned short*)alloc((size_t)NB*NT*NH*2);   // 32 MB
  float* h_bufs           = (float*)alloc((size_t)2*NB*NH*4);
  float* c_buf            = (float*)alloc((size_t)NB*NH*4);
  int*   cnt              = (int*)alloc(256*4);
  float* partials         = (float*)alloc((size_t)1024*2*4);
  const size_t fixedEnd = off;

  // ---- pick chunk size (largest that fits) ----
  int lg = -1;
  for (int L = 9; L >= 4; --L){
    size_t Mc = (size_t)NB << L;
    size_t per = Mc*ND*2 + 2*(Mc*NE*2) + Mc*4096*2 + Mc*NH*2 + 6*256;
    if (fixedEnd + per <= ws_size){ lg = L; break; }
  }
  if (lg < 0){ sentinel_kernel<<<1,1,0,stream>>>((float*)d_out); return; }
  const int Tc = 1 << lg;
  const int Mc = NB << lg;
  const int nChunks = NT >> lg;

  unsigned short* obs_c  = (unsigned short*)alloc((size_t)Mc*ND*2);
  unsigned short* enc1_c = (unsigned short*)alloc((size_t)Mc*NE*2);
  unsigned short* enc2_c = (unsigned short*)alloc((size_t)Mc*NE*2);
  unsigned short* xg_c   = (unsigned short*)alloc((size_t)Mc*4096*2);
  unsigned short* hist_c = (unsigned short*)alloc((size_t)Mc*NH*2);

  float* o = (float*)d_out;
  float* oLogits = o;
  float* oValues = o + (size_t)NB*NT*64;
  float* oH  = oValues + NB*NT;
  float* oC  = oH + NB*NH;
  float* oAr = oC + NB*NH;
  float* oTar= oAr + 1;

  // ---- one-time weight prep ----
  f2b_kernel<<<256 ,256,0,stream>>>(W1,   W1_b,  (long)NE*ND);
  f2b_kernel<<<512 ,256,0,stream>>>(W2,   W2_b,  (long)NE*NE);
  f2b_kernel<<<1024,256,0,stream>>>(W_ih, Wih_b, (long)4*NH*NE);
  prep_kernel<<<520,256,0,stream>>>(Wa, Wc, ba, bc, b_ih, b_hh, Whead_b, bias_heads, bias_xg);
  init_hc<<<128,256,0,stream>>>(hxs, cxs, h_bufs, c_buf, cnt);

  // ---- chunked pipeline ----
  for (int c = 0; c < nChunks; ++c){
    int t0 = c << lg, t1 = t0 + Tc;
    f2b_obs_chunk<<<512,256,0,stream>>>(obs, obs_c, lg, t0);
    gemm_bt<1,0><<<dim3(Mc/128,8) ,256,0,stream>>>(obs_c,  W1_b,  b1,      enc1_c, nullptr, nullptr, ND, NE, NE);
    gemm_bt<1,0><<<dim3(Mc/128,8) ,256,0,stream>>>(enc1_c, W2_b,  b2,      enc2_c, nullptr, nullptr, NE, NE, NE);
    gemm_bt<0,0><<<dim3(Mc/128,32),256,0,stream>>>(enc2_c, Wih_b, bias_xg, xg_c,   nullptr, nullptr, NE, 4096, 4096);

    int a_t0 = t0, a_t1 = t1, a_Tc = Tc;
    void* args[] = { (void*)&xg_c, (void*)&W_hh, (void*)&h_bufs, (void*)&c_buf,
                     (void*)&hist_c, (void*)&oH, (void*)&oC, (void*)&cnt,
                     (void*)&a_t0, (void*)&a_t1, (void*)&a_Tc };
    hipError_t ce = hipLaunchCooperativeKernel((const void*)lstm_chunk, dim3(256), dim3(512), args, 0u, stream);
    if (ce != hipSuccess){
      for (int t = t0; t < t1; ++t)
        lstm_step<<<256,256,0,stream>>>(xg_c, W_hh, h_bufs, c_buf, hist_c, oH, oC, cnt, t, t0, Tc);
    }
    ln_chunk<<<Mc,256,0,stream>>>(hist_c, ln_g, ln_b, outln_b, lg, t0);
  }

  // ---- heads + losses ----
  gemm_bt<0,1><<<dim3(128,1),256,0,stream>>>(outln_b, Whead_b, bias_heads, nullptr, oLogits, oValues, NH, 128, 65);
  loss_partial<<<1024,256,0,stream>>>(outln_b, partials);
  loss_final<<<1,256,0,stream>>>(partials, oAr, oTar);
}

// Round 5
// 7121.770 us; speedup vs baseline: 3.3278x; 1.1961x over previous
//
#include <hip/hip_runtime.h>

typedef __attribute__((ext_vector_type(8))) short bf16x8;
typedef __attribute__((ext_vector_type(8))) unsigned short u16x8;
typedef __attribute__((ext_vector_type(4))) unsigned short u16x4;
typedef __attribute__((ext_vector_type(4))) float f32x4;

#define NB 32
#define NT 512
#define ND 256
#define NE 1024
#define NH 1024

__device__ __forceinline__ float bf2f(unsigned short u){
  union { unsigned int i; float f; } w; w.i = ((unsigned int)u) << 16; return w.f;
}
__device__ __forceinline__ unsigned short f2bf(float f){
  union { float f; unsigned int i; } w; w.f = f;
  unsigned int r = (w.i >> 16) & 1u;
  return (unsigned short)((w.i + 0x7fffu + r) >> 16);
}

// ---- cache-bypass (coherence-point) memory ops ----
__device__ __forceinline__ f32x4 bypass_load_f32x4(const float* p){
  f32x4 r;
  asm volatile("global_load_dwordx4 %0, %1, off sc0 sc1" : "=v"(r) : "v"(p) : "memory");
  return r;  // caller must s_waitcnt before use
}
__device__ __forceinline__ int bypass_load_i32(const int* p){
  int r;
  asm volatile("global_load_dword %0, %1, off sc0 sc1\n\ts_waitcnt vmcnt(0)"
               : "=v"(r) : "v"(p) : "memory");
  return r;
}
__device__ __forceinline__ void bypass_store_f32x4(float* p, f32x4 v){
  asm volatile("global_store_dwordx4 %0, %1, off sc0 sc1" :: "v"(p), "v"(v) : "memory");
}

// ---- global_load_lds width=16 (m97 pattern) ----
__device__ __forceinline__ void gload_lds16(const void* g, void* l){
  __builtin_amdgcn_global_load_lds(
      (const __attribute__((address_space(1))) void*)g,
      (__attribute__((address_space(3))) void*)l, 16, 0, 0);
}

// ---------------- conversion / prep ----------------
__global__ void f2b_kernel(const float* __restrict__ src, unsigned short* __restrict__ dst, long n){
  long i = (long)blockIdx.x*blockDim.x + threadIdx.x;
  long stride = (long)gridDim.x*blockDim.x;
  for (; i < n; i += stride) dst[i] = f2bf(src[i]);
}

__global__ void f2b_obs_chunk(const float* __restrict__ obs, unsigned short* __restrict__ dst,
                              int lgTc, int t0){
  const int Tc = 1 << lgTc;
  const long n = (long)NB * Tc * ND;
  long i = (long)blockIdx.x*blockDim.x + threadIdx.x;
  long stride = (long)gridDim.x*blockDim.x;
  for (; i < n; i += stride){
    long lr = i >> 8;
    int col = (int)(i & 255);
    long gr = (lr >> lgTc)*NT + t0 + (lr & (Tc-1));
    dst[i] = f2bf(obs[gr*ND + col]);
  }
}

__global__ void prep_kernel(const float* __restrict__ Wa, const float* __restrict__ Wc,
                            const float* __restrict__ ba, const float* __restrict__ bc,
                            const float* __restrict__ b_ih, const float* __restrict__ b_hh,
                            unsigned short* __restrict__ Whead, float* __restrict__ bias_heads,
                            float* __restrict__ bias_xg){
  int i = blockIdx.x*blockDim.x + threadIdx.x;
  int stride = gridDim.x*blockDim.x;
  for (int v = i; v < 128*1024; v += stride){
    int n = v >> 10, k = v & 1023;
    float w = (n < 64) ? Wa[v] : (n == 64 ? Wc[k] : 0.f);
    Whead[v] = f2bf(w);
  }
  for (int v = i; v < 4096; v += stride) bias_xg[v] = b_ih[v] + b_hh[v];
  for (int v = i; v < 65; v += stride) bias_heads[v] = (v < 64) ? ba[v] : bc[0];
}

__global__ void init_hc(const float* __restrict__ hxs, const float* __restrict__ cxs,
                        float* __restrict__ h_bufs, float* __restrict__ c_buf,
                        int* __restrict__ cnt){
  int i = blockIdx.x*blockDim.x + threadIdx.x;
  if (i < NB*NH){ h_bufs[i] = hxs[i]; c_buf[i] = cxs[i]; }
  if (i < 1024) cnt[i] = 0;
}

__global__ void sentinel_kernel(float* __restrict__ out){ out[0] = 1.0e6f; }

// ---------------- bf16 MFMA GEMM: C[M,N] = act(A[M,K] @ Bw[N,K]^T + bias) ----------------
// 128x128 tile, 4 waves (2x2), BK=32, LDS double-buffered, global_load_lds w=16,
// 2-phase prefetch: stage(next) || compute(cur), one vmcnt(0)+barrier per K-step.
#define GEMM_COMPUTE(P) { \
  bf16x8 af[4], bfr[4]; \
  _Pragma("unroll") for (int f=0; f<4; f++){ \
    af[f]  = *(const bf16x8*)&As[P][(wm*64 + f*16 + fr)*32 + kf]; \
    bfr[f] = *(const bf16x8*)&Bs[P][(wn*64 + f*16 + fr)*32 + kf]; } \
  _Pragma("unroll") for (int i=0;i<4;i++) \
    _Pragma("unroll") for (int j=0;j<4;j++) \
      acc[i][j] = __builtin_amdgcn_mfma_f32_16x16x32_bf16(af[i], bfr[j], acc[i][j], 0, 0, 0); }

template<int SILU, int HEADS>
__global__ __launch_bounds__(256)
void gemm_bt(const unsigned short* __restrict__ A, const unsigned short* __restrict__ Bw,
             const float* __restrict__ bias, unsigned short* __restrict__ C,
             float* __restrict__ oLogits, float* __restrict__ oValues,
             int K, int N, int Nreal)
{
  __shared__ __align__(16) unsigned short As[2][128*32];
  __shared__ __align__(16) unsigned short Bs[2][128*32];
  const int tid = threadIdx.x;
  const int lane = tid & 63;
  const int w = tid >> 6;
  const int wm = w >> 1, wn = w & 1;
  const int m0 = blockIdx.x * 128, n0 = blockIdx.y * 128;
  f32x4 acc[4][4];
#pragma unroll
  for (int i=0;i<4;i++)
#pragma unroll
    for (int j=0;j<4;j++){ f32x4 z = {0.f,0.f,0.f,0.f}; acc[i][j] = z; }
  const int fr = lane & 15;
  const int kf = (lane >> 4) * 8;
  const int r0 = tid >> 2, s0 = tid & 3;
  const unsigned short* gA0 = A  + (size_t)(m0+r0)*K    + s0*8;
  const unsigned short* gA1 = A  + (size_t)(m0+r0+64)*K + s0*8;
  const unsigned short* gB0 = Bw + (size_t)(n0+r0)*K    + s0*8;
  const unsigned short* gB1 = Bw + (size_t)(n0+r0+64)*K + s0*8;

  auto stage = [&](int p, int k0){
    char* a = (char*)&As[p][0] + w*1024;
    char* b = (char*)&Bs[p][0] + w*1024;
    gload_lds16(gA0 + k0, a);
    gload_lds16(gA1 + k0, a + 4096);
    gload_lds16(gB0 + k0, b);
    gload_lds16(gB1 + k0, b + 4096);
  };

  stage(0, 0);
  asm volatile("s_waitcnt vmcnt(0)" ::: "memory");
  __syncthreads();
  int cur = 0;
  for (int k0 = 32; k0 < K; k0 += 32){
    stage(cur ^ 1, k0);        // prefetch next tile (async, in flight over compute)
    GEMM_COMPUTE(cur);
    asm volatile("s_waitcnt vmcnt(0)" ::: "memory");
    __syncthreads();
    cur ^= 1;
  }
  GEMM_COMPUTE(cur);

  const int mb = (lane >> 4) * 4;
  const int nb = lane & 15;
#pragma unroll
  for (int i=0;i<4;i++)
#pragma unroll
    for (int j=0;j<4;j++)
#pragma unroll
      for (int r=0;r<4;r++){
        int m = m0 + wm*64 + i*16 + mb + r;
        int n = n0 + wn*64 + j*16 + nb;
        if (HEADS && n >= Nreal) continue;
        float v = acc[i][j][r] + bias[n];
        if (SILU) v = v / (1.f + expf(-v));
        if (!HEADS) {
          C[(size_t)m*N + n] = f2bf(v);
        } else {
          if (n < 64) oLogits[(size_t)m*64 + n] = v;
          else if (n == 64) oValues[m] = v;
        }
      }
}

// ---------------- LSTM: persistent kernel (regular launch), spread-counter barrier ----------------
// 256 WGs x 512 thr, guaranteed co-resident (1 block/CU: 64KB LDS, 8 waves).
// WG owns hidden units wg*4..+3 (16 gate rows), fp32 W slice [16][1024] in LDS.
// Wave wv owns batches wv*4..+3; lane: kc=lane&15 (k-split), bsub=lane>>4.
// Barrier: arrival = 1 atomicAdd per WG into cnt[(wg&15)*64] (16 spread lines);
// release = wave 0 polls the 16 lines, sums, then __syncthreads.
#define SEL4(A0,A1,A2,A3) ((kc&2)?((kc&1)?(A3):(A2)):((kc&1)?(A1):(A0)))

__global__ __launch_bounds__(512)
void lstm_chunk(const unsigned short* __restrict__ xg, const float* __restrict__ Whh,
                float* __restrict__ h_bufs, float* __restrict__ c_buf,
                unsigned short* __restrict__ hist, float* __restrict__ dh, float* __restrict__ dc,
                int* __restrict__ cnt, int t0, int t1, int Tc)
{
  __shared__ __align__(16) float Wl[16*1024];   // 64 KB, [r][k]
  const int wg = blockIdx.x;
  const int n0w = wg * 4;
  const int tid = threadIdx.x;
  const int lane = tid & 63;
  const int wv = tid >> 6;
  const int kc = lane & 15;
  const int b = wv*4 + (lane >> 4);

  for (int i = tid*4; i < 16*1024; i += 2048){
    int r = i >> 10, k = i & 1023;
    int grow = (r>>2)*NH + n0w + (r&3);
    *(f32x4*)&Wl[i] = *(const f32x4*)&Whh[(size_t)grow*NH + k];
  }
  float c_reg = 0.f, h_keep = 0.f;
  if (kc < 4) c_reg = c_buf[b*NH + n0w + kc];
  __syncthreads();

  for (int t = t0; t < t1; t++){
    const float* hb = h_bufs + (size_t)(t&1)*(NB*NH);
    float* hb_next  = h_bufs + (size_t)((t+1)&1)*(NB*NH);
    const int tl = t - t0;

    // xg prefetch (independent of h; issues before the poll)
    float xgi=0.f, xgf=0.f, xgg=0.f, xgo=0.f;
    if (kc < 4){
      size_t xbase = ((size_t)b*Tc + tl)*4096 + n0w + kc;
      xgi = bf2f(xg[xbase]);
      xgf = bf2f(xg[xbase + 1024]);
      xgg = bf2f(xg[xbase + 2048]);
      xgo = bf2f(xg[xbase + 3072]);
    }

    // ---- release-poll: wave 0 only ----
    if (wv == 0){
      const int target = 256*t;
      while (true){
        int v = 0;
        if (lane < 16) v = bypass_load_i32(&cnt[lane*64]);
        v += __shfl_xor(v, 1);  v += __shfl_xor(v, 2);
        v += __shfl_xor(v, 4);  v += __shfl_xor(v, 8);
        v += __shfl_xor(v, 16); v += __shfl_xor(v, 32);
        if (v >= target) break;
        __builtin_amdgcn_s_sleep(1);
      }
    }
    __syncthreads();

    // ---- issue all 16 h loads (this lane's k-slice for its batch) ----
    f32x4 hq[16];
    const float* hrow = hb + (size_t)b*NH + kc*4;
#pragma unroll
    for (int kk=0; kk<16; kk++) hq[kk] = bypass_load_f32x4(hrow + kk*64);

    float acc[16];
#pragma unroll
    for (int r=0;r<16;r++) acc[r] = 0.f;

#pragma unroll
    for (int g=0; g<4; g++){
      if (g==0){ asm volatile("s_waitcnt vmcnt(12)" ::: "memory"); }
      else if (g==1){ asm volatile("s_waitcnt vmcnt(8)" ::: "memory"); }
      else if (g==2){ asm volatile("s_waitcnt vmcnt(4)" ::: "memory"); }
      else { asm volatile("s_waitcnt vmcnt(0)" ::: "memory"); }
      __builtin_amdgcn_sched_barrier(0);
#pragma unroll
      for (int kq=0; kq<4; kq++){
        const int kk = g*4 + kq;
#pragma unroll
        for (int r=0;r<16;r++){
          f32x4 wq = *(const f32x4*)&Wl[r*1024 + kk*64 + kc*4];
          acc[r] = fmaf(wq[0],hq[kk][0], fmaf(wq[1],hq[kk][1],
                   fmaf(wq[2],hq[kk][2], fmaf(wq[3],hq[kk][3], acc[r]))));
        }
      }
    }

    // reduce over the 16 kc lanes
#pragma unroll
    for (int r=0;r<16;r++){
      float v = acc[r];
      v += __shfl_xor(v, 1);
      v += __shfl_xor(v, 2);
      v += __shfl_xor(v, 4);
      v += __shfl_xor(v, 8);
      acc[r] = v;
    }

    // epilogue: lane kc<4 owns hidden unit kc for batch b
    float gi = SEL4(acc[0], acc[1], acc[2], acc[3])   + xgi;
    float gf = SEL4(acc[4], acc[5], acc[6], acc[7])   + xgf;
    float gg = SEL4(acc[8], acc[9], acc[10], acc[11]) + xgg;
    float go = SEL4(acc[12],acc[13],acc[14],acc[15])  + xgo;
    float iv = 1.f/(1.f+expf(-gi));
    float fv = 1.f/(1.f+expf(-gf));
    float gv = tanhf(gg);
    float ov = 1.f/(1.f+expf(-go));
    float c_new = fv*c_reg + iv*gv;
    float h_new = ov*tanhf(c_new);
    if (kc < 4){ c_reg = c_new; h_keep = h_new; }

    // gather 4 units of this batch into lane kc==0, store 16B
    const int base = lane & 48;
    float h0 = __shfl(h_new, base + 0);
    float h1 = __shfl(h_new, base + 1);
    float h2 = __shfl(h_new, base + 2);
    float h3 = __shfl(h_new, base + 3);
    if (kc == 0){
      f32x4 hv = { h0, h1, h2, h3 };
      bypass_store_f32x4(hb_next + (size_t)b*NH + n0w, hv);
      u16x4 hp;
      hp[0] = f2bf(h0); hp[1] = f2bf(h1); hp[2] = f2bf(h2); hp[3] = f2bf(h3);
      *(u16x4*)&hist[((size_t)b*Tc + tl)*NH + n0w] = hp;   // normal store; read after kernel boundary
    }

    // ---- arrival ----
    asm volatile("s_waitcnt vmcnt(0)" ::: "memory");
    __syncthreads();
    if (tid == 0) atomicAdd(&cnt[(wg & 15) * 64], 1);
  }
  if (kc < 4){
    c_buf[b*NH + n0w + kc] = c_reg;
    if (t1 == NT){ dh[b*NH + n0w + kc] = h_keep; dc[b*NH + n0w + kc] = c_reg; }
  }
}

// ---------------- LayerNorm (bf16 in, chunked rows) -> bf16 out_ln (global rows) ----------------
__global__ __launch_bounds__(256)
void ln_chunk(const unsigned short* __restrict__ X, const float* __restrict__ gam, const float* __restrict__ bet,
              unsigned short* __restrict__ Y, int lgTc, int t0)
{
  const int row = blockIdx.x;
  const int Tc = 1 << lgTc;
  const int bl = row >> lgTc, tl = row & (Tc-1);
  const long grow = (long)bl*NT + t0 + tl;
  const int tid = threadIdx.x;
  u16x4 xv = *(const u16x4*)&X[(size_t)row*NH + tid*4];
  float v0 = bf2f(xv[0]), v1 = bf2f(xv[1]), v2 = bf2f(xv[2]), v3 = bf2f(xv[3]);
  float s = v0+v1+v2+v3;
  s += __shfl_xor(s,1); s += __shfl_xor(s,2); s += __shfl_xor(s,4);
  s += __shfl_xor(s,8); s += __shfl_xor(s,16); s += __shfl_xor(s,32);
  __shared__ float red[8];
  if ((tid & 63) == 0) red[tid >> 6] = s;
  __syncthreads();
  float mean = (red[0]+red[1]+red[2]+red[3]) * (1.0f/NH);
  float d0 = v0-mean, d1 = v1-mean, d2 = v2-mean, d3 = v3-mean;
  float q = d0*d0 + d1*d1 + d2*d2 + d3*d3;
  q += __shfl_xor(q,1); q += __shfl_xor(q,2); q += __shfl_xor(q,4);
  q += __shfl_xor(q,8); q += __shfl_xor(q,16); q += __shfl_xor(q,32);
  if ((tid & 63) == 0) red[4 + (tid >> 6)] = q;
  __syncthreads();
  float var = (red[4]+red[5]+red[6]+red[7]) * (1.0f/NH);
  float rs = 1.f / sqrtf(var + 1e-5f);
  f32x4 gm = *(const f32x4*)&gam[tid*4];
  f32x4 bt = *(const f32x4*)&bet[tid*4];
  u16x4 ov;
  ov[0] = f2bf(d0*rs*gm[0] + bt[0]);
  ov[1] = f2bf(d1*rs*gm[1] + bt[1]);
  ov[2] = f2bf(d2*rs*gm[2] + bt[2]);
  ov[3] = f2bf(d3*rs*gm[3] + bt[3]);
  *(u16x4*)&Y[(size_t)grow*NH + tid*4] = ov;
}

// ---------------- ar / tar losses ----------------
__global__ __launch_bounds__(256)
void loss_partial(const unsigned short* __restrict__ Yu, float* __restrict__ partials)
{
  float ar = 0.f, tar = 0.f;
  long stride = (long)gridDim.x*256;
  for (long vv = (long)blockIdx.x*256 + threadIdx.x; vv < 2097152; vv += stride){
    long i = vv*8;
    int t = (int)((i >> 10) & 511);
    u16x8 y = *(const u16x8*)&Yu[i];
    float x[8];
#pragma unroll
    for (int q=0;q<8;q++){ x[q] = bf2f(y[q]); ar += x[q]*x[q]; }
    if (t > 0){
      u16x8 yp = *(const u16x8*)&Yu[i - 1024];
#pragma unroll
      for (int q=0;q<8;q++){ float d = x[q] - bf2f(yp[q]); tar += d*d; }
    }
  }
  ar += __shfl_xor(ar,1); ar += __shfl_xor(ar,2); ar += __shfl_xor(ar,4);
  ar += __shfl_xor(ar,8); ar += __shfl_xor(ar,16); ar += __shfl_xor(ar,32);
  tar += __shfl_xor(tar,1); tar += __shfl_xor(tar,2); tar += __shfl_xor(tar,4);
  tar += __shfl_xor(tar,8); tar += __shfl_xor(tar,16); tar += __shfl_xor(tar,32);
  __shared__ float red[16];
  int w = threadIdx.x >> 6;
  if ((threadIdx.x & 63) == 0){ red[w] = ar; red[8+w] = tar; }
  __syncthreads();
  if (threadIdx.x == 0){
    partials[blockIdx.x*2]   = red[0]+red[1]+red[2]+red[3];
    partials[blockIdx.x*2+1] = red[8]+red[9]+red[10]+red[11];
  }
}

__global__ __launch_bounds__(256)
void loss_final(const float* __restrict__ partials, float* __restrict__ oAr, float* __restrict__ oTar){
  double sa = 0.0, st = 0.0;
  for (int i = threadIdx.x; i < 1024; i += 256){ sa += (double)partials[2*i]; st += (double)partials[2*i+1]; }
  for (int m=1;m<64;m<<=1){ sa += __shfl_xor(sa, m); st += __shfl_xor(st, m); }
  __shared__ double rd[8];
  int w = threadIdx.x >> 6;
  if ((threadIdx.x & 63) == 0){ rd[w] = sa; rd[4+w] = st; }
  __syncthreads();
  if (threadIdx.x == 0){
    double a  = rd[0]+rd[1]+rd[2]+rd[3];
    double tt = rd[4]+rd[5]+rd[6]+rd[7];
    oAr[0]  = (float)(a  / 16777216.0 * 0.01);
    oTar[0] = (float)(tt / 16744448.0 * 0.01);
  }
}

// ---------------- launch ----------------
extern "C" void kernel_launch(void* const* d_in, const int* in_sizes, int n_in,
                              void* d_out, int out_size, void* d_ws, size_t ws_size,
                              hipStream_t stream)
{
  const float* obs  = (const float*)d_in[0];
  const float* hxs  = (const float*)d_in[1];
  const float* cxs  = (const float*)d_in[2];
  const float* W1   = (const float*)d_in[3];
  const float* b1   = (const float*)d_in[4];
  const float* W2   = (const float*)d_in[5];
  const float* b2   = (const float*)d_in[6];
  const float* W_ih = (const float*)d_in[7];
  const float* W_hh = (const float*)d_in[8];
  const float* b_ih = (const float*)d_in[9];
  const float* b_hh = (const float*)d_in[10];
  const float* ln_g = (const float*)d_in[11];
  const float* ln_b = (const float*)d_in[12];
  const float* Wa   = (const float*)d_in[13];
  const float* ba   = (const float*)d_in[14];
  const float* Wc   = (const float*)d_in[15];
  const float* bc   = (const float*)d_in[16];

  char* ws = (char*)d_ws;
  size_t off = 0;
  auto alloc = [&](size_t bytes)->char*{
    char* p = ws + off;
    off = (off + bytes + 255) & ~(size_t)255;
    return p;
  };
  // ---- fixed buffers ----
  unsigned short* W1_b    = (unsigned short*)alloc((size_t)NE*ND*2);
  unsigned short* W2_b    = (unsigned short*)alloc((size_t)NE*NE*2);
  unsigned short* Wih_b   = (unsigned short*)alloc((size_t)4*NH*NE*2);
  unsigned short* Whead_b = (unsigned short*)alloc((size_t)128*NH*2);
  float* bias_heads       = (float*)alloc(65*4);
  float* bias_xg          = (float*)alloc(4096*4);
  unsigned short* outln_b = (unsigned short*)alloc((size_t)NB*NT*NH*2);   // 32 MB
  float* h_bufs           = (float*)alloc((size_t)2*NB*NH*4);
  float* c_buf            = (float*)alloc((size_t)NB*NH*4);
  int*   cnt              = (int*)alloc(1024*4);
  float* partials         = (float*)alloc((size_t)1024*2*4);
  const size_t fixedEnd = off;

  // ---- pick chunk size (largest that fits) ----
  int lg = -1;
  for (int L = 9; L >= 4; --L){
    size_t Mc = (size_t)NB << L;
    size_t per = Mc*ND*2 + 2*(Mc*NE*2) + Mc*4096*2 + Mc*NH*2 + 6*256;
    if (fixedEnd + per <= ws_size){ lg = L; break; }
  }
  if (lg < 0){ sentinel_kernel<<<1,1,0,stream>>>((float*)d_out); return; }
  const int Tc = 1 << lg;
  const int Mc = NB << lg;
  const int nChunks = NT >> lg;

  unsigned short* obs_c  = (unsigned short*)alloc((size_t)Mc*ND*2);
  unsigned short* enc1_c = (unsigned short*)alloc((size_t)Mc*NE*2);
  unsigned short* enc2_c = (unsigned short*)alloc((size_t)Mc*NE*2);
  unsigned short* xg_c   = (unsigned short*)alloc((size_t)Mc*4096*2);
  unsigned short* hist_c = (unsigned short*)alloc((size_t)Mc*NH*2);

  float* o = (float*)d_out;
  float* oLogits = o;
  float* oValues = o + (size_t)NB*NT*64;
  float* oH  = oValues + NB*NT;
  float* oC  = oH + NB*NH;
  float* oAr = oC + NB*NH;
  float* oTar= oAr + 1;

  // ---- one-time weight prep ----
  f2b_kernel<<<256 ,256,0,stream>>>(W1,   W1_b,  (long)NE*ND);
  f2b_kernel<<<512 ,256,0,stream>>>(W2,   W2_b,  (long)NE*NE);
  f2b_kernel<<<1024,256,0,stream>>>(W_ih, Wih_b, (long)4*NH*NE);
  prep_kernel<<<520,256,0,stream>>>(Wa, Wc, ba, bc, b_ih, b_hh, Whead_b, bias_heads, bias_xg);
  init_hc<<<128,256,0,stream>>>(hxs, cxs, h_bufs, c_buf, cnt);

  // ---- chunked pipeline ----
  for (int c = 0; c < nChunks; ++c){
    int t0 = c << lg, t1 = t0 + Tc;
    f2b_obs_chunk<<<512,256,0,stream>>>(obs, obs_c, lg, t0);
    gemm_bt<1,0><<<dim3(Mc/128,8) ,256,0,stream>>>(obs_c,  W1_b,  b1,      enc1_c, nullptr, nullptr, ND, NE, NE);
    gemm_bt<1,0><<<dim3(Mc/128,8) ,256,0,stream>>>(enc1_c, W2_b,  b2,      enc2_c, nullptr, nullptr, NE, NE, NE);
    gemm_bt<0,0><<<dim3(Mc/128,32),256,0,stream>>>(enc2_c, Wih_b, bias_xg, xg_c,   nullptr, nullptr, NE, 4096, 4096);

    lstm_chunk<<<256,512,0,stream>>>(xg_c, W_hh, h_bufs, c_buf, hist_c, oH, oC, cnt, t0, t1, Tc);

    ln_chunk<<<Mc,256,0,stream>>>(hist_c, ln_g, ln_b, outln_b, lg, t0);
  }

  // ---- heads + losses ----
  gemm_bt<0,1><<<dim3(128,1),256,0,stream>>>(outln_b, Whead_b, bias_heads, nullptr, oLogits, oValues, NH, 128, 65);
  loss_partial<<<1024,256,0,stream>>>(outln_b, partials);
  loss_final<<<1,256,0,stream>>>(partials, oAr, oTar);
}

// Round 6
// 2617.477 us; speedup vs baseline: 9.0545x; 2.7209x over previous
//
#include <hip/hip_runtime.h>

typedef __attribute__((ext_vector_type(8))) short bf16x8;
typedef __attribute__((ext_vector_type(8))) unsigned short u16x8;
typedef __attribute__((ext_vector_type(4))) unsigned short u16x4;
typedef __attribute__((ext_vector_type(4))) float f32x4;

#define NB 32
#define NT 512
#define ND 256
#define NE 1024
#define NH 1024
#define LSTM_SMEM (131072 + 16640)   // W frags (hi+lo) + reduce buffer [16][260]

__device__ __forceinline__ float bf2f(unsigned short u){
  union { unsigned int i; float f; } w; w.i = ((unsigned int)u) << 16; return w.f;
}
__device__ __forceinline__ unsigned short f2bf(float f){
  union { float f; unsigned int i; } w; w.f = f;
  unsigned int r = (w.i >> 16) & 1u;
  return (unsigned short)((w.i + 0x7fffu + r) >> 16);
}

// ---- cache-bypass (coherence-point) memory ops ----
__device__ __forceinline__ f32x4 bypass_load_f32x4(const float* p){
  f32x4 r;
  asm volatile("global_load_dwordx4 %0, %1, off sc0 sc1" : "=v"(r) : "v"(p) : "memory");
  return r;  // caller must s_waitcnt before use
}
__device__ __forceinline__ int bypass_load_i32(const int* p){
  int r;
  asm volatile("global_load_dword %0, %1, off sc0 sc1\n\ts_waitcnt vmcnt(0)"
               : "=v"(r) : "v"(p) : "memory");
  return r;
}
__device__ __forceinline__ void bypass_store_f32x4(float* p, f32x4 v){
  asm volatile("global_store_dwordx4 %0, %1, off sc0 sc1" :: "v"(p), "v"(v) : "memory");
}

// ---- global_load_lds width=16 (m97 pattern) ----
__device__ __forceinline__ void gload_lds16(const void* g, void* l){
  __builtin_amdgcn_global_load_lds(
      (const __attribute__((address_space(1))) void*)g,
      (__attribute__((address_space(3))) void*)l, 16, 0, 0);
}

// ---- packed f32->bf16 convert + split-precision fragment build ----
__device__ __forceinline__ unsigned pkbf(float a, float b){
  unsigned r; asm("v_cvt_pk_bf16_f32 %0, %1, %2" : "=v"(r) : "v"(a), "v"(b)); return r;
}
__device__ __forceinline__ void make_frags(f32x4 x0, f32x4 x1, bf16x8& hi, bf16x8& lo){
  union Uv { unsigned u[4]; bf16x8 v; } H, L;
#pragma unroll
  for (int w=0; w<4; w++){
    float a = (w<2) ? x0[w*2]   : x1[(w-2)*2];
    float b = (w<2) ? x0[w*2+1] : x1[(w-2)*2+1];
    unsigned hw = pkbf(a, b);
    H.u[w] = hw;
    union { unsigned u; float f; } e0, e1;
    e0.u = hw << 16; e1.u = hw & 0xffff0000u;
    L.u[w] = pkbf(a - e0.f, b - e1.f);
  }
  hi = H.v; lo = L.v;
}

// ---------------- one-shot prep: weight conversion + state init ----------------
__global__ void mega_prep(const float* __restrict__ W1, const float* __restrict__ W2,
                          const float* __restrict__ Wih,
                          const float* __restrict__ Wa, const float* __restrict__ Wc,
                          const float* __restrict__ ba, const float* __restrict__ bc,
                          const float* __restrict__ b_ih, const float* __restrict__ b_hh,
                          const float* __restrict__ hxs, const float* __restrict__ cxs,
                          unsigned short* __restrict__ W1_b, unsigned short* __restrict__ W2_b,
                          unsigned short* __restrict__ Wih_b, unsigned short* __restrict__ Whead_b,
                          float* __restrict__ bias_heads, float* __restrict__ bias_xg,
                          float* __restrict__ h_bufs, float* __restrict__ c_buf,
                          int* __restrict__ cnt)
{
  long i0 = (long)blockIdx.x*256 + threadIdx.x;
  long stride = (long)gridDim.x*256;
  for (long i=i0; i<(long)NE*ND;   i+=stride) W1_b[i]  = f2bf(W1[i]);
  for (long i=i0; i<(long)NE*NE;   i+=stride) W2_b[i]  = f2bf(W2[i]);
  for (long i=i0; i<(long)4*NH*NE; i+=stride) Wih_b[i] = f2bf(Wih[i]);
  for (long i=i0; i<128*1024; i+=stride){
    int n = (int)(i>>10), k = (int)(i&1023);
    Whead_b[i] = f2bf(n<64 ? Wa[i] : (n==64 ? Wc[k] : 0.f));
  }
  for (long i=i0; i<4096; i+=stride) bias_xg[i] = b_ih[i] + b_hh[i];
  for (long i=i0; i<65;   i+=stride) bias_heads[i] = (i<64) ? ba[i] : bc[0];
  for (long i=i0; i<NB*NH; i+=stride){ h_bufs[i] = hxs[i]; c_buf[i] = cxs[i]; }
  for (long i=i0; i<1024; i+=stride) cnt[i] = 0;
}

__global__ void f2b_obs_chunk(const float* __restrict__ obs, unsigned short* __restrict__ dst,
                              int lgTc, int t0){
  const int Tc = 1 << lgTc;
  const long n = (long)NB * Tc * ND;
  long i = (long)blockIdx.x*blockDim.x + threadIdx.x;
  long stride = (long)gridDim.x*blockDim.x;
  for (; i < n; i += stride){
    long lr = i >> 8;
    int col = (int)(i & 255);
    long gr = (lr >> lgTc)*NT + t0 + (lr & (Tc-1));
    dst[i] = f2bf(obs[gr*ND + col]);
  }
}

__global__ void sentinel_kernel(float* __restrict__ out){ out[0] = 1.0e6f; }

// ---------------- bf16 MFMA GEMM (r5-verified): 128x128, dbuf LDS, 2-phase prefetch ----------------
#define GEMM_COMPUTE(P) { \
  bf16x8 af[4], bfr[4]; \
  _Pragma("unroll") for (int f=0; f<4; f++){ \
    af[f]  = *(const bf16x8*)&As[P][(wm*64 + f*16 + fr)*32 + kf]; \
    bfr[f] = *(const bf16x8*)&Bs[P][(wn*64 + f*16 + fr)*32 + kf]; } \
  _Pragma("unroll") for (int i=0;i<4;i++) \
    _Pragma("unroll") for (int j=0;j<4;j++) \
      acc[i][j] = __builtin_amdgcn_mfma_f32_16x16x32_bf16(af[i], bfr[j], acc[i][j], 0, 0, 0); }

template<int SILU, int HEADS>
__global__ __launch_bounds__(256)
void gemm_bt(const unsigned short* __restrict__ A, const unsigned short* __restrict__ Bw,
             const float* __restrict__ bias, unsigned short* __restrict__ C,
             float* __restrict__ oLogits, float* __restrict__ oValues,
             int K, int N, int Nreal)
{
  __shared__ __align__(16) unsigned short As[2][128*32];
  __shared__ __align__(16) unsigned short Bs[2][128*32];
  const int tid = threadIdx.x;
  const int lane = tid & 63;
  const int w = tid >> 6;
  const int wm = w >> 1, wn = w & 1;
  const int m0 = blockIdx.x * 128, n0 = blockIdx.y * 128;
  f32x4 acc[4][4];
#pragma unroll
  for (int i=0;i<4;i++)
#pragma unroll
    for (int j=0;j<4;j++){ f32x4 z = {0.f,0.f,0.f,0.f}; acc[i][j] = z; }
  const int fr = lane & 15;
  const int kf = (lane >> 4) * 8;
  const int r0 = tid >> 2, s0 = tid & 3;
  const unsigned short* gA0 = A  + (size_t)(m0+r0)*K    + s0*8;
  const unsigned short* gA1 = A  + (size_t)(m0+r0+64)*K + s0*8;
  const unsigned short* gB0 = Bw + (size_t)(n0+r0)*K    + s0*8;
  const unsigned short* gB1 = Bw + (size_t)(n0+r0+64)*K + s0*8;

  auto stage = [&](int p, int k0){
    char* a = (char*)&As[p][0] + w*1024;
    char* b = (char*)&Bs[p][0] + w*1024;
    gload_lds16(gA0 + k0, a);
    gload_lds16(gA1 + k0, a + 4096);
    gload_lds16(gB0 + k0, b);
    gload_lds16(gB1 + k0, b + 4096);
  };

  stage(0, 0);
  asm volatile("s_waitcnt vmcnt(0)" ::: "memory");
  __syncthreads();
  int cur = 0;
  for (int k0 = 32; k0 < K; k0 += 32){
    stage(cur ^ 1, k0);
    GEMM_COMPUTE(cur);
    asm volatile("s_waitcnt vmcnt(0)" ::: "memory");
    __syncthreads();
    cur ^= 1;
  }
  GEMM_COMPUTE(cur);

  const int mb = (lane >> 4) * 4;
  const int nb = lane & 15;
#pragma unroll
  for (int i=0;i<4;i++)
#pragma unroll
    for (int j=0;j<4;j++)
#pragma unroll
      for (int r=0;r<4;r++){
        int m = m0 + wm*64 + i*16 + mb + r;
        int n = n0 + wn*64 + j*16 + nb;
        if (HEADS && n >= Nreal) continue;
        float v = acc[i][j][r] + bias[n];
        if (SILU) v = v / (1.f + expf(-v));
        if (!HEADS) {
          C[(size_t)m*N + n] = f2bf(v);
        } else {
          if (n < 64) oLogits[(size_t)m*64 + n] = v;
          else if (n == 64) oValues[m] = v;
        }
      }
}

// ---------------- LSTM: persistent MFMA kernel, split-precision (fp32-equivalent) ----------------
// 256 WGs x 512 thr, 1 block/CU (147KB dynamic LDS). WG (bh=wg&1, ug=wg>>1):
// batches b0=bh*16..+16, units n0w=ug*8..+8 (32 gate rows r=g*8+uu).
// W fragments (hi+lo bf16) pre-staged once in LDS as MFMA B-frags.
// Per step/wave: 8 bypass h loads -> A-frags (hi+lo in regs), 24 MFMA, LDS reduce.
// Barrier: spread-counter (16 lines), arrival atomicAdd per WG, wave0 polls.
__global__ __launch_bounds__(512)
void lstm_mfma(const unsigned short* __restrict__ xg, const float* __restrict__ Whh,
               float* __restrict__ h_bufs, float* __restrict__ c_buf,
               unsigned short* __restrict__ hist, float* __restrict__ dh, float* __restrict__ dc,
               int* __restrict__ cnt, int t0, int t1, int Tc)
{
  extern __shared__ char smem[];
  unsigned short* Wf = (unsigned short*)smem;          // [term][kt 32][nt 2][lane 64] x 8 ushort
  float* red = (float*)(smem + 131072);                // [m 16][260] (r*8+wv, padded)
  const int wg = blockIdx.x;
  const int bh = wg & 1, ug = wg >> 1;
  const int b0 = bh*16, n0w = ug*8;
  const int tid = threadIdx.x;
  const int lane = tid & 63;
  const int wv = tid >> 6;
  const int fr = lane & 15;
  const int q8 = (lane >> 4) * 8;

  // ---- one-time: stage W hi/lo fragments ----
  for (int s = tid; s < 8192; s += 512){
    int term = s >> 12, kt = (s >> 7) & 31, nt = (s >> 6) & 1, l = s & 63;
    int r = nt*16 + (l & 15);
    int g = r >> 3, uu2 = r & 7;
    const float* src = Whh + (size_t)(g*NH + n0w + uu2)*NH + kt*32 + (l>>4)*8;
    u16x8 o;
#pragma unroll
    for (int j=0;j<8;j++){
      float wv_ = src[j];
      unsigned short hi = f2bf(wv_);
      o[j] = (term==0) ? hi : f2bf(wv_ - bf2f(hi));
    }
    *(u16x8*)&Wf[(size_t)s*8] = o;
  }

  const int bl = tid >> 3;        // valid for tid<128
  const int uu = tid & 7;
  float c_reg = 0.f, h_keep = 0.f;
  if (tid < 128) c_reg = c_buf[(b0 + bl)*NH + n0w + uu];
  __syncthreads();

  for (int t = t0; t < t1; t++){
    const float* hb = h_bufs + (size_t)(t & 1)*(NB*NH);
    float* hb_next  = h_bufs + (size_t)((t+1)&1)*(NB*NH);
    const int tl = t - t0;

    // xg prefetch (before poll; independent of h)
    float xgv[4] = {0.f,0.f,0.f,0.f};
    if (tid < 128){
      size_t xbase = ((size_t)(b0+bl)*Tc + tl)*4096 + n0w + uu;
#pragma unroll
      for (int g=0; g<4; g++) xgv[g] = bf2f(xg[xbase + g*1024]);
    }

    // ---- release-poll: wave 0 only ----
    if (wv == 0){
      const int target = 256*t;
      while (true){
        int v = 0;
        if (lane < 16) v = bypass_load_i32(&cnt[lane*64]);
        v += __shfl_xor(v,1); v += __shfl_xor(v,2); v += __shfl_xor(v,4);
        v += __shfl_xor(v,8); v += __shfl_xor(v,16); v += __shfl_xor(v,32);
        if (v >= target) break;
        __builtin_amdgcn_s_sleep(1);
      }
    }
    __syncthreads();

    // ---- h A-frag loads: wave's 128-k slice, batch row fr ----
    f32x4 hv[8];
#pragma unroll
    for (int ks=0; ks<4; ks++){
      const float* p = hb + (size_t)(b0 + fr)*NH + (wv*4 + ks)*32 + q8;
      hv[ks*2]   = bypass_load_f32x4(p);
      hv[ks*2+1] = bypass_load_f32x4(p + 4);
    }
    asm volatile("s_waitcnt vmcnt(0)" ::: "memory");
    __builtin_amdgcn_sched_barrier(0);

    bf16x8 ahi[4], alo[4];
#pragma unroll
    for (int ks=0; ks<4; ks++) make_frags(hv[2*ks], hv[2*ks+1], ahi[ks], alo[ks]);

    f32x4 acc[2];
    { f32x4 z = {0.f,0.f,0.f,0.f}; acc[0] = z; acc[1] = z; }
#pragma unroll
    for (int ks=0; ks<4; ks++){
      int kt = wv*4 + ks;
#pragma unroll
      for (int nt=0; nt<2; nt++){
        bf16x8 bhi = *(const bf16x8*)&Wf[kt*1024 + nt*512 + lane*8];
        bf16x8 blo = *(const bf16x8*)&Wf[32768 + kt*1024 + nt*512 + lane*8];
        acc[nt] = __builtin_amdgcn_mfma_f32_16x16x32_bf16(ahi[ks], bhi, acc[nt], 0,0,0);
        acc[nt] = __builtin_amdgcn_mfma_f32_16x16x32_bf16(ahi[ks], blo, acc[nt], 0,0,0);
        acc[nt] = __builtin_amdgcn_mfma_f32_16x16x32_bf16(alo[ks], bhi, acc[nt], 0,0,0);
      }
    }

    // ---- cross-wave reduce: partials to LDS ----
#pragma unroll
    for (int nt=0; nt<2; nt++)
#pragma unroll
      for (int r4=0; r4<4; r4++)
        red[((lane>>4)*4 + r4)*260 + (nt*16 + fr)*8 + wv] = acc[nt][r4];
    __syncthreads();

    // ---- epilogue: 128 threads, one (batch, unit) each ----
    if (tid < 128){
      float gate[4];
#pragma unroll
      for (int g=0; g<4; g++){
        int base = bl*260 + (g*8 + uu)*8;
        f32x4 s0 = *(const f32x4*)&red[base];
        f32x4 s1 = *(const f32x4*)&red[base+4];
        gate[g] = ((s0[0]+s0[1])+(s0[2]+s0[3])) + ((s1[0]+s1[1])+(s1[2]+s1[3])) + xgv[g];
      }
      float iv = 1.f/(1.f+expf(-gate[0]));
      float fv = 1.f/(1.f+expf(-gate[1]));
      float gv = tanhf(gate[2]);
      float ov = 1.f/(1.f+expf(-gate[3]));
      float c_new = fv*c_reg + iv*gv;
      float h_new = ov*tanhf(c_new);
      c_reg = c_new; h_keep = h_new;
      float h0 = __shfl(h_new, (lane & 60) + 0);
      float h1 = __shfl(h_new, (lane & 60) + 1);
      float h2 = __shfl(h_new, (lane & 60) + 2);
      float h3 = __shfl(h_new, (lane & 60) + 3);
      if ((uu & 3) == 0){
        f32x4 hvv = { h0, h1, h2, h3 };
        bypass_store_f32x4(hb_next + (size_t)(b0+bl)*NH + n0w + uu, hvv);
        u16x4 hp; hp[0]=f2bf(h0); hp[1]=f2bf(h1); hp[2]=f2bf(h2); hp[3]=f2bf(h3);
        *(u16x4*)&hist[((size_t)(b0+bl)*Tc + tl)*NH + n0w + uu] = hp;
      }
    }
    // ---- arrival (barrier drains stores; then signal) ----
    __syncthreads();
    if (tid == 0) atomicAdd(&cnt[(wg & 15)*64], 1);
  }
  if (tid < 128){
    c_buf[(b0+bl)*NH + n0w + uu] = c_reg;
    if (t1 == NT){ dh[(b0+bl)*NH + n0w + uu] = h_keep; dc[(b0+bl)*NH + n0w + uu] = c_reg; }
  }
}

// ---------------- LSTM fallback: r5-verified VALU persistent kernel (static 64KB LDS) ----------------
#define SEL4(A0,A1,A2,A3) ((kc&2)?((kc&1)?(A3):(A2)):((kc&1)?(A1):(A0)))

__global__ __launch_bounds__(512)
void lstm_valu(const unsigned short* __restrict__ xg, const float* __restrict__ Whh,
               float* __restrict__ h_bufs, float* __restrict__ c_buf,
               unsigned short* __restrict__ hist, float* __restrict__ dh, float* __restrict__ dc,
               int* __restrict__ cnt, int t0, int t1, int Tc)
{
  __shared__ __align__(16) float Wl[16*1024];
  const int wg = blockIdx.x;
  const int n0w = wg * 4;
  const int tid = threadIdx.x;
  const int lane = tid & 63;
  const int wv = tid >> 6;
  const int kc = lane & 15;
  const int b = wv*4 + (lane >> 4);

  for (int i = tid*4; i < 16*1024; i += 2048){
    int r = i >> 10, k = i & 1023;
    int grow = (r>>2)*NH + n0w + (r&3);
    *(f32x4*)&Wl[i] = *(const f32x4*)&Whh[(size_t)grow*NH + k];
  }
  float c_reg = 0.f, h_keep = 0.f;
  if (kc < 4) c_reg = c_buf[b*NH + n0w + kc];
  __syncthreads();

  for (int t = t0; t < t1; t++){
    const float* hb = h_bufs + (size_t)(t&1)*(NB*NH);
    float* hb_next  = h_bufs + (size_t)((t+1)&1)*(NB*NH);
    const int tl = t - t0;
    float xgi=0.f, xgf=0.f, xgg=0.f, xgo=0.f;
    if (kc < 4){
      size_t xbase = ((size_t)b*Tc + tl)*4096 + n0w + kc;
      xgi = bf2f(xg[xbase]);
      xgf = bf2f(xg[xbase + 1024]);
      xgg = bf2f(xg[xbase + 2048]);
      xgo = bf2f(xg[xbase + 3072]);
    }
    if (wv == 0){
      const int target = 256*t;
      while (true){
        int v = 0;
        if (lane < 16) v = bypass_load_i32(&cnt[lane*64]);
        v += __shfl_xor(v,1); v += __shfl_xor(v,2); v += __shfl_xor(v,4);
        v += __shfl_xor(v,8); v += __shfl_xor(v,16); v += __shfl_xor(v,32);
        if (v >= target) break;
        __builtin_amdgcn_s_sleep(1);
      }
    }
    __syncthreads();

    f32x4 hq[16];
    const float* hrow = hb + (size_t)b*NH + kc*4;
#pragma unroll
    for (int kk=0; kk<16; kk++) hq[kk] = bypass_load_f32x4(hrow + kk*64);

    float acc[16];
#pragma unroll
    for (int r=0;r<16;r++) acc[r] = 0.f;
#pragma unroll
    for (int g=0; g<4; g++){
      if (g==0){ asm volatile("s_waitcnt vmcnt(12)" ::: "memory"); }
      else if (g==1){ asm volatile("s_waitcnt vmcnt(8)" ::: "memory"); }
      else if (g==2){ asm volatile("s_waitcnt vmcnt(4)" ::: "memory"); }
      else { asm volatile("s_waitcnt vmcnt(0)" ::: "memory"); }
      __builtin_amdgcn_sched_barrier(0);
#pragma unroll
      for (int kq=0; kq<4; kq++){
        const int kk = g*4 + kq;
#pragma unroll
        for (int r=0;r<16;r++){
          f32x4 wq = *(const f32x4*)&Wl[r*1024 + kk*64 + kc*4];
          acc[r] = fmaf(wq[0],hq[kk][0], fmaf(wq[1],hq[kk][1],
                   fmaf(wq[2],hq[kk][2], fmaf(wq[3],hq[kk][3], acc[r]))));
        }
      }
    }
#pragma unroll
    for (int r=0;r<16;r++){
      float v = acc[r];
      v += __shfl_xor(v, 1);
      v += __shfl_xor(v, 2);
      v += __shfl_xor(v, 4);
      v += __shfl_xor(v, 8);
      acc[r] = v;
    }
    float gi = SEL4(acc[0], acc[1], acc[2], acc[3])   + xgi;
    float gf = SEL4(acc[4], acc[5], acc[6], acc[7])   + xgf;
    float gg = SEL4(acc[8], acc[9], acc[10], acc[11]) + xgg;
    float go = SEL4(acc[12],acc[13],acc[14],acc[15])  + xgo;
    float iv = 1.f/(1.f+expf(-gi));
    float fv = 1.f/(1.f+expf(-gf));
    float gv = tanhf(gg);
    float ov = 1.f/(1.f+expf(-go));
    float c_new = fv*c_reg + iv*gv;
    float h_new = ov*tanhf(c_new);
    if (kc < 4){ c_reg = c_new; h_keep = h_new; }
    const int base = lane & 48;
    float h0 = __shfl(h_new, base + 0);
    float h1 = __shfl(h_new, base + 1);
    float h2 = __shfl(h_new, base + 2);
    float h3 = __shfl(h_new, base + 3);
    if (kc == 0){
      f32x4 hvv = { h0, h1, h2, h3 };
      bypass_store_f32x4(hb_next + (size_t)b*NH + n0w, hvv);
      u16x4 hp;
      hp[0] = f2bf(h0); hp[1] = f2bf(h1); hp[2] = f2bf(h2); hp[3] = f2bf(h3);
      *(u16x4*)&hist[((size_t)b*Tc + tl)*NH + n0w] = hp;
    }
    asm volatile("s_waitcnt vmcnt(0)" ::: "memory");
    __syncthreads();
    if (tid == 0) atomicAdd(&cnt[(wg & 15) * 64], 1);
  }
  if (kc < 4){
    c_buf[b*NH + n0w + kc] = c_reg;
    if (t1 == NT){ dh[b*NH + n0w + kc] = h_keep; dc[b*NH + n0w + kc] = c_reg; }
  }
}

// ---------------- LayerNorm (bf16 in, chunked rows) -> bf16 out_ln (global rows) ----------------
__global__ __launch_bounds__(256)
void ln_chunk(const unsigned short* __restrict__ X, const float* __restrict__ gam, const float* __restrict__ bet,
              unsigned short* __restrict__ Y, int lgTc, int t0)
{
  const int row = blockIdx.x;
  const int Tc = 1 << lgTc;
  const int bl = row >> lgTc, tl = row & (Tc-1);
  const long grow = (long)bl*NT + t0 + tl;
  const int tid = threadIdx.x;
  u16x4 xv = *(const u16x4*)&X[(size_t)row*NH + tid*4];
  float v0 = bf2f(xv[0]), v1 = bf2f(xv[1]), v2 = bf2f(xv[2]), v3 = bf2f(xv[3]);
  float s = v0+v1+v2+v3;
  s += __shfl_xor(s,1); s += __shfl_xor(s,2); s += __shfl_xor(s,4);
  s += __shfl_xor(s,8); s += __shfl_xor(s,16); s += __shfl_xor(s,32);
  __shared__ float red[8];
  if ((tid & 63) == 0) red[tid >> 6] = s;
  __syncthreads();
  float mean = (red[0]+red[1]+red[2]+red[3]) * (1.0f/NH);
  float d0 = v0-mean, d1 = v1-mean, d2 = v2-mean, d3 = v3-mean;
  float q = d0*d0 + d1*d1 + d2*d2 + d3*d3;
  q += __shfl_xor(q,1); q += __shfl_xor(q,2); q += __shfl_xor(q,4);
  q += __shfl_xor(q,8); q += __shfl_xor(q,16); q += __shfl_xor(q,32);
  if ((tid & 63) == 0) red[4 + (tid >> 6)] = q;
  __syncthreads();
  float var = (red[4]+red[5]+red[6]+red[7]) * (1.0f/NH);
  float rs = 1.f / sqrtf(var + 1e-5f);
  f32x4 gm = *(const f32x4*)&gam[tid*4];
  f32x4 bt = *(const f32x4*)&bet[tid*4];
  u16x4 ov;
  ov[0] = f2bf(d0*rs*gm[0] + bt[0]);
  ov[1] = f2bf(d1*rs*gm[1] + bt[1]);
  ov[2] = f2bf(d2*rs*gm[2] + bt[2]);
  ov[3] = f2bf(d3*rs*gm[3] + bt[3]);
  *(u16x4*)&Y[(size_t)grow*NH + tid*4] = ov;
}

// ---------------- ar / tar losses ----------------
__global__ __launch_bounds__(256)
void loss_partial(const unsigned short* __restrict__ Yu, float* __restrict__ partials)
{
  float ar = 0.f, tar = 0.f;
  long stride = (long)gridDim.x*256;
  for (long vv = (long)blockIdx.x*256 + threadIdx.x; vv < 2097152; vv += stride){
    long i = vv*8;
    int t = (int)((i >> 10) & 511);
    u16x8 y = *(const u16x8*)&Yu[i];
    float x[8];
#pragma unroll
    for (int q=0;q<8;q++){ x[q] = bf2f(y[q]); ar += x[q]*x[q]; }
    if (t > 0){
      u16x8 yp = *(const u16x8*)&Yu[i - 1024];
#pragma unroll
      for (int q=0;q<8;q++){ float d = x[q] - bf2f(yp[q]); tar += d*d; }
    }
  }
  ar += __shfl_xor(ar,1); ar += __shfl_xor(ar,2); ar += __shfl_xor(ar,4);
  ar += __shfl_xor(ar,8); ar += __shfl_xor(ar,16); ar += __shfl_xor(ar,32);
  tar += __shfl_xor(tar,1); tar += __shfl_xor(tar,2); tar += __shfl_xor(tar,4);
  tar += __shfl_xor(tar,8); tar += __shfl_xor(tar,16); tar += __shfl_xor(tar,32);
  __shared__ float red[16];
  int w = threadIdx.x >> 6;
  if ((threadIdx.x & 63) == 0){ red[w] = ar; red[8+w] = tar; }
  __syncthreads();
  if (threadIdx.x == 0){
    partials[blockIdx.x*2]   = red[0]+red[1]+red[2]+red[3];
    partials[blockIdx.x*2+1] = red[8]+red[9]+red[10]+red[11];
  }
}

__global__ __launch_bounds__(256)
void loss_final(const float* __restrict__ partials, float* __restrict__ oAr, float* __restrict__ oTar){
  double sa = 0.0, st = 0.0;
  for (int i = threadIdx.x; i < 1024; i += 256){ sa += (double)partials[2*i]; st += (double)partials[2*i+1]; }
  for (int m=1;m<64;m<<=1){ sa += __shfl_xor(sa, m); st += __shfl_xor(st, m); }
  __shared__ double rd[8];
  int w = threadIdx.x >> 6;
  if ((threadIdx.x & 63) == 0){ rd[w] = sa; rd[4+w] = st; }
  __syncthreads();
  if (threadIdx.x == 0){
    double a  = rd[0]+rd[1]+rd[2]+rd[3];
    double tt = rd[4]+rd[5]+rd[6]+rd[7];
    oAr[0]  = (float)(a  / 16777216.0 * 0.01);
    oTar[0] = (float)(tt / 16744448.0 * 0.01);
  }
}

// ---------------- launch ----------------
extern "C" void kernel_launch(void* const* d_in, const int* in_sizes, int n_in,
                              void* d_out, int out_size, void* d_ws, size_t ws_size,
                              hipStream_t stream)
{
  const float* obs  = (const float*)d_in[0];
  const float* hxs  = (const float*)d_in[1];
  const float* cxs  = (const float*)d_in[2];
  const float* W1   = (const float*)d_in[3];
  const float* b1   = (const float*)d_in[4];
  const float* W2   = (const float*)d_in[5];
  const float* b2   = (const float*)d_in[6];
  const float* W_ih = (const float*)d_in[7];
  const float* W_hh = (const float*)d_in[8];
  const float* b_ih = (const float*)d_in[9];
  const float* b_hh = (const float*)d_in[10];
  const float* ln_g = (const float*)d_in[11];
  const float* ln_b = (const float*)d_in[12];
  const float* Wa   = (const float*)d_in[13];
  const float* ba   = (const float*)d_in[14];
  const float* Wc   = (const float*)d_in[15];
  const float* bc   = (const float*)d_in[16];

  char* ws = (char*)d_ws;
  size_t off = 0;
  auto alloc = [&](size_t bytes)->char*{
    char* p = ws + off;
    off = (off + bytes + 255) & ~(size_t)255;
    return p;
  };
  unsigned short* W1_b    = (unsigned short*)alloc((size_t)NE*ND*2);
  unsigned short* W2_b    = (unsigned short*)alloc((size_t)NE*NE*2);
  unsigned short* Wih_b   = (unsigned short*)alloc((size_t)4*NH*NE*2);
  unsigned short* Whead_b = (unsigned short*)alloc((size_t)128*NH*2);
  float* bias_heads       = (float*)alloc(65*4);
  float* bias_xg          = (float*)alloc(4096*4);
  unsigned short* outln_b = (unsigned short*)alloc((size_t)NB*NT*NH*2);   // 32 MB
  float* h_bufs           = (float*)alloc((size_t)2*NB*NH*4);
  float* c_buf            = (float*)alloc((size_t)NB*NH*4);
  int*   cnt              = (int*)alloc(1024*4);
  float* partials         = (float*)alloc((size_t)1024*2*4);
  const size_t fixedEnd = off;

  int lg = -1;
  for (int L = 9; L >= 4; --L){
    size_t Mc = (size_t)NB << L;
    size_t per = Mc*ND*2 + 2*(Mc*NE*2) + Mc*4096*2 + Mc*NH*2 + 6*256;
    if (fixedEnd + per <= ws_size){ lg = L; break; }
  }
  if (lg < 0){ sentinel_kernel<<<1,1,0,stream>>>((float*)d_out); return; }
  const int Tc = 1 << lg;
  const int Mc = NB << lg;
  const int nChunks = NT >> lg;

  unsigned short* obs_c  = (unsigned short*)alloc((size_t)Mc*ND*2);
  unsigned short* enc1_c = (unsigned short*)alloc((size_t)Mc*NE*2);
  unsigned short* enc2_c = (unsigned short*)alloc((size_t)Mc*NE*2);
  unsigned short* xg_c   = (unsigned short*)alloc((size_t)Mc*4096*2);
  unsigned short* hist_c = (unsigned short*)alloc((size_t)Mc*NH*2);

  float* o = (float*)d_out;
  float* oLogits = o;
  float* oValues = o + (size_t)NB*NT*64;
  float* oH  = oValues + NB*NT;
  float* oC  = oH + NB*NH;
  float* oAr = oC + NB*NH;
  float* oTar= oAr + 1;

  mega_prep<<<2048,256,0,stream>>>(W1, W2, W_ih, Wa, Wc, ba, bc, b_ih, b_hh, hxs, cxs,
                                   W1_b, W2_b, Wih_b, Whead_b, bias_heads, bias_xg,
                                   h_bufs, c_buf, cnt);

  for (int c = 0; c < nChunks; ++c){
    int t0 = c << lg, t1 = t0 + Tc;
    f2b_obs_chunk<<<512,256,0,stream>>>(obs, obs_c, lg, t0);
    gemm_bt<1,0><<<dim3(Mc/128,8) ,256,0,stream>>>(obs_c,  W1_b,  b1,      enc1_c, nullptr, nullptr, ND, NE, NE);
    gemm_bt<1,0><<<dim3(Mc/128,8) ,256,0,stream>>>(enc1_c, W2_b,  b2,      enc2_c, nullptr, nullptr, NE, NE, NE);
    gemm_bt<0,0><<<dim3(Mc/128,32),256,0,stream>>>(enc2_c, Wih_b, bias_xg, xg_c,   nullptr, nullptr, NE, 4096, 4096);

    (void)hipGetLastError();  // clear stale error state
    lstm_mfma<<<256,512,LSTM_SMEM,stream>>>(xg_c, W_hh, h_bufs, c_buf, hist_c, oH, oC, cnt, t0, t1, Tc);
    if (hipGetLastError() != hipSuccess)
      lstm_valu<<<256,512,0,stream>>>(xg_c, W_hh, h_bufs, c_buf, hist_c, oH, oC, cnt, t0, t1, Tc);

    ln_chunk<<<Mc,256,0,stream>>>(hist_c, ln_g, ln_b, outln_b, lg, t0);
  }

  gemm_bt<0,1><<<dim3(128,1),256,0,stream>>>(outln_b, Whead_b, bias_heads, nullptr, oLogits, oValues, NH, 128, 65);
  loss_partial<<<1024,256,0,stream>>>(outln_b, partials);
  loss_final<<<1,256,0,stream>>>(partials, oAr, oTar);
}

// Round 7
// 2566.777 us; speedup vs baseline: 9.2334x; 1.0198x over previous
//
#include <hip/hip_runtime.h>

typedef __attribute__((ext_vector_type(8))) short bf16x8;
typedef __attribute__((ext_vector_type(8))) unsigned short u16x8;
typedef __attribute__((ext_vector_type(4))) unsigned short u16x4;
typedef __attribute__((ext_vector_type(4))) float f32x4;

#define NB 32
#define NT 512
#define ND 256
#define NE 1024
#define NH 1024
#define LSTM_SMEM (131072 + 18432)   // W frags (hi+lo) + reduce buffer [16][32][9] f32

__device__ __forceinline__ float bf2f(unsigned short u){
  union { unsigned int i; float f; } w; w.i = ((unsigned int)u) << 16; return w.f;
}
__device__ __forceinline__ unsigned short f2bf(float f){
  union { float f; unsigned int i; } w; w.f = f;
  unsigned int r = (w.i >> 16) & 1u;
  return (unsigned short)((w.i + 0x7fffu + r) >> 16);
}

// ---- cache-bypass (coherence-point) memory ops ----
__device__ __forceinline__ f32x4 bypass_load_f32x4(const float* p){
  f32x4 r;
  asm volatile("global_load_dwordx4 %0, %1, off sc0 sc1" : "=v"(r) : "v"(p) : "memory");
  return r;  // caller must s_waitcnt before use
}
__device__ __forceinline__ int bypass_load_i32(const int* p){
  int r;
  asm volatile("global_load_dword %0, %1, off sc0 sc1\n\ts_waitcnt vmcnt(0)"
               : "=v"(r) : "v"(p) : "memory");
  return r;
}
__device__ __forceinline__ void bypass_store_f32x4(float* p, f32x4 v){
  asm volatile("global_store_dwordx4 %0, %1, off sc0 sc1" :: "v"(p), "v"(v) : "memory");
}
__device__ __forceinline__ void bypass_store_i32(int* p, int v){
  asm volatile("global_store_dword %0, %1, off sc0 sc1" :: "v"(p), "v"(v) : "memory");
}

// ---- global_load_lds width=16 (m97 pattern) ----
__device__ __forceinline__ void gload_lds16(const void* g, void* l){
  __builtin_amdgcn_global_load_lds(
      (const __attribute__((address_space(1))) void*)g,
      (__attribute__((address_space(3))) void*)l, 16, 0, 0);
}

// ---- packed f32->bf16 convert + split-precision fragment build ----
__device__ __forceinline__ unsigned pkbf(float a, float b){
  unsigned r; asm("v_cvt_pk_bf16_f32 %0, %1, %2" : "=v"(r) : "v"(a), "v"(b)); return r;
}
__device__ __forceinline__ void make_frags(f32x4 x0, f32x4 x1, bf16x8& hi, bf16x8& lo){
  union Uv { unsigned u[4]; bf16x8 v; } H, L;
#pragma unroll
  for (int w=0; w<4; w++){
    float a = (w<2) ? x0[w*2]   : x1[(w-2)*2];
    float b = (w<2) ? x0[w*2+1] : x1[(w-2)*2+1];
    unsigned hw = pkbf(a, b);
    H.u[w] = hw;
    union { unsigned u; float f; } e0, e1;
    e0.u = hw << 16; e1.u = hw & 0xffff0000u;
    L.u[w] = pkbf(a - e0.f, b - e1.f);
  }
  hi = H.v; lo = L.v;
}

// ---------------- one-shot prep: weight conversion + state init ----------------
__global__ void mega_prep(const float* __restrict__ W1, const float* __restrict__ W2,
                          const float* __restrict__ Wih,
                          const float* __restrict__ Wa, const float* __restrict__ Wc,
                          const float* __restrict__ ba, const float* __restrict__ bc,
                          const float* __restrict__ b_ih, const float* __restrict__ b_hh,
                          const float* __restrict__ hxs, const float* __restrict__ cxs,
                          unsigned short* __restrict__ W1_b, unsigned short* __restrict__ W2_b,
                          unsigned short* __restrict__ Wih_b, unsigned short* __restrict__ Whead_b,
                          float* __restrict__ bias_heads, float* __restrict__ bias_xg,
                          float* __restrict__ h_bufs, float* __restrict__ c_buf,
                          int* __restrict__ flags)
{
  long i0 = (long)blockIdx.x*256 + threadIdx.x;
  long stride = (long)gridDim.x*256;
  for (long i=i0; i<(long)NE*ND;   i+=stride) W1_b[i]  = f2bf(W1[i]);
  for (long i=i0; i<(long)NE*NE;   i+=stride) W2_b[i]  = f2bf(W2[i]);
  for (long i=i0; i<(long)4*NH*NE; i+=stride) Wih_b[i] = f2bf(Wih[i]);
  for (long i=i0; i<128*1024; i+=stride){
    int n = (int)(i>>10), k = (int)(i&1023);
    Whead_b[i] = f2bf(n<64 ? Wa[i] : (n==64 ? Wc[k] : 0.f));
  }
  for (long i=i0; i<4096; i+=stride) bias_xg[i] = b_ih[i] + b_hh[i];
  for (long i=i0; i<65;   i+=stride) bias_heads[i] = (i<64) ? ba[i] : bc[0];
  for (long i=i0; i<NB*NH; i+=stride){ h_bufs[i] = hxs[i]; c_buf[i] = cxs[i]; }
  for (long i=i0; i<8192; i+=stride) flags[i] = 0;
}

__global__ void f2b_obs_chunk(const float* __restrict__ obs, unsigned short* __restrict__ dst,
                              int lgTc, int t0){
  const int Tc = 1 << lgTc;
  const long n = (long)NB * Tc * ND;
  long i = (long)blockIdx.x*blockDim.x + threadIdx.x;
  long stride = (long)gridDim.x*blockDim.x;
  for (; i < n; i += stride){
    long lr = i >> 8;
    int col = (int)(i & 255);
    long gr = (lr >> lgTc)*NT + t0 + (lr & (Tc-1));
    dst[i] = f2bf(obs[gr*ND + col]);
  }
}

__global__ void sentinel_kernel(float* __restrict__ out){ out[0] = 1.0e6f; }

// ---------------- bf16 MFMA GEMM (r5-verified): 128x128, dbuf LDS, 2-phase prefetch ----------------
#define GEMM_COMPUTE(P) { \
  bf16x8 af[4], bfr[4]; \
  _Pragma("unroll") for (int f=0; f<4; f++){ \
    af[f]  = *(const bf16x8*)&As[P][(wm*64 + f*16 + fr)*32 + kf]; \
    bfr[f] = *(const bf16x8*)&Bs[P][(wn*64 + f*16 + fr)*32 + kf]; } \
  _Pragma("unroll") for (int i=0;i<4;i++) \
    _Pragma("unroll") for (int j=0;j<4;j++) \
      acc[i][j] = __builtin_amdgcn_mfma_f32_16x16x32_bf16(af[i], bfr[j], acc[i][j], 0, 0, 0); }

template<int SILU, int HEADS>
__global__ __launch_bounds__(256)
void gemm_bt(const unsigned short* __restrict__ A, const unsigned short* __restrict__ Bw,
             const float* __restrict__ bias, unsigned short* __restrict__ C,
             float* __restrict__ oLogits, float* __restrict__ oValues,
             int K, int N, int Nreal)
{
  __shared__ __align__(16) unsigned short As[2][128*32];
  __shared__ __align__(16) unsigned short Bs[2][128*32];
  const int tid = threadIdx.x;
  const int lane = tid & 63;
  const int w = tid >> 6;
  const int wm = w >> 1, wn = w & 1;
  const int m0 = blockIdx.x * 128, n0 = blockIdx.y * 128;
  f32x4 acc[4][4];
#pragma unroll
  for (int i=0;i<4;i++)
#pragma unroll
    for (int j=0;j<4;j++){ f32x4 z = {0.f,0.f,0.f,0.f}; acc[i][j] = z; }
  const int fr = lane & 15;
  const int kf = (lane >> 4) * 8;
  const int r0 = tid >> 2, s0 = tid & 3;
  const unsigned short* gA0 = A  + (size_t)(m0+r0)*K    + s0*8;
  const unsigned short* gA1 = A  + (size_t)(m0+r0+64)*K + s0*8;
  const unsigned short* gB0 = Bw + (size_t)(n0+r0)*K    + s0*8;
  const unsigned short* gB1 = Bw + (size_t)(n0+r0+64)*K + s0*8;

  auto stage = [&](int p, int k0){
    char* a = (char*)&As[p][0] + w*1024;
    char* b = (char*)&Bs[p][0] + w*1024;
    gload_lds16(gA0 + k0, a);
    gload_lds16(gA1 + k0, a + 4096);
    gload_lds16(gB0 + k0, b);
    gload_lds16(gB1 + k0, b + 4096);
  };

  stage(0, 0);
  asm volatile("s_waitcnt vmcnt(0)" ::: "memory");
  __syncthreads();
  int cur = 0;
  for (int k0 = 32; k0 < K; k0 += 32){
    stage(cur ^ 1, k0);
    GEMM_COMPUTE(cur);
    asm volatile("s_waitcnt vmcnt(0)" ::: "memory");
    __syncthreads();
    cur ^= 1;
  }
  GEMM_COMPUTE(cur);

  const int mb = (lane >> 4) * 4;
  const int nb = lane & 15;
#pragma unroll
  for (int i=0;i<4;i++)
#pragma unroll
    for (int j=0;j<4;j++)
#pragma unroll
      for (int r=0;r<4;r++){
        int m = m0 + wm*64 + i*16 + mb + r;
        int n = n0 + wn*64 + j*16 + nb;
        if (HEADS && n >= Nreal) continue;
        float v = acc[i][j][r] + bias[n];
        if (SILU) v = v / (1.f + expf(-v));
        if (!HEADS) {
          C[(size_t)m*N + n] = f2bf(v);
        } else {
          if (n < 64) oLogits[(size_t)m*64 + n] = v;
          else if (n == 64) oValues[m] = v;
        }
      }
}

// ---------------- LSTM: persistent MFMA kernel, per-producer flags ----------------
// 256 WGs x 512 thr, 1 block/CU. WG (bh=wg&1, ug=wg>>1): batches b0=bh*16..+16,
// units n0w=ug*8..+8 (32 gate rows). W hi/lo bf16 fragments staged once in LDS.
// Wave wv owns k-slice [wv*128,+128) -> its producers are WGs ug' in [wv*16,+16), same bh.
// Barrier: WG stores flags[wg*32]=t+1 (bypass) after step t; each wave polls only
// its 16 producers (>= t) before loading h. No atomics, no global release.
__global__ __launch_bounds__(512)
void lstm_mfma(const unsigned short* __restrict__ xg, const float* __restrict__ Whh,
               float* __restrict__ h_bufs, float* __restrict__ c_buf,
               unsigned short* __restrict__ hist, float* __restrict__ dh, float* __restrict__ dc,
               int* __restrict__ flags, int t0, int t1, int Tc)
{
  extern __shared__ char smem[];
  unsigned short* Wf = (unsigned short*)smem;          // [term][kt 32][nt 2][lane 64] x 8 ushort
  float* red = (float*)(smem + 131072);                // [batch 16][row 32][wv 9] (pad 9)
  const int wg = blockIdx.x;
  const int bh = wg & 1, ug = wg >> 1;
  const int b0 = bh*16, n0w = ug*8;
  const int tid = threadIdx.x;
  const int lane = tid & 63;
  const int wv = tid >> 6;
  const int fr = lane & 15;
  const int q8 = (lane >> 4) * 8;

  // ---- one-time: stage W hi/lo fragments ----
  for (int s = tid; s < 8192; s += 512){
    int term = s >> 12, kt = (s >> 7) & 31, nt = (s >> 6) & 1, l = s & 63;
    int r = nt*16 + (l & 15);
    int g = r >> 3, uu2 = r & 7;
    const float* src = Whh + (size_t)(g*NH + n0w + uu2)*NH + kt*32 + (l>>4)*8;
    u16x8 o;
#pragma unroll
    for (int j=0;j<8;j++){
      float wv_ = src[j];
      unsigned short hi = f2bf(wv_);
      o[j] = (term==0) ? hi : f2bf(wv_ - bf2f(hi));
    }
    *(u16x8*)&Wf[(size_t)s*8] = o;
  }

  // epilogue ownership: lanes 0..15 of EVERY wave; pair = (bl, uu)
  const int bl = wv*2 + (lane >> 3);   // batch-local 0..15 (lane<16)
  const int uu = lane & 7;             // unit 0..7
  float c_reg = 0.f, h_keep = 0.f;
  if (lane < 16) c_reg = c_buf[(b0 + bl)*NH + n0w + uu];
  __syncthreads();

  for (int t = t0; t < t1; t++){
    const float* hb = h_bufs + (size_t)(t & 1)*(NB*NH);
    float* hb_next  = h_bufs + (size_t)((t+1)&1)*(NB*NH);
    const int tl = t - t0;

    // xg prefetch (before poll; independent of h)
    float xgv[4] = {0.f,0.f,0.f,0.f};
    if (lane < 16){
      size_t xbase = ((size_t)(b0+bl)*Tc + tl)*4096 + n0w + uu;
#pragma unroll
      for (int g=0; g<4; g++) xgv[g] = bf2f(xg[xbase + g*1024]);
    }

    // ---- per-wave producer poll: wait my 16 producers finished step t-1 ----
    {
      const int pw = ((wv*16 + fr)*2 + bh) * 32;
      while (true){
        int v = bypass_load_i32(&flags[pw]);
        v = min(v, __shfl_xor(v, 1));
        v = min(v, __shfl_xor(v, 2));
        v = min(v, __shfl_xor(v, 4));
        v = min(v, __shfl_xor(v, 8));
        if (v >= t) break;
        __builtin_amdgcn_s_sleep(1);
      }
    }

    // ---- h A-frag loads: wave's 128-k slice, batch row fr ----
    f32x4 hv[8];
#pragma unroll
    for (int ks=0; ks<4; ks++){
      const float* p = hb + (size_t)(b0 + fr)*NH + (wv*4 + ks)*32 + q8;
      hv[ks*2]   = bypass_load_f32x4(p);
      hv[ks*2+1] = bypass_load_f32x4(p + 4);
    }
    asm volatile("s_waitcnt vmcnt(0)" ::: "memory");
    __builtin_amdgcn_sched_barrier(0);

    bf16x8 ahi[4], alo[4];
#pragma unroll
    for (int ks=0; ks<4; ks++) make_frags(hv[2*ks], hv[2*ks+1], ahi[ks], alo[ks]);

    f32x4 acc[2];
    { f32x4 z = {0.f,0.f,0.f,0.f}; acc[0] = z; acc[1] = z; }
#pragma unroll
    for (int ks=0; ks<4; ks++){
      int kt = wv*4 + ks;
#pragma unroll
      for (int nt=0; nt<2; nt++){
        bf16x8 bhi = *(const bf16x8*)&Wf[kt*1024 + nt*512 + lane*8];
        bf16x8 blo = *(const bf16x8*)&Wf[32768 + kt*1024 + nt*512 + lane*8];
        acc[nt] = __builtin_amdgcn_mfma_f32_16x16x32_bf16(ahi[ks], bhi, acc[nt], 0,0,0);
        acc[nt] = __builtin_amdgcn_mfma_f32_16x16x32_bf16(ahi[ks], blo, acc[nt], 0,0,0);
        acc[nt] = __builtin_amdgcn_mfma_f32_16x16x32_bf16(alo[ks], bhi, acc[nt], 0,0,0);
      }
    }

    // ---- cross-wave reduce: partials to LDS ([16][32][9] layout, 4-way max) ----
#pragma unroll
    for (int nt=0; nt<2; nt++)
#pragma unroll
      for (int r4=0; r4<4; r4++){
        int batch = (lane>>4)*4 + r4;
        red[batch*288 + (nt*16 + fr)*9 + wv] = acc[nt][r4];
      }
    __syncthreads();

    // ---- epilogue: lanes 0..15 of every wave, one (batch, unit) each ----
    if (lane < 16){
      float gate[4];
#pragma unroll
      for (int g=0; g<4; g++){
        const float* rp = &red[bl*288 + (g*8 + uu)*9];
        float s = 0.f;
#pragma unroll
        for (int w8=0; w8<8; w8++) s += rp[w8];
        gate[g] = s + xgv[g];
      }
      float iv = 1.f/(1.f+expf(-gate[0]));
      float fv = 1.f/(1.f+expf(-gate[1]));
      float gv = tanhf(gate[2]);
      float ov = 1.f/(1.f+expf(-gate[3]));
      float c_new = fv*c_reg + iv*gv;
      float h_new = ov*tanhf(c_new);
      c_reg = c_new; h_keep = h_new;
      float h0 = __shfl(h_new, (lane & ~3) + 0);
      float h1 = __shfl(h_new, (lane & ~3) + 1);
      float h2 = __shfl(h_new, (lane & ~3) + 2);
      float h3 = __shfl(h_new, (lane & ~3) + 3);
      if ((lane & 3) == 0){
        f32x4 hvv = { h0, h1, h2, h3 };
        bypass_store_f32x4(hb_next + (size_t)(b0+bl)*NH + n0w + uu, hvv);
        u16x4 hp; hp[0]=f2bf(h0); hp[1]=f2bf(h1); hp[2]=f2bf(h2); hp[3]=f2bf(h3);
        *(u16x4*)&hist[((size_t)(b0+bl)*Tc + tl)*NH + n0w + uu] = hp;
      }
    }
    // ---- publish: barrier drains every wave's stores, then single flag store ----
    __syncthreads();
    if (tid == 0) bypass_store_i32(&flags[wg*32], t+1);
  }
  if (lane < 16){
    c_buf[(b0+bl)*NH + n0w + uu] = c_reg;
    if (t1 == NT){ dh[(b0+bl)*NH + n0w + uu] = h_keep; dc[(b0+bl)*NH + n0w + uu] = c_reg; }
  }
}

// ---------------- LSTM fallback: r5-verified VALU persistent kernel (static 64KB LDS) ----------------
#define SEL4(A0,A1,A2,A3) ((kc&2)?((kc&1)?(A3):(A2)):((kc&1)?(A1):(A0)))

__global__ __launch_bounds__(512)
void lstm_valu(const unsigned short* __restrict__ xg, const float* __restrict__ Whh,
               float* __restrict__ h_bufs, float* __restrict__ c_buf,
               unsigned short* __restrict__ hist, float* __restrict__ dh, float* __restrict__ dc,
               int* __restrict__ cnt, int t0, int t1, int Tc)
{
  __shared__ __align__(16) float Wl[16*1024];
  const int wg = blockIdx.x;
  const int n0w = wg * 4;
  const int tid = threadIdx.x;
  const int lane = tid & 63;
  const int wv = tid >> 6;
  const int kc = lane & 15;
  const int b = wv*4 + (lane >> 4);

  for (int i = tid*4; i < 16*1024; i += 2048){
    int r = i >> 10, k = i & 1023;
    int grow = (r>>2)*NH + n0w + (r&3);
    *(f32x4*)&Wl[i] = *(const f32x4*)&Whh[(size_t)grow*NH + k];
  }
  float c_reg = 0.f, h_keep = 0.f;
  if (kc < 4) c_reg = c_buf[b*NH + n0w + kc];
  __syncthreads();

  for (int t = t0; t < t1; t++){
    const float* hb = h_bufs + (size_t)(t&1)*(NB*NH);
    float* hb_next  = h_bufs + (size_t)((t+1)&1)*(NB*NH);
    const int tl = t - t0;
    float xgi=0.f, xgf=0.f, xgg=0.f, xgo=0.f;
    if (kc < 4){
      size_t xbase = ((size_t)b*Tc + tl)*4096 + n0w + kc;
      xgi = bf2f(xg[xbase]);
      xgf = bf2f(xg[xbase + 1024]);
      xgg = bf2f(xg[xbase + 2048]);
      xgo = bf2f(xg[xbase + 3072]);
    }
    if (wv == 0){
      const int target = 256*t;
      while (true){
        int v = 0;
        if (lane < 16) v = bypass_load_i32(&cnt[lane*64]);
        v += __shfl_xor(v,1); v += __shfl_xor(v,2); v += __shfl_xor(v,4);
        v += __shfl_xor(v,8); v += __shfl_xor(v,16); v += __shfl_xor(v,32);
        if (v >= target) break;
        __builtin_amdgcn_s_sleep(1);
      }
    }
    __syncthreads();

    f32x4 hq[16];
    const float* hrow = hb + (size_t)b*NH + kc*4;
#pragma unroll
    for (int kk=0; kk<16; kk++) hq[kk] = bypass_load_f32x4(hrow + kk*64);

    float acc[16];
#pragma unroll
    for (int r=0;r<16;r++) acc[r] = 0.f;
#pragma unroll
    for (int g=0; g<4; g++){
      if (g==0){ asm volatile("s_waitcnt vmcnt(12)" ::: "memory"); }
      else if (g==1){ asm volatile("s_waitcnt vmcnt(8)" ::: "memory"); }
      else if (g==2){ asm volatile("s_waitcnt vmcnt(4)" ::: "memory"); }
      else { asm volatile("s_waitcnt vmcnt(0)" ::: "memory"); }
      __builtin_amdgcn_sched_barrier(0);
#pragma unroll
      for (int kq=0; kq<4; kq++){
        const int kk = g*4 + kq;
#pragma unroll
        for (int r=0;r<16;r++){
          f32x4 wq = *(const f32x4*)&Wl[r*1024 + kk*64 + kc*4];
          acc[r] = fmaf(wq[0],hq[kk][0], fmaf(wq[1],hq[kk][1],
                   fmaf(wq[2],hq[kk][2], fmaf(wq[3],hq[kk][3], acc[r]))));
        }
      }
    }
#pragma unroll
    for (int r=0;r<16;r++){
      float v = acc[r];
      v += __shfl_xor(v, 1);
      v += __shfl_xor(v, 2);
      v += __shfl_xor(v, 4);
      v += __shfl_xor(v, 8);
      acc[r] = v;
    }
    float gi = SEL4(acc[0], acc[1], acc[2], acc[3])   + xgi;
    float gf = SEL4(acc[4], acc[5], acc[6], acc[7])   + xgf;
    float gg = SEL4(acc[8], acc[9], acc[10], acc[11]) + xgg;
    float go = SEL4(acc[12],acc[13],acc[14],acc[15])  + xgo;
    float iv = 1.f/(1.f+expf(-gi));
    float fv = 1.f/(1.f+expf(-gf));
    float gv = tanhf(gg);
    float ov = 1.f/(1.f+expf(-go));
    float c_new = fv*c_reg + iv*gv;
    float h_new = ov*tanhf(c_new);
    if (kc < 4){ c_reg = c_new; h_keep = h_new; }
    const int base = lane & 48;
    float h0 = __shfl(h_new, base + 0);
    float h1 = __shfl(h_new, base + 1);
    float h2 = __shfl(h_new, base + 2);
    float h3 = __shfl(h_new, base + 3);
    if (kc == 0){
      f32x4 hvv = { h0, h1, h2, h3 };
      bypass_store_f32x4(hb_next + (size_t)b*NH + n0w, hvv);
      u16x4 hp;
      hp[0] = f2bf(h0); hp[1] = f2bf(h1); hp[2] = f2bf(h2); hp[3] = f2bf(h3);
      *(u16x4*)&hist[((size_t)b*Tc + tl)*NH + n0w] = hp;
    }
    asm volatile("s_waitcnt vmcnt(0)" ::: "memory");
    __syncthreads();
    if (tid == 0) atomicAdd(&cnt[(wg & 15) * 64], 1);
  }
  if (kc < 4){
    c_buf[b*NH + n0w + kc] = c_reg;
    if (t1 == NT){ dh[b*NH + n0w + kc] = h_keep; dc[b*NH + n0w + kc] = c_reg; }
  }
}

// ---------------- LayerNorm: wave-per-row (no block barrier), 4 rows/block ----------------
__global__ __launch_bounds__(256)
void ln_chunk(const unsigned short* __restrict__ X, const float* __restrict__ gam, const float* __restrict__ bet,
              unsigned short* __restrict__ Y, int lgTc, int t0)
{
  const int Tc = 1 << lgTc;
  const int row = blockIdx.x*4 + (threadIdx.x >> 6);   // local row
  const int lane = threadIdx.x & 63;
  const int bl = row >> lgTc, tl = row & (Tc-1);
  const long grow = (long)bl*NT + t0 + tl;
  u16x8 a0 = *(const u16x8*)&X[(size_t)row*NH + lane*16];
  u16x8 a1 = *(const u16x8*)&X[(size_t)row*NH + lane*16 + 8];
  float x[16];
  float s = 0.f;
#pragma unroll
  for (int j=0;j<8;j++){ x[j] = bf2f(a0[j]); x[8+j] = bf2f(a1[j]); }
#pragma unroll
  for (int j=0;j<16;j++) s += x[j];
  s += __shfl_xor(s,1); s += __shfl_xor(s,2); s += __shfl_xor(s,4);
  s += __shfl_xor(s,8); s += __shfl_xor(s,16); s += __shfl_xor(s,32);
  const float mean = s * (1.0f/NH);
  float q = 0.f;
#pragma unroll
  for (int j=0;j<16;j++){ float d = x[j]-mean; q += d*d; }
  q += __shfl_xor(q,1); q += __shfl_xor(q,2); q += __shfl_xor(q,4);
  q += __shfl_xor(q,8); q += __shfl_xor(q,16); q += __shfl_xor(q,32);
  const float rs = 1.f / sqrtf(q * (1.0f/NH) + 1e-5f);
  f32x4 g0 = *(const f32x4*)&gam[lane*16];
  f32x4 g1 = *(const f32x4*)&gam[lane*16+4];
  f32x4 g2 = *(const f32x4*)&gam[lane*16+8];
  f32x4 g3 = *(const f32x4*)&gam[lane*16+12];
  f32x4 b0 = *(const f32x4*)&bet[lane*16];
  f32x4 b1 = *(const f32x4*)&bet[lane*16+4];
  f32x4 b2 = *(const f32x4*)&bet[lane*16+8];
  f32x4 b3 = *(const f32x4*)&bet[lane*16+12];
  u16x8 o0, o1;
#pragma unroll
  for (int j=0;j<4;j++){
    o0[j]   = f2bf((x[j]   -mean)*rs*g0[j] + b0[j]);
    o0[4+j] = f2bf((x[4+j] -mean)*rs*g1[j] + b1[j]);
    o1[j]   = f2bf((x[8+j] -mean)*rs*g2[j] + b2[j]);
    o1[4+j] = f2bf((x[12+j]-mean)*rs*g3[j] + b3[j]);
  }
  *(u16x8*)&Y[(size_t)grow*NH + lane*16]     = o0;
  *(u16x8*)&Y[(size_t)grow*NH + lane*16 + 8] = o1;
}

// ---------------- ar / tar losses ----------------
__global__ __launch_bounds__(256)
void loss_partial(const unsigned short* __restrict__ Yu, float* __restrict__ partials)
{
  float ar = 0.f, tar = 0.f;
  long stride = (long)gridDim.x*256;
  for (long vv = (long)blockIdx.x*256 + threadIdx.x; vv < 2097152; vv += stride){
    long i = vv*8;
    int t = (int)((i >> 10) & 511);
    u16x8 y = *(const u16x8*)&Yu[i];
    float x[8];
#pragma unroll
    for (int q=0;q<8;q++){ x[q] = bf2f(y[q]); ar += x[q]*x[q]; }
    if (t > 0){
      u16x8 yp = *(const u16x8*)&Yu[i - 1024];
#pragma unroll
      for (int q=0;q<8;q++){ float d = x[q] - bf2f(yp[q]); tar += d*d; }
    }
  }
  ar += __shfl_xor(ar,1); ar += __shfl_xor(ar,2); ar += __shfl_xor(ar,4);
  ar += __shfl_xor(ar,8); ar += __shfl_xor(ar,16); ar += __shfl_xor(ar,32);
  tar += __shfl_xor(tar,1); tar += __shfl_xor(tar,2); tar += __shfl_xor(tar,4);
  tar += __shfl_xor(tar,8); tar += __shfl_xor(tar,16); tar += __shfl_xor(tar,32);
  __shared__ float red[16];
  int w = threadIdx.x >> 6;
  if ((threadIdx.x & 63) == 0){ red[w] = ar; red[8+w] = tar; }
  __syncthreads();
  if (threadIdx.x == 0){
    partials[blockIdx.x*2]   = red[0]+red[1]+red[2]+red[3];
    partials[blockIdx.x*2+1] = red[8]+red[9]+red[10]+red[11];
  }
}

__global__ __launch_bounds__(256)
void loss_final(const float* __restrict__ partials, float* __restrict__ oAr, float* __restrict__ oTar){
  double sa = 0.0, st = 0.0;
  for (int i = threadIdx.x; i < 1024; i += 256){ sa += (double)partials[2*i]; st += (double)partials[2*i+1]; }
  for (int m=1;m<64;m<<=1){ sa += __shfl_xor(sa, m); st += __shfl_xor(st, m); }
  __shared__ double rd[8];
  int w = threadIdx.x >> 6;
  if ((threadIdx.x & 63) == 0){ rd[w] = sa; rd[4+w] = st; }
  __syncthreads();
  if (threadIdx.x == 0){
    double a  = rd[0]+rd[1]+rd[2]+rd[3];
    double tt = rd[4]+rd[5]+rd[6]+rd[7];
    oAr[0]  = (float)(a  / 16777216.0 * 0.01);
    oTar[0] = (float)(tt / 16744448.0 * 0.01);
  }
}

// ---------------- launch ----------------
extern "C" void kernel_launch(void* const* d_in, const int* in_sizes, int n_in,
                              void* d_out, int out_size, void* d_ws, size_t ws_size,
                              hipStream_t stream)
{
  const float* obs  = (const float*)d_in[0];
  const float* hxs  = (const float*)d_in[1];
  const float* cxs  = (const float*)d_in[2];
  const float* W1   = (const float*)d_in[3];
  const float* b1   = (const float*)d_in[4];
  const float* W2   = (const float*)d_in[5];
  const float* b2   = (const float*)d_in[6];
  const float* W_ih = (const float*)d_in[7];
  const float* W_hh = (const float*)d_in[8];
  const float* b_ih = (const float*)d_in[9];
  const float* b_hh = (const float*)d_in[10];
  const float* ln_g = (const float*)d_in[11];
  const float* ln_b = (const float*)d_in[12];
  const float* Wa   = (const float*)d_in[13];
  const float* ba   = (const float*)d_in[14];
  const float* Wc   = (const float*)d_in[15];
  const float* bc   = (const float*)d_in[16];

  char* ws = (char*)d_ws;
  size_t off = 0;
  auto alloc = [&](size_t bytes)->char*{
    char* p = ws + off;
    off = (off + bytes + 255) & ~(size_t)255;
    return p;
  };
  unsigned short* W1_b    = (unsigned short*)alloc((size_t)NE*ND*2);
  unsigned short* W2_b    = (unsigned short*)alloc((size_t)NE*NE*2);
  unsigned short* Wih_b   = (unsigned short*)alloc((size_t)4*NH*NE*2);
  unsigned short* Whead_b = (unsigned short*)alloc((size_t)128*NH*2);
  float* bias_heads       = (float*)alloc(65*4);
  float* bias_xg          = (float*)alloc(4096*4);
  unsigned short* outln_b = (unsigned short*)alloc((size_t)NB*NT*NH*2);   // 32 MB
  float* h_bufs           = (float*)alloc((size_t)2*NB*NH*4);
  float* c_buf            = (float*)alloc((size_t)NB*NH*4);
  int*   flags            = (int*)alloc(8192*4);
  float* partials         = (float*)alloc((size_t)1024*2*4);
  const size_t fixedEnd = off;

  int lg = -1;
  for (int L = 9; L >= 4; --L){
    size_t Mc = (size_t)NB << L;
    size_t per = Mc*ND*2 + 2*(Mc*NE*2) + Mc*4096*2 + Mc*NH*2 + 6*256;
    if (fixedEnd + per <= ws_size){ lg = L; break; }
  }
  if (lg < 0){ sentinel_kernel<<<1,1,0,stream>>>((float*)d_out); return; }
  const int Tc = 1 << lg;
  const int Mc = NB << lg;
  const int nChunks = NT >> lg;

  unsigned short* obs_c  = (unsigned short*)alloc((size_t)Mc*ND*2);
  unsigned short* enc1_c = (unsigned short*)alloc((size_t)Mc*NE*2);
  unsigned short* enc2_c = (unsigned short*)alloc((size_t)Mc*NE*2);
  unsigned short* xg_c   = (unsigned short*)alloc((size_t)Mc*4096*2);
  unsigned short* hist_c = (unsigned short*)alloc((size_t)Mc*NH*2);

  float* o = (float*)d_out;
  float* oLogits = o;
  float* oValues = o + (size_t)NB*NT*64;
  float* oH  = oValues + NB*NT;
  float* oC  = oH + NB*NH;
  float* oAr = oC + NB*NH;
  float* oTar= oAr + 1;

  mega_prep<<<2048,256,0,stream>>>(W1, W2, W_ih, Wa, Wc, ba, bc, b_ih, b_hh, hxs, cxs,
                                   W1_b, W2_b, Wih_b, Whead_b, bias_heads, bias_xg,
                                   h_bufs, c_buf, flags);

  for (int c = 0; c < nChunks; ++c){
    int t0 = c << lg, t1 = t0 + Tc;
    f2b_obs_chunk<<<512,256,0,stream>>>(obs, obs_c, lg, t0);
    gemm_bt<1,0><<<dim3(Mc/128,8) ,256,0,stream>>>(obs_c,  W1_b,  b1,      enc1_c, nullptr, nullptr, ND, NE, NE);
    gemm_bt<1,0><<<dim3(Mc/128,8) ,256,0,stream>>>(enc1_c, W2_b,  b2,      enc2_c, nullptr, nullptr, NE, NE, NE);
    gemm_bt<0,0><<<dim3(Mc/128,32),256,0,stream>>>(enc2_c, Wih_b, bias_xg, xg_c,   nullptr, nullptr, NE, 4096, 4096);

    (void)hipGetLastError();  // clear stale error state
    lstm_mfma<<<256,512,LSTM_SMEM,stream>>>(xg_c, W_hh, h_bufs, c_buf, hist_c, oH, oC, flags, t0, t1, Tc);
    if (hipGetLastError() != hipSuccess)
      lstm_valu<<<256,512,0,stream>>>(xg_c, W_hh, h_bufs, c_buf, hist_c, oH, oC, flags, t0, t1, Tc);

    ln_chunk<<<Mc/4,256,0,stream>>>(hist_c, ln_g, ln_b, outln_b, lg, t0);
  }

  gemm_bt<0,1><<<dim3(128,1),256,0,stream>>>(outln_b, Whead_b, bias_heads, nullptr, oLogits, oValues, NH, 128, 65);
  loss_partial<<<1024,256,0,stream>>>(outln_b, partials);
  loss_final<<<1,256,0,stream>>>(partials, oAr, oTar);
}

// Round 8
// 2213.029 us; speedup vs baseline: 10.7093x; 1.1598x over previous
//
#include <hip/hip_runtime.h>

typedef __attribute__((ext_vector_type(8))) short bf16x8;
typedef __attribute__((ext_vector_type(8))) unsigned short u16x8;
typedef __attribute__((ext_vector_type(4))) unsigned short u16x4;
typedef __attribute__((ext_vector_type(4))) float f32x4;
typedef __attribute__((ext_vector_type(2))) unsigned int u32x2;

#define NB 32
#define NT 512
#define ND 256
#define NE 1024
#define NH 1024
#define LSTM_SMEM (131072 + 18432)   // W frags (hi+lo) + reduce buffer [16][32][9] f32

__device__ __forceinline__ float bf2f(unsigned short u){
  union { unsigned int i; float f; } w; w.i = ((unsigned int)u) << 16; return w.f;
}
__device__ __forceinline__ unsigned short f2bf(float f){
  union { float f; unsigned int i; } w; w.f = f;
  unsigned int r = (w.i >> 16) & 1u;
  return (unsigned short)((w.i + 0x7fffu + r) >> 16);
}

// ---- cache-bypass (coherence-point) memory ops ----
__device__ __forceinline__ bf16x8 bypass_load_b128(const unsigned short* p){
  bf16x8 r;
  asm volatile("global_load_dwordx4 %0, %1, off sc0 sc1" : "=v"(r) : "v"(p) : "memory");
  return r;  // caller must s_waitcnt before use
}
__device__ __forceinline__ int bypass_load_i32(const int* p){
  int r;
  asm volatile("global_load_dword %0, %1, off sc0 sc1\n\ts_waitcnt vmcnt(0)"
               : "=v"(r) : "v"(p) : "memory");
  return r;
}
__device__ __forceinline__ void bypass_store_b64(unsigned short* p, u32x2 v){
  asm volatile("global_store_dwordx2 %0, %1, off sc0 sc1" :: "v"(p), "v"(v) : "memory");
}
__device__ __forceinline__ void bypass_store_i32(int* p, int v){
  asm volatile("global_store_dword %0, %1, off sc0 sc1" :: "v"(p), "v"(v) : "memory");
}

// ---- global_load_lds width=16 (m97 pattern) ----
__device__ __forceinline__ void gload_lds16(const void* g, void* l){
  __builtin_amdgcn_global_load_lds(
      (const __attribute__((address_space(1))) void*)g,
      (__attribute__((address_space(3))) void*)l, 16, 0, 0);
}

// ---------------- one-shot prep: weight conversion + state init ----------------
__global__ void mega_prep(const float* __restrict__ W1, const float* __restrict__ W2,
                          const float* __restrict__ Wih,
                          const float* __restrict__ Wa, const float* __restrict__ Wc,
                          const float* __restrict__ ba, const float* __restrict__ bc,
                          const float* __restrict__ b_ih, const float* __restrict__ b_hh,
                          const float* __restrict__ hxs, const float* __restrict__ cxs,
                          unsigned short* __restrict__ W1_b, unsigned short* __restrict__ W2_b,
                          unsigned short* __restrict__ Wih_b, unsigned short* __restrict__ Whead_b,
                          float* __restrict__ bias_heads, float* __restrict__ bias_xg,
                          unsigned short* __restrict__ h16, float* __restrict__ c_buf,
                          int* __restrict__ flags)
{
  long i0 = (long)blockIdx.x*256 + threadIdx.x;
  long stride = (long)gridDim.x*256;
  for (long i=i0; i<(long)NE*ND;   i+=stride) W1_b[i]  = f2bf(W1[i]);
  for (long i=i0; i<(long)NE*NE;   i+=stride) W2_b[i]  = f2bf(W2[i]);
  for (long i=i0; i<(long)4*NH*NE; i+=stride) Wih_b[i] = f2bf(Wih[i]);
  for (long i=i0; i<128*1024; i+=stride){
    int n = (int)(i>>10), k = (int)(i&1023);
    Whead_b[i] = f2bf(n<64 ? Wa[i] : (n==64 ? Wc[k] : 0.f));
  }
  for (long i=i0; i<4096; i+=stride) bias_xg[i] = b_ih[i] + b_hh[i];
  for (long i=i0; i<65;   i+=stride) bias_heads[i] = (i<64) ? ba[i] : bc[0];
  for (long i=i0; i<NB*NH; i+=stride){ h16[i] = f2bf(hxs[i]); c_buf[i] = cxs[i]; }
  for (long i=i0; i<8192; i+=stride) flags[i] = 0;
}

__global__ void f2b_obs_chunk(const float* __restrict__ obs, unsigned short* __restrict__ dst,
                              int lgTc, int t0){
  const int Tc = 1 << lgTc;
  const long n = (long)NB * Tc * ND;
  long i = (long)blockIdx.x*blockDim.x + threadIdx.x;
  long stride = (long)gridDim.x*blockDim.x;
  for (; i < n; i += stride){
    long lr = i >> 8;
    int col = (int)(i & 255);
    long gr = (lr >> lgTc)*NT + t0 + (lr & (Tc-1));
    dst[i] = f2bf(obs[gr*ND + col]);
  }
}

__global__ void sentinel_kernel(float* __restrict__ out){ out[0] = 1.0e6f; }

// ---------------- bf16 MFMA GEMM (r5-verified): 128x128, dbuf LDS, 2-phase prefetch ----------------
#define GEMM_COMPUTE(P) { \
  bf16x8 af[4], bfr[4]; \
  _Pragma("unroll") for (int f=0; f<4; f++){ \
    af[f]  = *(const bf16x8*)&As[P][(wm*64 + f*16 + fr)*32 + kf]; \
    bfr[f] = *(const bf16x8*)&Bs[P][(wn*64 + f*16 + fr)*32 + kf]; } \
  _Pragma("unroll") for (int i=0;i<4;i++) \
    _Pragma("unroll") for (int j=0;j<4;j++) \
      acc[i][j] = __builtin_amdgcn_mfma_f32_16x16x32_bf16(af[i], bfr[j], acc[i][j], 0, 0, 0); }

template<int SILU, int HEADS>
__global__ __launch_bounds__(256)
void gemm_bt(const unsigned short* __restrict__ A, const unsigned short* __restrict__ Bw,
             const float* __restrict__ bias, unsigned short* __restrict__ C,
             float* __restrict__ oLogits, float* __restrict__ oValues,
             int K, int N, int Nreal)
{
  __shared__ __align__(16) unsigned short As[2][128*32];
  __shared__ __align__(16) unsigned short Bs[2][128*32];
  const int tid = threadIdx.x;
  const int lane = tid & 63;
  const int w = tid >> 6;
  const int wm = w >> 1, wn = w & 1;
  const int m0 = blockIdx.x * 128, n0 = blockIdx.y * 128;
  f32x4 acc[4][4];
#pragma unroll
  for (int i=0;i<4;i++)
#pragma unroll
    for (int j=0;j<4;j++){ f32x4 z = {0.f,0.f,0.f,0.f}; acc[i][j] = z; }
  const int fr = lane & 15;
  const int kf = (lane >> 4) * 8;
  const int r0 = tid >> 2, s0 = tid & 3;
  const unsigned short* gA0 = A  + (size_t)(m0+r0)*K    + s0*8;
  const unsigned short* gA1 = A  + (size_t)(m0+r0+64)*K + s0*8;
  const unsigned short* gB0 = Bw + (size_t)(n0+r0)*K    + s0*8;
  const unsigned short* gB1 = Bw + (size_t)(n0+r0+64)*K + s0*8;

  auto stage = [&](int p, int k0){
    char* a = (char*)&As[p][0] + w*1024;
    char* b = (char*)&Bs[p][0] + w*1024;
    gload_lds16(gA0 + k0, a);
    gload_lds16(gA1 + k0, a + 4096);
    gload_lds16(gB0 + k0, b);
    gload_lds16(gB1 + k0, b + 4096);
  };

  stage(0, 0);
  asm volatile("s_waitcnt vmcnt(0)" ::: "memory");
  __syncthreads();
  int cur = 0;
  for (int k0 = 32; k0 < K; k0 += 32){
    stage(cur ^ 1, k0);
    GEMM_COMPUTE(cur);
    asm volatile("s_waitcnt vmcnt(0)" ::: "memory");
    __syncthreads();
    cur ^= 1;
  }
  GEMM_COMPUTE(cur);

  const int mb = (lane >> 4) * 4;
  const int nb = lane & 15;
#pragma unroll
  for (int i=0;i<4;i++)
#pragma unroll
    for (int j=0;j<4;j++)
#pragma unroll
      for (int r=0;r<4;r++){
        int m = m0 + wm*64 + i*16 + mb + r;
        int n = n0 + wn*64 + j*16 + nb;
        if (HEADS && n >= Nreal) continue;
        float v = acc[i][j][r] + bias[n];
        if (SILU) v = v / (1.f + expf(-v));
        if (!HEADS) {
          C[(size_t)m*N + n] = f2bf(v);
        } else {
          if (n < 64) oLogits[(size_t)m*64 + n] = v;
          else if (n == 64) oValues[m] = v;
        }
      }
}

// ---------------- LSTM: persistent MFMA kernel, bf16-h exchange, 3-buffer rotation ----------------
// 256 WGs x 512 thr, 1 block/CU. WG (bh=wg&1, ug=wg>>1): batches b0=bh*16..+16,
// units n0w=ug*8..+8 (32 gate rows). W hi/lo bf16 fragments staged once in LDS.
// h transmitted bf16 (hi only): gate = h_bf16 . (W_hi + W_lo); c stays fp32 local.
// h buffers rotate mod 3 (provably safe vs +-1 WG skew under partial polls).
// Wave wv owns k-slice [wv*128,+128) -> producers = WGs ug' in [wv*16,+16), same bh.
__global__ __launch_bounds__(512)
void lstm_mfma(const unsigned short* __restrict__ xg, const float* __restrict__ Whh,
               unsigned short* __restrict__ h16, float* __restrict__ c_buf,
               unsigned short* __restrict__ hist, float* __restrict__ dh, float* __restrict__ dc,
               int* __restrict__ flags, int t0, int t1, int Tc)
{
  extern __shared__ char smem[];
  unsigned short* Wf = (unsigned short*)smem;          // [term][kt 32][nt 2][lane 64] x 8 ushort
  float* red = (float*)(smem + 131072);                // [batch 16][row 32][wv 9] (pad 9)
  const int wg = blockIdx.x;
  const int bh = wg & 1, ug = wg >> 1;
  const int b0 = bh*16, n0w = ug*8;
  const int tid = threadIdx.x;
  const int lane = tid & 63;
  const int wv = tid >> 6;
  const int fr = lane & 15;
  const int q8 = (lane >> 4) * 8;

  // ---- one-time: stage W hi/lo fragments ----
  for (int s = tid; s < 8192; s += 512){
    int term = s >> 12, kt = (s >> 7) & 31, nt = (s >> 6) & 1, l = s & 63;
    int r = nt*16 + (l & 15);
    int g = r >> 3, uu2 = r & 7;
    const float* src = Whh + (size_t)(g*NH + n0w + uu2)*NH + kt*32 + (l>>4)*8;
    u16x8 o;
#pragma unroll
    for (int j=0;j<8;j++){
      float wv_ = src[j];
      unsigned short hi = f2bf(wv_);
      o[j] = (term==0) ? hi : f2bf(wv_ - bf2f(hi));
    }
    *(u16x8*)&Wf[(size_t)s*8] = o;
  }

  // epilogue ownership: lanes 0..15 of EVERY wave; pair = (bl, uu)
  const int bl = wv*2 + (lane >> 3);   // batch-local 0..15 (lane<16)
  const int uu = lane & 7;             // unit 0..7
  float c_reg = 0.f, h_keep = 0.f;
  if (lane < 16) c_reg = c_buf[(b0 + bl)*NH + n0w + uu];
  __syncthreads();

  int pcur = t0 % 3;                   // buffer holding state tag t0
  for (int t = t0; t < t1; t++){
    const int pnext = (pcur == 2) ? 0 : pcur + 1;
    const unsigned short* hb = h16 + (size_t)pcur  * (NB*NH);
    unsigned short* hb_next  = h16 + (size_t)pnext * (NB*NH);
    const int tl = t - t0;

    // xg prefetch (before poll; independent of h)
    float xgv[4] = {0.f,0.f,0.f,0.f};
    if (lane < 16){
      size_t xbase = ((size_t)(b0+bl)*Tc + tl)*4096 + n0w + uu;
#pragma unroll
      for (int g=0; g<4; g++) xgv[g] = bf2f(xg[xbase + g*1024]);
    }

    // ---- per-wave producer poll: wait my 16 producers finished step t-1 ----
    {
      const int pw = ((wv*16 + fr)*2 + bh) * 32;
      while (true){
        int v = bypass_load_i32(&flags[pw]);
        v = min(v, __shfl_xor(v, 1));
        v = min(v, __shfl_xor(v, 2));
        v = min(v, __shfl_xor(v, 4));
        v = min(v, __shfl_xor(v, 8));
        if (v >= t) break;
        __builtin_amdgcn_s_sleep(1);
      }
    }

    // ---- h A-frag loads: 4 x 16B, land directly as bf16 MFMA A-fragments ----
    bf16x8 a[4];
#pragma unroll
    for (int ks=0; ks<4; ks++)
      a[ks] = bypass_load_b128(hb + (size_t)(b0 + fr)*NH + (wv*4 + ks)*32 + q8);
    asm volatile("s_waitcnt vmcnt(0)" ::: "memory");
    __builtin_amdgcn_sched_barrier(0);

    f32x4 acc[2];
    { f32x4 z = {0.f,0.f,0.f,0.f}; acc[0] = z; acc[1] = z; }
#pragma unroll
    for (int ks=0; ks<4; ks++){
      int kt = wv*4 + ks;
#pragma unroll
      for (int nt=0; nt<2; nt++){
        bf16x8 bhi = *(const bf16x8*)&Wf[kt*1024 + nt*512 + lane*8];
        bf16x8 blo = *(const bf16x8*)&Wf[32768 + kt*1024 + nt*512 + lane*8];
        acc[nt] = __builtin_amdgcn_mfma_f32_16x16x32_bf16(a[ks], bhi, acc[nt], 0,0,0);
        acc[nt] = __builtin_amdgcn_mfma_f32_16x16x32_bf16(a[ks], blo, acc[nt], 0,0,0);
      }
    }

    // ---- cross-wave reduce: partials to LDS ([16][32][9] layout) ----
#pragma unroll
    for (int nt=0; nt<2; nt++)
#pragma unroll
      for (int r4=0; r4<4; r4++){
        int batch = (lane>>4)*4 + r4;
        red[batch*288 + (nt*16 + fr)*9 + wv] = acc[nt][r4];
      }
    __syncthreads();

    // ---- epilogue: lanes 0..15 of every wave, one (batch, unit) each ----
    if (lane < 16){
      float gate[4];
#pragma unroll
      for (int g=0; g<4; g++){
        const float* rp = &red[bl*288 + (g*8 + uu)*9];
        float s = 0.f;
#pragma unroll
        for (int w8=0; w8<8; w8++) s += rp[w8];
        gate[g] = s + xgv[g];
      }
      float iv = 1.f/(1.f+expf(-gate[0]));
      float fv = 1.f/(1.f+expf(-gate[1]));
      float gv = tanhf(gate[2]);
      float ov = 1.f/(1.f+expf(-gate[3]));
      float c_new = fv*c_reg + iv*gv;
      float h_new = ov*tanhf(c_new);
      c_reg = c_new; h_keep = h_new;
      float h0 = __shfl(h_new, (lane & ~3) + 0);
      float h1 = __shfl(h_new, (lane & ~3) + 1);
      float h2 = __shfl(h_new, (lane & ~3) + 2);
      float h3 = __shfl(h_new, (lane & ~3) + 3);
      if ((lane & 3) == 0){
        unsigned short p0 = f2bf(h0), p1 = f2bf(h1), p2 = f2bf(h2), p3 = f2bf(h3);
        u32x2 pk; pk[0] = (unsigned)p0 | ((unsigned)p1 << 16);
        pk[1] = (unsigned)p2 | ((unsigned)p3 << 16);
        bypass_store_b64(hb_next + (size_t)(b0+bl)*NH + n0w + uu, pk);
        u16x4 hp = { p0, p1, p2, p3 };
        *(u16x4*)&hist[((size_t)(b0+bl)*Tc + tl)*NH + n0w + uu] = hp;
      }
    }
    // ---- publish: barrier drains every wave's stores, then single flag store ----
    asm volatile("s_waitcnt vmcnt(0)" ::: "memory");
    __syncthreads();
    if (tid == 0) bypass_store_i32(&flags[wg*32], t+1);
    pcur = pnext;
  }
  if (lane < 16){
    c_buf[(b0+bl)*NH + n0w + uu] = c_reg;
    if (t1 == NT){ dh[(b0+bl)*NH + n0w + uu] = h_keep; dc[(b0+bl)*NH + n0w + uu] = c_reg; }
  }
}

// ---------------- LayerNorm: wave-per-row (no block barrier), 4 rows/block ----------------
__global__ __launch_bounds__(256)
void ln_chunk(const unsigned short* __restrict__ X, const float* __restrict__ gam, const float* __restrict__ bet,
              unsigned short* __restrict__ Y, int lgTc, int t0)
{
  const int Tc = 1 << lgTc;
  const int row = blockIdx.x*4 + (threadIdx.x >> 6);   // local row
  const int lane = threadIdx.x & 63;
  const int bl = row >> lgTc, tl = row & (Tc-1);
  const long grow = (long)bl*NT + t0 + tl;
  u16x8 a0 = *(const u16x8*)&X[(size_t)row*NH + lane*16];
  u16x8 a1 = *(const u16x8*)&X[(size_t)row*NH + lane*16 + 8];
  float x[16];
  float s = 0.f;
#pragma unroll
  for (int j=0;j<8;j++){ x[j] = bf2f(a0[j]); x[8+j] = bf2f(a1[j]); }
#pragma unroll
  for (int j=0;j<16;j++) s += x[j];
  s += __shfl_xor(s,1); s += __shfl_xor(s,2); s += __shfl_xor(s,4);
  s += __shfl_xor(s,8); s += __shfl_xor(s,16); s += __shfl_xor(s,32);
  const float mean = s * (1.0f/NH);
  float q = 0.f;
#pragma unroll
  for (int j=0;j<16;j++){ float d = x[j]-mean; q += d*d; }
  q += __shfl_xor(q,1); q += __shfl_xor(q,2); q += __shfl_xor(q,4);
  q += __shfl_xor(q,8); q += __shfl_xor(q,16); q += __shfl_xor(q,32);
  const float rs = 1.f / sqrtf(q * (1.0f/NH) + 1e-5f);
  f32x4 g0 = *(const f32x4*)&gam[lane*16];
  f32x4 g1 = *(const f32x4*)&gam[lane*16+4];
  f32x4 g2 = *(const f32x4*)&gam[lane*16+8];
  f32x4 g3 = *(const f32x4*)&gam[lane*16+12];
  f32x4 b0 = *(const f32x4*)&bet[lane*16];
  f32x4 b1 = *(const f32x4*)&bet[lane*16+4];
  f32x4 b2 = *(const f32x4*)&bet[lane*16+8];
  f32x4 b3 = *(const f32x4*)&bet[lane*16+12];
  u16x8 o0, o1;
#pragma unroll
  for (int j=0;j<4;j++){
    o0[j]   = f2bf((x[j]   -mean)*rs*g0[j] + b0[j]);
    o0[4+j] = f2bf((x[4+j] -mean)*rs*g1[j] + b1[j]);
    o1[j]   = f2bf((x[8+j] -mean)*rs*g2[j] + b2[j]);
    o1[4+j] = f2bf((x[12+j]-mean)*rs*g3[j] + b3[j]);
  }
  *(u16x8*)&Y[(size_t)grow*NH + lane*16]     = o0;
  *(u16x8*)&Y[(size_t)grow*NH + lane*16 + 8] = o1;
}

// ---------------- ar / tar losses ----------------
__global__ __launch_bounds__(256)
void loss_partial(const unsigned short* __restrict__ Yu, float* __restrict__ partials)
{
  float ar = 0.f, tar = 0.f;
  long stride = (long)gridDim.x*256;
  for (long vv = (long)blockIdx.x*256 + threadIdx.x; vv < 2097152; vv += stride){
    long i = vv*8;
    int t = (int)((i >> 10) & 511);
    u16x8 y = *(const u16x8*)&Yu[i];
    float x[8];
#pragma unroll
    for (int q=0;q<8;q++){ x[q] = bf2f(y[q]); ar += x[q]*x[q]; }
    if (t > 0){
      u16x8 yp = *(const u16x8*)&Yu[i - 1024];
#pragma unroll
      for (int q=0;q<8;q++){ float d = x[q] - bf2f(yp[q]); tar += d*d; }
    }
  }
  ar += __shfl_xor(ar,1); ar += __shfl_xor(ar,2); ar += __shfl_xor(ar,4);
  ar += __shfl_xor(ar,8); ar += __shfl_xor(ar,16); ar += __shfl_xor(ar,32);
  tar += __shfl_xor(tar,1); tar += __shfl_xor(tar,2); tar += __shfl_xor(tar,4);
  tar += __shfl_xor(tar,8); tar += __shfl_xor(tar,16); tar += __shfl_xor(tar,32);
  __shared__ float red[16];
  int w = threadIdx.x >> 6;
  if ((threadIdx.x & 63) == 0){ red[w] = ar; red[8+w] = tar; }
  __syncthreads();
  if (threadIdx.x == 0){
    partials[blockIdx.x*2]   = red[0]+red[1]+red[2]+red[3];
    partials[blockIdx.x*2+1] = red[8]+red[9]+red[10]+red[11];
  }
}

__global__ __launch_bounds__(256)
void loss_final(const float* __restrict__ partials, float* __restrict__ oAr, float* __restrict__ oTar){
  double sa = 0.0, st = 0.0;
  for (int i = threadIdx.x; i < 1024; i += 256){ sa += (double)partials[2*i]; st += (double)partials[2*i+1]; }
  for (int m=1;m<64;m<<=1){ sa += __shfl_xor(sa, m); st += __shfl_xor(st, m); }
  __shared__ double rd[8];
  int w = threadIdx.x >> 6;
  if ((threadIdx.x & 63) == 0){ rd[w] = sa; rd[4+w] = st; }
  __syncthreads();
  if (threadIdx.x == 0){
    double a  = rd[0]+rd[1]+rd[2]+rd[3];
    double tt = rd[4]+rd[5]+rd[6]+rd[7];
    oAr[0]  = (float)(a  / 16777216.0 * 0.01);
    oTar[0] = (float)(tt / 16744448.0 * 0.01);
  }
}

// ---------------- launch ----------------
extern "C" void kernel_launch(void* const* d_in, const int* in_sizes, int n_in,
                              void* d_out, int out_size, void* d_ws, size_t ws_size,
                              hipStream_t stream)
{
  const float* obs  = (const float*)d_in[0];
  const float* hxs  = (const float*)d_in[1];
  const float* cxs  = (const float*)d_in[2];
  const float* W1   = (const float*)d_in[3];
  const float* b1   = (const float*)d_in[4];
  const float* W2   = (const float*)d_in[5];
  const float* b2   = (const float*)d_in[6];
  const float* W_ih = (const float*)d_in[7];
  const float* W_hh = (const float*)d_in[8];
  const float* b_ih = (const float*)d_in[9];
  const float* b_hh = (const float*)d_in[10];
  const float* ln_g = (const float*)d_in[11];
  const float* ln_b = (const float*)d_in[12];
  const float* Wa   = (const float*)d_in[13];
  const float* ba   = (const float*)d_in[14];
  const float* Wc   = (const float*)d_in[15];
  const float* bc   = (const float*)d_in[16];

  char* ws = (char*)d_ws;
  size_t off = 0;
  auto alloc = [&](size_t bytes)->char*{
    char* p = ws + off;
    off = (off + bytes + 255) & ~(size_t)255;
    return p;
  };
  unsigned short* W1_b    = (unsigned short*)alloc((size_t)NE*ND*2);
  unsigned short* W2_b    = (unsigned short*)alloc((size_t)NE*NE*2);
  unsigned short* Wih_b   = (unsigned short*)alloc((size_t)4*NH*NE*2);
  unsigned short* Whead_b = (unsigned short*)alloc((size_t)128*NH*2);
  float* bias_heads       = (float*)alloc(65*4);
  float* bias_xg          = (float*)alloc(4096*4);
  unsigned short* outln_b = (unsigned short*)alloc((size_t)NB*NT*NH*2);   // 32 MB
  unsigned short* h16     = (unsigned short*)alloc((size_t)3*NB*NH*2);    // 3-buffer rotation
  float* c_buf            = (float*)alloc((size_t)NB*NH*4);
  int*   flags            = (int*)alloc(8192*4);
  float* partials         = (float*)alloc((size_t)1024*2*4);
  const size_t fixedEnd = off;

  int lg = -1;
  for (int L = 9; L >= 4; --L){
    size_t Mc = (size_t)NB << L;
    size_t per = Mc*ND*2 + 2*(Mc*NE*2) + Mc*4096*2 + Mc*NH*2 + 6*256;
    if (fixedEnd + per <= ws_size){ lg = L; break; }
  }
  if (lg < 0){ sentinel_kernel<<<1,1,0,stream>>>((float*)d_out); return; }
  const int Tc = 1 << lg;
  const int Mc = NB << lg;
  const int nChunks = NT >> lg;

  unsigned short* obs_c  = (unsigned short*)alloc((size_t)Mc*ND*2);
  unsigned short* enc1_c = (unsigned short*)alloc((size_t)Mc*NE*2);
  unsigned short* enc2_c = (unsigned short*)alloc((size_t)Mc*NE*2);
  unsigned short* xg_c   = (unsigned short*)alloc((size_t)Mc*4096*2);
  unsigned short* hist_c = (unsigned short*)alloc((size_t)Mc*NH*2);

  float* o = (float*)d_out;
  float* oLogits = o;
  float* oValues = o + (size_t)NB*NT*64;
  float* oH  = oValues + NB*NT;
  float* oC  = oH + NB*NH;
  float* oAr = oC + NB*NH;
  float* oTar= oAr + 1;

  mega_prep<<<2048,256,0,stream>>>(W1, W2, W_ih, Wa, Wc, ba, bc, b_ih, b_hh, hxs, cxs,
                                   W1_b, W2_b, Wih_b, Whead_b, bias_heads, bias_xg,
                                   h16, c_buf, flags);

  for (int c = 0; c < nChunks; ++c){
    int t0 = c << lg, t1 = t0 + Tc;
    f2b_obs_chunk<<<512,256,0,stream>>>(obs, obs_c, lg, t0);
    gemm_bt<1,0><<<dim3(Mc/128,8) ,256,0,stream>>>(obs_c,  W1_b,  b1,      enc1_c, nullptr, nullptr, ND, NE, NE);
    gemm_bt<1,0><<<dim3(Mc/128,8) ,256,0,stream>>>(enc1_c, W2_b,  b2,      enc2_c, nullptr, nullptr, NE, NE, NE);
    gemm_bt<0,0><<<dim3(Mc/128,32),256,0,stream>>>(enc2_c, Wih_b, bias_xg, xg_c,   nullptr, nullptr, NE, 4096, 4096);

    lstm_mfma<<<256,512,LSTM_SMEM,stream>>>(xg_c, W_hh, h16, c_buf, hist_c, oH, oC, flags, t0, t1, Tc);

    ln_chunk<<<Mc/4,256,0,stream>>>(hist_c, ln_g, ln_b, outln_b, lg, t0);
  }

  gemm_bt<0,1><<<dim3(128,1),256,0,stream>>>(outln_b, Whead_b, bias_heads, nullptr, oLogits, oValues, NH, 128, 65);
  loss_partial<<<1024,256,0,stream>>>(outln_b, partials);
  loss_final<<<1,256,0,stream>>>(partials, oAr, oTar);
}